// Round 2
// baseline (5163.332 us; speedup 1.0000x reference)
//
#include <hip/hip_runtime.h>
#include <cstdint>

#define B_ 4
#define N_ 8192
#define DIM_ 512
#define H_ 8
#define DH_ 64
#define M_ 256
#define L_ 32
#define INNER_ 512
#define K3_ 1536
#define RESK_ 33

struct __align__(16) ushort8_t { unsigned short u[8]; };

__device__ __forceinline__ float bf2f(unsigned short u) {
  return __uint_as_float(((unsigned)u) << 16);
}
__device__ __forceinline__ unsigned short f2bf(float f) {
  unsigned x = __float_as_uint(f);
  return (unsigned short)((x + 0x7fffu + ((x >> 16) & 1u)) >> 16);  // RNE
}

// ---------------- LayerNorm row stats: mu, rsigma ----------------
__global__ __launch_bounds__(256) void ln_stats(const float* __restrict__ x,
                                                float2* __restrict__ st)
{
  int row = blockIdx.x;
  int tid = threadIdx.x;
  float2 v = reinterpret_cast<const float2*>(x + (size_t)row * DIM_)[tid];
  float s = v.x + v.y, s2 = v.x * v.x + v.y * v.y;
  #pragma unroll
  for (int off = 32; off; off >>= 1) { s += __shfl_down(s, off); s2 += __shfl_down(s2, off); }
  __shared__ float rs[4], rs2[4];
  int wid = tid >> 6, lane = tid & 63;
  if (lane == 0) { rs[wid] = s; rs2[wid] = s2; }
  __syncthreads();
  if (tid == 0) {
    float ts = rs[0] + rs[1] + rs[2] + rs[3];
    float ts2 = rs2[0] + rs2[1] + rs2[2] + rs2[3];
    float mu = ts * (1.f / DIM_);
    float var = ts2 * (1.f / DIM_) - mu * mu;
    st[row] = make_float2(mu, rsqrtf(var + 1e-5f));
  }
}

// ---------------- QKV GEMM with fused LN on A, bf16 head-major scatter out ----------------
// C[32768 x 1536] = LN(x) @ w_qkv ; q cols scaled 0.125; out -> qb/kb/vb [B*H][N][64] bf16
__global__ __launch_bounds__(256) void gemm_qkv(const float* __restrict__ x,
    const float2* __restrict__ st, const float* __restrict__ lnw, const float* __restrict__ lnb,
    const float* __restrict__ wqkv,
    unsigned short* __restrict__ qb, unsigned short* __restrict__ kb, unsigned short* __restrict__ vb)
{
  __shared__ float As[8][128];
  __shared__ float Bs[8][128];
  int tid = threadIdx.x;
  int bm = blockIdx.y * 128, bn = blockIdx.x * 128;
  int ty = tid >> 4, tx = tid & 15;
  int arow = (tid * 4) >> 3, akk = (tid * 4) & 7;
  int bkk = (tid * 4) >> 7, bcol = (tid * 4) & 127;
  float2 stv = st[bm + arow];
  float acc[8][8] = {};
  for (int k0 = 0; k0 < DIM_; k0 += 8) {
    float4 av = *reinterpret_cast<const float4*>(&x[(size_t)(bm + arow) * DIM_ + k0 + akk]);
    float4 wv = *reinterpret_cast<const float4*>(&lnw[k0 + akk]);
    float4 bv2 = *reinterpret_cast<const float4*>(&lnb[k0 + akk]);
    av.x = (av.x - stv.x) * stv.y * wv.x + bv2.x;
    av.y = (av.y - stv.x) * stv.y * wv.y + bv2.y;
    av.z = (av.z - stv.x) * stv.y * wv.z + bv2.z;
    av.w = (av.w - stv.x) * stv.y * wv.w + bv2.w;
    float4 bv = *reinterpret_cast<const float4*>(&wqkv[(size_t)(k0 + bkk) * K3_ + bn + bcol]);
    __syncthreads();
    As[akk + 0][arow] = av.x; As[akk + 1][arow] = av.y;
    As[akk + 2][arow] = av.z; As[akk + 3][arow] = av.w;
    *reinterpret_cast<float4*>(&Bs[bkk][bcol]) = bv;
    __syncthreads();
    #pragma unroll
    for (int kk = 0; kk < 8; kk++) {
      float ar[8], br[8];
      #pragma unroll
      for (int i = 0; i < 8; i++) ar[i] = As[kk][ty * 8 + i];
      #pragma unroll
      for (int j = 0; j < 8; j++) br[j] = Bs[kk][tx * 8 + j];
      #pragma unroll
      for (int i = 0; i < 8; i++)
        #pragma unroll
        for (int j = 0; j < 8; j++) acc[i][j] += ar[i] * br[j];
    }
  }
  int c0 = bn + tx * 8;
  int which = c0 >> 9;           // 0=q 1=k 2=v (8-col group never crosses 512 boundary)
  int hh = (c0 >> 6) & (H_ - 1); // never crosses 64 boundary
  int d0 = c0 & 63;
  unsigned short* dst = which == 0 ? qb : (which == 1 ? kb : vb);
  float qs = which == 0 ? 0.125f : 1.0f;
  for (int i = 0; i < 8; i++) {
    int r = bm + ty * 8 + i;
    int b = r >> 13, n = r & (N_ - 1);
    ushort8_t pk;
    #pragma unroll
    for (int j = 0; j < 8; j++) pk.u[j] = f2bf(acc[i][j] * qs);
    *reinterpret_cast<ushort8_t*>(&dst[(((size_t)(b * H_ + hh) * N_ + n) << 6) + d0]) = pk;
  }
}

// ---------------- landmark means: block per (bh, m), 64 threads ----------------
__global__ __launch_bounds__(64) void landmark_kernel(const unsigned short* __restrict__ qb,
    const unsigned short* __restrict__ kb, float* __restrict__ ql, float* __restrict__ kl)
{
  int id = blockIdx.x;
  int m = id & (M_ - 1);
  int bh = id >> 8;
  int d = threadIdx.x;
  size_t base = (((size_t)bh * N_ + m * L_) << 6) + d;
  float sq = 0, sk = 0;
  #pragma unroll 4
  for (int j = 0; j < L_; j++) {
    sq += bf2f(qb[base + ((size_t)j << 6)]);
    sk += bf2f(kb[base + ((size_t)j << 6)]);
  }
  ql[((size_t)bh * M_ + m) * DH_ + d] = sq * (1.f / L_);
  kl[((size_t)bh * M_ + m) * DH_ + d] = sk * (1.f / L_);
}

// ---------------- sim2 + softmax -> attn2: block per (bh, row i) ----------------
__global__ __launch_bounds__(256) void attn2_kernel(const float* __restrict__ ql,
    const float* __restrict__ kl, float* __restrict__ a2)
{
  int id = blockIdx.x;
  int i = id & (M_ - 1);
  int bh = id >> 8;
  int j = threadIdx.x;
  __shared__ float qs[DH_];
  __shared__ float wred[4];
  if (j < DH_) qs[j] = ql[((size_t)bh * M_ + i) * DH_ + j];
  __syncthreads();
  const float* krow = kl + ((size_t)bh * M_ + j) * DH_;
  float s = 0;
  #pragma unroll
  for (int d = 0; d < DH_; d++) s += qs[d] * krow[d];
  float mx = s;
  #pragma unroll
  for (int off = 1; off < 64; off <<= 1) mx = fmaxf(mx, __shfl_xor(mx, off));
  int wid = j >> 6, lane = j & 63;
  if (lane == 0) wred[wid] = mx;
  __syncthreads();
  mx = fmaxf(fmaxf(wred[0], wred[1]), fmaxf(wred[2], wred[3]));
  float e = __expf(s - mx);
  float sum = e;
  #pragma unroll
  for (int off = 1; off < 64; off <<= 1) sum += __shfl_xor(sum, off);
  __syncthreads();
  if (lane == 0) wred[wid] = sum;
  __syncthreads();
  sum = wred[0] + wred[1] + wred[2] + wred[3];
  a2[((size_t)bh * M_ + i) * M_ + j] = e / sum;
}

// ---------------- pinv scale: global max row-sum & max col-sum ----------------
__global__ void zero_scal(unsigned int* scal) { scal[threadIdx.x] = 0u; }

__global__ __launch_bounds__(256) void pinv_scale_kernel(const float* __restrict__ a2,
    unsigned int* __restrict__ scal)
{
  int bh = blockIdx.x;
  int t = threadIdx.x;
  const float* xb = a2 + (size_t)bh * M_ * M_;
  float rowsum = 0, colsum = 0;
  for (int j = 0; j < M_; j++) {
    rowsum += xb[(size_t)t * M_ + j];   // softmax outputs >= 0
    colsum += xb[(size_t)j * M_ + t];
  }
  #pragma unroll
  for (int off = 1; off < 64; off <<= 1) {
    rowsum = fmaxf(rowsum, __shfl_xor(rowsum, off));
    colsum = fmaxf(colsum, __shfl_xor(colsum, off));
  }
  __shared__ float wr[4], wc[4];
  int wid = t >> 6, lane = t & 63;
  if (lane == 0) { wr[wid] = rowsum; wc[wid] = colsum; }
  __syncthreads();
  if (t == 0) {
    float rm = fmaxf(fmaxf(wr[0], wr[1]), fmaxf(wr[2], wr[3]));
    float cm = fmaxf(fmaxf(wc[0], wc[1]), fmaxf(wc[2], wc[3]));
    atomicMax(&scal[0], __float_as_uint(rm));
    atomicMax(&scal[1], __float_as_uint(cm));
  }
}

__global__ __launch_bounds__(256) void zinit_kernel(const float* __restrict__ a2,
    const unsigned int* __restrict__ scal, float* __restrict__ z)
{
  int bh = blockIdx.x;
  int j = threadIdx.x;
  float inv = 1.f / (__uint_as_float(scal[0]) * __uint_as_float(scal[1]));
  const float* xb = a2 + (size_t)bh * M_ * M_;
  float* zr = z + (size_t)bh * M_ * M_ + (size_t)j * M_;
  for (int i = 0; i < M_; i++) zr[i] = xb[(size_t)i * M_ + j] * inv;  // z = x^T / s
}

// ---------------- batched 64x64x16 SGEMM: C = scale * A @ (useI? aI - B : B) ----------------
__global__ __launch_bounds__(256) void bgemm64(const float* __restrict__ A,
    const float* __restrict__ Bm, float* __restrict__ C, int Nc, int Kd,
    long long sA, long long sB, long long sC, float aI, float scale, int useI)
{
  __shared__ float As[16][64];
  __shared__ float Bs[16][64];
  int batch = blockIdx.z;
  const float* Ab = A + (size_t)batch * sA;
  const float* Bb = Bm + (size_t)batch * sB;
  float* Cb = C + (size_t)batch * sC;
  int bm = blockIdx.y * 64, bn = blockIdx.x * 64;
  int tid = threadIdx.x;
  int ty = tid >> 4, tx = tid & 15;
  int arow = (tid * 4) >> 4, akk = (tid * 4) & 15;
  int bkk = (tid * 4) >> 6, bcol = (tid * 4) & 63;
  float acc[4][4] = {};
  for (int k0 = 0; k0 < Kd; k0 += 16) {
    float4 av = *reinterpret_cast<const float4*>(&Ab[(size_t)(bm + arow) * Kd + k0 + akk]);
    float4 bv = *reinterpret_cast<const float4*>(&Bb[(size_t)(k0 + bkk) * Nc + bn + bcol]);
    if (useI) {
      int kr = k0 + bkk, cc = bn + bcol;
      bv.x = (kr == cc + 0 ? aI : 0.f) - bv.x;
      bv.y = (kr == cc + 1 ? aI : 0.f) - bv.y;
      bv.z = (kr == cc + 2 ? aI : 0.f) - bv.z;
      bv.w = (kr == cc + 3 ? aI : 0.f) - bv.w;
    }
    __syncthreads();
    As[akk + 0][arow] = av.x; As[akk + 1][arow] = av.y;
    As[akk + 2][arow] = av.z; As[akk + 3][arow] = av.w;
    *reinterpret_cast<float4*>(&Bs[bkk][bcol]) = bv;
    __syncthreads();
    #pragma unroll
    for (int kk = 0; kk < 16; kk++) {
      float ar[4], br[4];
      #pragma unroll
      for (int i = 0; i < 4; i++) ar[i] = As[kk][ty * 4 + i];
      #pragma unroll
      for (int j = 0; j < 4; j++) br[j] = Bs[kk][tx * 4 + j];
      #pragma unroll
      for (int i = 0; i < 4; i++)
        #pragma unroll
        for (int j = 0; j < 4; j++) acc[i][j] += ar[i] * br[j];
    }
  }
  for (int i = 0; i < 4; i++)
    #pragma unroll
    for (int j = 0; j < 4; j++)
      Cb[(size_t)(bm + ty * 4 + i) * Nc + bn + tx * 4 + j] = scale * acc[i][j];
}

// ---------------- pv = softmax(q_l @ k^T over n) @ v  (flash-style, bf16 k/v) ----------------
__global__ __launch_bounds__(256) void pv_kernel(const unsigned short* __restrict__ kb,
    const unsigned short* __restrict__ vb, const float* __restrict__ ql, float* __restrict__ pv)
{
  int blk = blockIdx.x;
  int mt = blk & 15;
  int bh = blk >> 4;
  int tid = threadIdx.x;
  int wid = tid >> 6, lane = tid & 63;
  __shared__ float klds[64][65];
  __shared__ float vlds[64][65];
  __shared__ float qlds[16][DH_];
  __shared__ float plds[4][4][64];
  for (int e = tid; e < 16 * DH_; e += 256) {
    int r = e >> 6, d = e & 63;
    qlds[r][d] = ql[((size_t)bh * M_ + mt * 16 + r) * DH_ + d];
  }
  float acc[4] = {0, 0, 0, 0}, srun[4] = {0, 0, 0, 0}, mrun[4];
  #pragma unroll
  for (int r = 0; r < 4; r++) mrun[r] = -1e30f;
  const unsigned short* kbase = kb + (((size_t)bh * N_) << 6);
  const unsigned short* vbase = vb + (((size_t)bh * N_) << 6);
  __syncthreads();
  for (int n0 = 0; n0 < N_; n0 += 64) {
    __syncthreads();
    for (int e = tid * 4; e < 64 * 64; e += 1024) {
      int nn = e >> 6, d = e & 63;
      ushort4 k4 = *reinterpret_cast<const ushort4*>(&kbase[(((size_t)(n0 + nn)) << 6) + d]);
      ushort4 v4 = *reinterpret_cast<const ushort4*>(&vbase[(((size_t)(n0 + nn)) << 6) + d]);
      klds[nn][d] = bf2f(k4.x); klds[nn][d + 1] = bf2f(k4.y);
      klds[nn][d + 2] = bf2f(k4.z); klds[nn][d + 3] = bf2f(k4.w);
      vlds[nn][d] = bf2f(v4.x); vlds[nn][d + 1] = bf2f(v4.y);
      vlds[nn][d + 2] = bf2f(v4.z); vlds[nn][d + 3] = bf2f(v4.w);
    }
    __syncthreads();
    float s[4] = {0, 0, 0, 0};
    for (int d0 = 0; d0 < DH_; d0 += 16) {
      float kr[16];
      #pragma unroll
      for (int dd = 0; dd < 16; dd++) kr[dd] = klds[lane][d0 + dd];
      #pragma unroll
      for (int r = 0; r < 4; r++) {
        int rowq = wid * 4 + r;
        float a = 0;
        #pragma unroll
        for (int dd = 0; dd < 16; dd++) a += qlds[rowq][d0 + dd] * kr[dd];
        s[r] += a;
      }
    }
    #pragma unroll
    for (int r = 0; r < 4; r++) {
      float mx = s[r];
      #pragma unroll
      for (int off = 1; off < 64; off <<= 1) mx = fmaxf(mx, __shfl_xor(mx, off));
      float mnew = fmaxf(mrun[r], mx);
      float p = __expf(s[r] - mnew);
      float psum = p;
      #pragma unroll
      for (int off = 1; off < 64; off <<= 1) psum += __shfl_xor(psum, off);
      float corr = __expf(mrun[r] - mnew);
      srun[r] = srun[r] * corr + psum;
      acc[r] *= corr;
      mrun[r] = mnew;
      plds[wid][r][lane] = p;
    }
    __syncthreads();
    for (int j = 0; j < 64; j++) {
      float v = vlds[j][lane];
      #pragma unroll
      for (int r = 0; r < 4; r++) acc[r] += plds[wid][r][j] * v;
    }
  }
  #pragma unroll
  for (int r = 0; r < 4; r++)
    pv[((size_t)bh * M_ + mt * 16 + wid * 4 + r) * DH_ + lane] = acc[r] / srun[r];
}

// ---------------- oh = softmax(q @ k_l^T) @ W2, one wave per query row ----------------
__global__ __launch_bounds__(256) void out1_kernel(const unsigned short* __restrict__ qb,
    const float* __restrict__ kl, const float* __restrict__ w2, unsigned short* __restrict__ oh)
{
  int wid = threadIdx.x >> 6, lane = threadIdx.x & 63;
  long long row = (long long)blockIdx.x * 4 + wid;   // over B*H*N
  int n = (int)(row & (N_ - 1));
  int bh = (int)(row >> 13);
  int h = bh & (H_ - 1), b = bh >> 3;
  __shared__ float qs[4][DH_];
  __shared__ float ps[4][M_];
  qs[wid][lane] = bf2f(qb[(((size_t)bh * N_ + n) << 6) + lane]);
  __syncthreads();
  const float* klb = kl + (size_t)bh * M_ * DH_;
  float s[4];
  #pragma unroll
  for (int e = 0; e < 4; e++) {
    const float* krow = klb + (size_t)(e * 64 + lane) * DH_;
    float a = 0;
    #pragma unroll
    for (int d = 0; d < DH_; d++) a += qs[wid][d] * krow[d];
    s[e] = a;
  }
  float mx = fmaxf(fmaxf(s[0], s[1]), fmaxf(s[2], s[3]));
  #pragma unroll
  for (int off = 1; off < 64; off <<= 1) mx = fmaxf(mx, __shfl_xor(mx, off));
  float sum = 0, p[4];
  #pragma unroll
  for (int e = 0; e < 4; e++) { p[e] = __expf(s[e] - mx); sum += p[e]; }
  #pragma unroll
  for (int off = 1; off < 64; off <<= 1) sum += __shfl_xor(sum, off);
  #pragma unroll
  for (int e = 0; e < 4; e++) ps[wid][e * 64 + lane] = p[e];
  __syncthreads();
  const float* w2b = w2 + (size_t)bh * M_ * DH_;
  float acc = 0;
  #pragma unroll 8
  for (int j = 0; j < M_; j++) acc += ps[wid][j] * w2b[(size_t)j * DH_ + lane];
  oh[((size_t)(b * N_ + n) << 9) + h * DH_ + lane] = f2bf(acc / sum);
}

// ---------------- depthwise conv residual: oh += conv(v) ----------------
__global__ __launch_bounds__(256) void conv_kernel(const unsigned short* __restrict__ vb,
    const float* __restrict__ rw, unsigned short* __restrict__ oh)
{
  long long idx = (long long)blockIdx.x * 256 + threadIdx.x;  // over B*N*INNER
  int c = (int)(idx & (INNER_ - 1));
  long long bn = idx >> 9;
  int n = (int)(bn & (N_ - 1));
  int b = (int)(bn >> 13);
  int h = c >> 6, d = c & 63;
  const unsigned short* vbb = vb + (((size_t)(b * H_ + h) * N_) << 6) + d;
  float acc = 0;
  #pragma unroll
  for (int j = 0; j < RESK_; j++) {
    int nn = n + j - RESK_ / 2;
    if (nn >= 0 && nn < N_) acc += rw[h * RESK_ + j] * bf2f(vbb[((size_t)nn) << 6]);
  }
  oh[idx] = f2bf(bf2f(oh[idx]) + acc);
}

// ---------------- final GEMM: out = oh(bf16) @ w_out + b_out + x ----------------
__global__ __launch_bounds__(256) void gemm_out(const unsigned short* __restrict__ oh,
    const float* __restrict__ wout, const float* __restrict__ bias,
    const float* __restrict__ resid, float* __restrict__ out)
{
  __shared__ float As[8][128];
  __shared__ float Bs[8][128];
  int tid = threadIdx.x;
  int bm = blockIdx.y * 128, bn = blockIdx.x * 128;
  int ty = tid >> 4, tx = tid & 15;
  int arow = (tid * 4) >> 3, akk = (tid * 4) & 7;
  int bkk = (tid * 4) >> 7, bcol = (tid * 4) & 127;
  float acc[8][8] = {};
  for (int k0 = 0; k0 < INNER_; k0 += 8) {
    ushort4 a4 = *reinterpret_cast<const ushort4*>(&oh[((size_t)(bm + arow) << 9) + k0 + akk]);
    float4 bv = *reinterpret_cast<const float4*>(&wout[(size_t)(k0 + bkk) * DIM_ + bn + bcol]);
    __syncthreads();
    As[akk + 0][arow] = bf2f(a4.x); As[akk + 1][arow] = bf2f(a4.y);
    As[akk + 2][arow] = bf2f(a4.z); As[akk + 3][arow] = bf2f(a4.w);
    *reinterpret_cast<float4*>(&Bs[bkk][bcol]) = bv;
    __syncthreads();
    #pragma unroll
    for (int kk = 0; kk < 8; kk++) {
      float ar[8], br[8];
      #pragma unroll
      for (int i = 0; i < 8; i++) ar[i] = As[kk][ty * 8 + i];
      #pragma unroll
      for (int j = 0; j < 8; j++) br[j] = Bs[kk][tx * 8 + j];
      #pragma unroll
      for (int i = 0; i < 8; i++)
        #pragma unroll
        for (int j = 0; j < 8; j++) acc[i][j] += ar[i] * br[j];
    }
  }
  for (int i = 0; i < 8; i++) {
    int r = bm + ty * 8 + i;
    int c0 = bn + tx * 8;
    float4 r0 = *reinterpret_cast<const float4*>(&resid[(size_t)r * DIM_ + c0]);
    float4 r1 = *reinterpret_cast<const float4*>(&resid[(size_t)r * DIM_ + c0 + 4]);
    float4 b0 = *reinterpret_cast<const float4*>(&bias[c0]);
    float4 b1 = *reinterpret_cast<const float4*>(&bias[c0 + 4]);
    float4 o0 = make_float4(acc[i][0] + b0.x + r0.x, acc[i][1] + b0.y + r0.y,
                            acc[i][2] + b0.z + r0.z, acc[i][3] + b0.w + r0.w);
    float4 o1 = make_float4(acc[i][4] + b1.x + r1.x, acc[i][5] + b1.y + r1.y,
                            acc[i][6] + b1.z + r1.z, acc[i][7] + b1.w + r1.w);
    *reinterpret_cast<float4*>(&out[(size_t)r * DIM_ + c0])     = o0;
    *reinterpret_cast<float4*>(&out[(size_t)r * DIM_ + c0 + 4]) = o1;
  }
}

extern "C" void kernel_launch(void* const* d_in, const int* in_sizes, int n_in,
                              void* d_out, int out_size, void* d_ws, size_t ws_size,
                              hipStream_t stream)
{
  const float* x     = (const float*)d_in[0];
  const float* ln_w  = (const float*)d_in[1];
  const float* ln_b  = (const float*)d_in[2];
  const float* w_qkv = (const float*)d_in[3];
  const float* w_out = (const float*)d_in[4];
  const float* b_out = (const float*)d_in[5];
  const float* res_w = (const float*)d_in[6];
  float* out = (float*)d_out;

  // ---- workspace layout (bf16-heavy): ~136.3 MiB ----
  const size_t HEADEL = (size_t)B_ * H_ * N_ * DH_;     // 16,777,216
  const size_t SMALL  = (size_t)B_ * H_ * M_ * DH_;     // 524,288
  unsigned short* qb = (unsigned short*)d_ws;
  unsigned short* kb = qb + HEADEL;
  unsigned short* vb = kb + HEADEL;
  unsigned short* oh = vb + HEADEL;
  float* ql  = (float*)(oh + HEADEL);
  float* kl  = ql + SMALL;
  float* pvb = kl + SMALL;
  float* w2b = pvb + SMALL;
  float2* stats = (float2*)(w2b + SMALL);               // B*N entries
  unsigned int* scal = (unsigned int*)(stats + (size_t)B_ * N_);
  size_t need = (size_t)((char*)(scal + 64) - (char*)d_ws);
  if (ws_size < need) return;  // clean fail -> diagnoses ws_size too small

  // ---- pinv chain lives in d_out (dead before gemm_out overwrites it) ----
  const size_t SZ = (size_t)M_ * M_;                    // 65,536
  float* a2 = (float*)d_out;                            // 32 * 64KB*4 = 8 MiB
  float* z0 = a2 + (size_t)B_ * H_ * SZ;
  float* z1 = z0 + (size_t)B_ * H_ * SZ;
  float* z2 = z1 + (size_t)B_ * H_ * SZ;
  float* z3 = z2 + (size_t)B_ * H_ * SZ;                // total 40 MiB <= 64 MiB

  ln_stats<<<B_ * N_, 256, 0, stream>>>(x, stats);
  gemm_qkv<<<dim3(K3_ / 128, (B_ * N_) / 128), 256, 0, stream>>>(
      x, stats, ln_w, ln_b, w_qkv, qb, kb, vb);
  landmark_kernel<<<B_ * H_ * M_, 64, 0, stream>>>(qb, kb, ql, kl);
  attn2_kernel<<<B_ * H_ * M_, 256, 0, stream>>>(ql, kl, a2);
  zero_scal<<<1, 2, 0, stream>>>(scal);
  pinv_scale_kernel<<<B_ * H_, 256, 0, stream>>>(a2, scal);
  zinit_kernel<<<B_ * H_, 256, 0, stream>>>(a2, scal, z0);
  pv_kernel<<<B_ * H_ * (M_ / 16), 256, 0, stream>>>(kb, vb, ql, pvb);

  const long long SZL = (long long)SZ;
  float* cur = z0; float* u = z1; float* vv = z2; float* wb = z3;
  for (int it = 0; it < 6; it++) {
    bgemm64<<<dim3(4, 4, B_ * H_), 256, 0, stream>>>(a2, cur, u, M_, M_, SZL, SZL, SZL, 0.f, 1.f, 0);
    bgemm64<<<dim3(4, 4, B_ * H_), 256, 0, stream>>>(u, u, vv, M_, M_, SZL, SZL, SZL, 7.f, 1.f, 1);
    bgemm64<<<dim3(4, 4, B_ * H_), 256, 0, stream>>>(u, vv, wb, M_, M_, SZL, SZL, SZL, 15.f, 1.f, 1);
    bgemm64<<<dim3(4, 4, B_ * H_), 256, 0, stream>>>(cur, wb, u, M_, M_, SZL, SZL, SZL, 13.f, 0.25f, 1);
    float* oc = cur; cur = u; u = vv; vv = wb; wb = oc;
  }

  // W2 = pinv @ pv  (256x64 per bh)
  bgemm64<<<dim3(1, 4, B_ * H_), 256, 0, stream>>>(cur, pvb, w2b, DH_, M_,
      SZL, (long long)M_ * DH_, (long long)M_ * DH_, 0.f, 1.f, 0);

  out1_kernel<<<(B_ * H_ * N_) / 4, 256, 0, stream>>>(qb, kl, w2b, oh);
  conv_kernel<<<(int)(((long long)B_ * N_ * INNER_) / 256), 256, 0, stream>>>(vb, res_w, oh);
  gemm_out<<<dim3(DIM_ / 128, (B_ * N_) / 128), 256, 0, stream>>>(oh, w_out, b_out, x, out);
}

// Round 3
// 2654.056 us; speedup vs baseline: 1.9454x; 1.9454x over previous
//
#include <hip/hip_runtime.h>
#include <cstdint>

#define B_ 4
#define N_ 8192
#define DIM_ 512
#define H_ 8
#define DH_ 64
#define M_ 256
#define L_ 32
#define INNER_ 512
#define K3_ 1536
#define RESK_ 33

struct __align__(16) ushort8_t { unsigned short u[8]; };
typedef short bf16x8 __attribute__((ext_vector_type(8)));
typedef float f32x4 __attribute__((ext_vector_type(4)));

__device__ __forceinline__ float bf2f(unsigned short u) {
  return __uint_as_float(((unsigned)u) << 16);
}
__device__ __forceinline__ unsigned short f2bf(float f) {
  unsigned x = __float_as_uint(f);
  return (unsigned short)((x + 0x7fffu + ((x >> 16) & 1u)) >> 16);  // RNE
}

// ---------------- LayerNorm row stats: mu, rsigma ----------------
__global__ __launch_bounds__(256) void ln_stats(const float* __restrict__ x,
                                                float2* __restrict__ st)
{
  int row = blockIdx.x;
  int tid = threadIdx.x;
  float2 v = reinterpret_cast<const float2*>(x + (size_t)row * DIM_)[tid];
  float s = v.x + v.y, s2 = v.x * v.x + v.y * v.y;
  #pragma unroll
  for (int off = 32; off; off >>= 1) { s += __shfl_down(s, off); s2 += __shfl_down(s2, off); }
  __shared__ float rs[4], rs2[4];
  int wid = tid >> 6, lane = tid & 63;
  if (lane == 0) { rs[wid] = s; rs2[wid] = s2; }
  __syncthreads();
  if (tid == 0) {
    float ts = rs[0] + rs[1] + rs[2] + rs[3];
    float ts2 = rs2[0] + rs2[1] + rs2[2] + rs2[3];
    float mu = ts * (1.f / DIM_);
    float var = ts2 * (1.f / DIM_) - mu * mu;
    st[row] = make_float2(mu, rsqrtf(var + 1e-5f));
  }
}

// ---------------- QKV GEMM with fused LN on A, bf16 head-major scatter out ----------------
__global__ __launch_bounds__(256) void gemm_qkv(const float* __restrict__ x,
    const float2* __restrict__ st, const float* __restrict__ lnw, const float* __restrict__ lnb,
    const float* __restrict__ wqkv,
    unsigned short* __restrict__ qb, unsigned short* __restrict__ kb, unsigned short* __restrict__ vb)
{
  __shared__ float As[8][128];
  __shared__ float Bs[8][128];
  int tid = threadIdx.x;
  int bm = blockIdx.y * 128, bn = blockIdx.x * 128;
  int ty = tid >> 4, tx = tid & 15;
  int arow = (tid * 4) >> 3, akk = (tid * 4) & 7;
  int bkk = (tid * 4) >> 7, bcol = (tid * 4) & 127;
  float2 stv = st[bm + arow];
  float acc[8][8] = {};
  for (int k0 = 0; k0 < DIM_; k0 += 8) {
    float4 av = *reinterpret_cast<const float4*>(&x[(size_t)(bm + arow) * DIM_ + k0 + akk]);
    float4 wv = *reinterpret_cast<const float4*>(&lnw[k0 + akk]);
    float4 bv2 = *reinterpret_cast<const float4*>(&lnb[k0 + akk]);
    av.x = (av.x - stv.x) * stv.y * wv.x + bv2.x;
    av.y = (av.y - stv.x) * stv.y * wv.y + bv2.y;
    av.z = (av.z - stv.x) * stv.y * wv.z + bv2.z;
    av.w = (av.w - stv.x) * stv.y * wv.w + bv2.w;
    float4 bv = *reinterpret_cast<const float4*>(&wqkv[(size_t)(k0 + bkk) * K3_ + bn + bcol]);
    __syncthreads();
    As[akk + 0][arow] = av.x; As[akk + 1][arow] = av.y;
    As[akk + 2][arow] = av.z; As[akk + 3][arow] = av.w;
    *reinterpret_cast<float4*>(&Bs[bkk][bcol]) = bv;
    __syncthreads();
    #pragma unroll
    for (int kk = 0; kk < 8; kk++) {
      float ar[8], br[8];
      #pragma unroll
      for (int i = 0; i < 8; i++) ar[i] = As[kk][ty * 8 + i];
      #pragma unroll
      for (int j = 0; j < 8; j++) br[j] = Bs[kk][tx * 8 + j];
      #pragma unroll
      for (int i = 0; i < 8; i++)
        #pragma unroll
        for (int j = 0; j < 8; j++) acc[i][j] += ar[i] * br[j];
    }
  }
  int c0 = bn + tx * 8;
  int which = c0 >> 9;
  int hh = (c0 >> 6) & (H_ - 1);
  int d0 = c0 & 63;
  unsigned short* dst = which == 0 ? qb : (which == 1 ? kb : vb);
  float qs = which == 0 ? 0.125f : 1.0f;
  for (int i = 0; i < 8; i++) {
    int r = bm + ty * 8 + i;
    int b = r >> 13, n = r & (N_ - 1);
    ushort8_t pk;
    #pragma unroll
    for (int j = 0; j < 8; j++) pk.u[j] = f2bf(acc[i][j] * qs);
    *reinterpret_cast<ushort8_t*>(&dst[(((size_t)(b * H_ + hh) * N_ + n) << 6) + d0]) = pk;
  }
}

// ---------------- landmark means ----------------
__global__ __launch_bounds__(64) void landmark_kernel(const unsigned short* __restrict__ qb,
    const unsigned short* __restrict__ kb, float* __restrict__ ql, float* __restrict__ kl)
{
  int id = blockIdx.x;
  int m = id & (M_ - 1);
  int bh = id >> 8;
  int d = threadIdx.x;
  size_t base = (((size_t)bh * N_ + m * L_) << 6) + d;
  float sq = 0, sk = 0;
  #pragma unroll 4
  for (int j = 0; j < L_; j++) {
    sq += bf2f(qb[base + ((size_t)j << 6)]);
    sk += bf2f(kb[base + ((size_t)j << 6)]);
  }
  ql[((size_t)bh * M_ + m) * DH_ + d] = sq * (1.f / L_);
  kl[((size_t)bh * M_ + m) * DH_ + d] = sk * (1.f / L_);
}

// ---------------- sim2 + softmax -> attn2 ----------------
__global__ __launch_bounds__(256) void attn2_kernel(const float* __restrict__ ql,
    const float* __restrict__ kl, float* __restrict__ a2)
{
  int id = blockIdx.x;
  int i = id & (M_ - 1);
  int bh = id >> 8;
  int j = threadIdx.x;
  __shared__ float qs[DH_];
  __shared__ float wred[4];
  if (j < DH_) qs[j] = ql[((size_t)bh * M_ + i) * DH_ + j];
  __syncthreads();
  const float* krow = kl + ((size_t)bh * M_ + j) * DH_;
  float s = 0;
  #pragma unroll
  for (int d = 0; d < DH_; d++) s += qs[d] * krow[d];
  float mx = s;
  #pragma unroll
  for (int off = 1; off < 64; off <<= 1) mx = fmaxf(mx, __shfl_xor(mx, off));
  int wid = j >> 6, lane = j & 63;
  if (lane == 0) wred[wid] = mx;
  __syncthreads();
  mx = fmaxf(fmaxf(wred[0], wred[1]), fmaxf(wred[2], wred[3]));
  float e = __expf(s - mx);
  float sum = e;
  #pragma unroll
  for (int off = 1; off < 64; off <<= 1) sum += __shfl_xor(sum, off);
  __syncthreads();
  if (lane == 0) wred[wid] = sum;
  __syncthreads();
  sum = wred[0] + wred[1] + wred[2] + wred[3];
  a2[((size_t)bh * M_ + i) * M_ + j] = e / sum;
}

// ---------------- pinv scale ----------------
__global__ void zero_scal(unsigned int* scal) { scal[threadIdx.x] = 0u; }

__global__ __launch_bounds__(256) void pinv_scale_kernel(const float* __restrict__ a2,
    unsigned int* __restrict__ scal)
{
  int bh = blockIdx.x;
  int t = threadIdx.x;
  const float* xb = a2 + (size_t)bh * M_ * M_;
  float rowsum = 0, colsum = 0;
  for (int j = 0; j < M_; j++) {
    rowsum += xb[(size_t)t * M_ + j];
    colsum += xb[(size_t)j * M_ + t];
  }
  #pragma unroll
  for (int off = 1; off < 64; off <<= 1) {
    rowsum = fmaxf(rowsum, __shfl_xor(rowsum, off));
    colsum = fmaxf(colsum, __shfl_xor(colsum, off));
  }
  __shared__ float wr[4], wc[4];
  int wid = t >> 6, lane = t & 63;
  if (lane == 0) { wr[wid] = rowsum; wc[wid] = colsum; }
  __syncthreads();
  if (t == 0) {
    float rm = fmaxf(fmaxf(wr[0], wr[1]), fmaxf(wr[2], wr[3]));
    float cm = fmaxf(fmaxf(wc[0], wc[1]), fmaxf(wc[2], wc[3]));
    atomicMax(&scal[0], __float_as_uint(rm));
    atomicMax(&scal[1], __float_as_uint(cm));
  }
}

__global__ __launch_bounds__(256) void zinit_kernel(const float* __restrict__ a2,
    const unsigned int* __restrict__ scal, float* __restrict__ z)
{
  int bh = blockIdx.x;
  int j = threadIdx.x;
  float inv = 1.f / (__uint_as_float(scal[0]) * __uint_as_float(scal[1]));
  const float* xb = a2 + (size_t)bh * M_ * M_;
  float* zr = z + (size_t)bh * M_ * M_ + (size_t)j * M_;
  for (int i = 0; i < M_; i++) zr[i] = xb[(size_t)i * M_ + j] * inv;
}

// ---------------- batched 64x64x16 SGEMM ----------------
__global__ __launch_bounds__(256) void bgemm64(const float* __restrict__ A,
    const float* __restrict__ Bm, float* __restrict__ C, int Nc, int Kd,
    long long sA, long long sB, long long sC, float aI, float scale, int useI)
{
  __shared__ float As[16][64];
  __shared__ float Bs[16][64];
  int batch = blockIdx.z;
  const float* Ab = A + (size_t)batch * sA;
  const float* Bb = Bm + (size_t)batch * sB;
  float* Cb = C + (size_t)batch * sC;
  int bm = blockIdx.y * 64, bn = blockIdx.x * 64;
  int tid = threadIdx.x;
  int ty = tid >> 4, tx = tid & 15;
  int arow = (tid * 4) >> 4, akk = (tid * 4) & 15;
  int bkk = (tid * 4) >> 6, bcol = (tid * 4) & 63;
  float acc[4][4] = {};
  for (int k0 = 0; k0 < Kd; k0 += 16) {
    float4 av = *reinterpret_cast<const float4*>(&Ab[(size_t)(bm + arow) * Kd + k0 + akk]);
    float4 bv = *reinterpret_cast<const float4*>(&Bb[(size_t)(k0 + bkk) * Nc + bn + bcol]);
    if (useI) {
      int kr = k0 + bkk, cc = bn + bcol;
      bv.x = (kr == cc + 0 ? aI : 0.f) - bv.x;
      bv.y = (kr == cc + 1 ? aI : 0.f) - bv.y;
      bv.z = (kr == cc + 2 ? aI : 0.f) - bv.z;
      bv.w = (kr == cc + 3 ? aI : 0.f) - bv.w;
    }
    __syncthreads();
    As[akk + 0][arow] = av.x; As[akk + 1][arow] = av.y;
    As[akk + 2][arow] = av.z; As[akk + 3][arow] = av.w;
    *reinterpret_cast<float4*>(&Bs[bkk][bcol]) = bv;
    __syncthreads();
    #pragma unroll
    for (int kk = 0; kk < 16; kk++) {
      float ar[4], br[4];
      #pragma unroll
      for (int i = 0; i < 4; i++) ar[i] = As[kk][ty * 4 + i];
      #pragma unroll
      for (int j = 0; j < 4; j++) br[j] = Bs[kk][tx * 4 + j];
      #pragma unroll
      for (int i = 0; i < 4; i++)
        #pragma unroll
        for (int j = 0; j < 4; j++) acc[i][j] += ar[i] * br[j];
    }
  }
  for (int i = 0; i < 4; i++)
    #pragma unroll
    for (int j = 0; j < 4; j++)
      Cb[(size_t)(bm + ty * 4 + i) * Nc + bn + tx * 4 + j] = scale * acc[i][j];
}

// ---------------- pv = softmax(q_l @ k^T over n) @ v  (flash-style, bf16 k/v) ----------------
__global__ __launch_bounds__(256) void pv_kernel(const unsigned short* __restrict__ kb,
    const unsigned short* __restrict__ vb, const float* __restrict__ ql, float* __restrict__ pv)
{
  int blk = blockIdx.x;
  int mt = blk & 15;
  int bh = blk >> 4;
  int tid = threadIdx.x;
  int wid = tid >> 6, lane = tid & 63;
  __shared__ float klds[64][65];
  __shared__ float vlds[64][65];
  __shared__ float qlds[16][DH_];
  __shared__ float plds[4][4][64];
  for (int e = tid; e < 16 * DH_; e += 256) {
    int r = e >> 6, d = e & 63;
    qlds[r][d] = ql[((size_t)bh * M_ + mt * 16 + r) * DH_ + d];
  }
  float acc[4] = {0, 0, 0, 0}, srun[4] = {0, 0, 0, 0}, mrun[4];
  #pragma unroll
  for (int r = 0; r < 4; r++) mrun[r] = -1e30f;
  const unsigned short* kbase = kb + (((size_t)bh * N_) << 6);
  const unsigned short* vbase = vb + (((size_t)bh * N_) << 6);
  __syncthreads();
  for (int n0 = 0; n0 < N_; n0 += 64) {
    __syncthreads();
    for (int e = tid * 4; e < 64 * 64; e += 1024) {
      int nn = e >> 6, d = e & 63;
      ushort4 k4 = *reinterpret_cast<const ushort4*>(&kbase[(((size_t)(n0 + nn)) << 6) + d]);
      ushort4 v4 = *reinterpret_cast<const ushort4*>(&vbase[(((size_t)(n0 + nn)) << 6) + d]);
      klds[nn][d] = bf2f(k4.x); klds[nn][d + 1] = bf2f(k4.y);
      klds[nn][d + 2] = bf2f(k4.z); klds[nn][d + 3] = bf2f(k4.w);
      vlds[nn][d] = bf2f(v4.x); vlds[nn][d + 1] = bf2f(v4.y);
      vlds[nn][d + 2] = bf2f(v4.z); vlds[nn][d + 3] = bf2f(v4.w);
    }
    __syncthreads();
    float s[4] = {0, 0, 0, 0};
    for (int d0 = 0; d0 < DH_; d0 += 16) {
      float kr[16];
      #pragma unroll
      for (int dd = 0; dd < 16; dd++) kr[dd] = klds[lane][d0 + dd];
      #pragma unroll
      for (int r = 0; r < 4; r++) {
        int rowq = wid * 4 + r;
        float a = 0;
        #pragma unroll
        for (int dd = 0; dd < 16; dd++) a += qlds[rowq][d0 + dd] * kr[dd];
        s[r] += a;
      }
    }
    #pragma unroll
    for (int r = 0; r < 4; r++) {
      float mx = s[r];
      #pragma unroll
      for (int off = 1; off < 64; off <<= 1) mx = fmaxf(mx, __shfl_xor(mx, off));
      float mnew = fmaxf(mrun[r], mx);
      float p = __expf(s[r] - mnew);
      float psum = p;
      #pragma unroll
      for (int off = 1; off < 64; off <<= 1) psum += __shfl_xor(psum, off);
      float corr = __expf(mrun[r] - mnew);
      srun[r] = srun[r] * corr + psum;
      acc[r] *= corr;
      mrun[r] = mnew;
      plds[wid][r][lane] = p;
    }
    __syncthreads();
    for (int j = 0; j < 64; j++) {
      float v = vlds[j][lane];
      #pragma unroll
      for (int r = 0; r < 4; r++) acc[r] += plds[wid][r][j] * v;
    }
  }
  #pragma unroll
  for (int r = 0; r < 4; r++)
    pv[((size_t)bh * M_ + mt * 16 + wid * 4 + r) * DH_ + lane] = acc[r] / srun[r];
}

// ---------------- convert kl -> bf16 and W2 -> bf16 transposed ----------------
__global__ __launch_bounds__(256) void cvt_small(const float* __restrict__ kl,
    const float* __restrict__ w2b, unsigned short* __restrict__ klb, unsigned short* __restrict__ w2t)
{
  int bh = blockIdx.x;
  size_t base = (size_t)bh << 14;   // 16384
  for (int e = threadIdx.x; e < M_ * DH_; e += 256) {
    klb[base + e] = f2bf(kl[base + e]);
    int m = e >> 6, dh = e & 63;
    w2t[base + (size_t)dh * M_ + m] = f2bf(w2b[base + e]);
  }
}

// ---------------- attn1: oh = softmax(q @ kl^T) @ W2 via MFMA ----------------
// block: 256 thr (4 waves), one bh, 256 q-rows (wave w, sub s -> rows sub*64+w*16)
__global__ __launch_bounds__(256) void attn1_kernel(
    const unsigned short* __restrict__ qb,   // [bh][n][64] bf16
    const unsigned short* __restrict__ klb,  // [bh][m][64] bf16
    const unsigned short* __restrict__ w2t,  // [bh][dh][m] bf16 (transposed)
    unsigned short* __restrict__ oh)         // [b][n][512] bf16
{
  int ntile = blockIdx.x & 31;
  int bh = blockIdx.x >> 5;
  int h = bh & (H_ - 1), b = bh >> 3;
  int tid = threadIdx.x, wid = tid >> 6, lane = tid & 63;
  int lr = lane & 15, lg = lane >> 4;
  __shared__ unsigned short plds_all[4][16][264];
  unsigned short* plds = &plds_all[wid][0][0];

  const unsigned short* qbh  = qb  + (((size_t)bh * N_) << 6);
  const unsigned short* klbh = klb + ((size_t)bh << 14);
  const unsigned short* w2bh = w2t + ((size_t)bh << 14);

  const f32x4 zf = {0.f, 0.f, 0.f, 0.f};
  for (int sub = 0; sub < 4; sub++) {
    int n0 = ntile * 256 + sub * 64 + wid * 16;
    // ---- A-fragments of q (16 rows x 64 d) ----
    bf16x8 aq0 = *reinterpret_cast<const bf16x8*>(&qbh[((size_t)(n0 + lr) << 6) + lg * 8]);
    bf16x8 aq1 = *reinterpret_cast<const bf16x8*>(&qbh[((size_t)(n0 + lr) << 6) + 32 + lg * 8]);
    // ---- S = q @ kl^T : 16 col-tiles of 16 ----
    f32x4 accs[16];
    #pragma unroll
    for (int mt = 0; mt < 16; mt++) {
      bf16x8 b0 = *reinterpret_cast<const bf16x8*>(&klbh[((size_t)(mt * 16 + lr) << 6) + lg * 8]);
      bf16x8 b1 = *reinterpret_cast<const bf16x8*>(&klbh[((size_t)(mt * 16 + lr) << 6) + 32 + lg * 8]);
      f32x4 a = __builtin_amdgcn_mfma_f32_16x16x32_bf16(aq0, b0, zf, 0, 0, 0);
      accs[mt] = __builtin_amdgcn_mfma_f32_16x16x32_bf16(aq1, b1, a, 0, 0, 0);
    }
    // ---- softmax over m (per row r: row = 4*lg + r, col = mt*16 + lr) ----
    float mx[4], rs[4];
    #pragma unroll
    for (int r = 0; r < 4; r++) {
      float m0 = accs[0][r];
      #pragma unroll
      for (int mt = 1; mt < 16; mt++) m0 = fmaxf(m0, accs[mt][r]);
      #pragma unroll
      for (int off = 1; off < 16; off <<= 1) m0 = fmaxf(m0, __shfl_xor(m0, off));
      mx[r] = m0;
      float s0 = 0.f;
      #pragma unroll
      for (int mt = 0; mt < 16; mt++) {
        float p = __expf(accs[mt][r] - m0);
        accs[mt][r] = p;
        s0 += p;
      }
      #pragma unroll
      for (int off = 1; off < 16; off <<= 1) s0 += __shfl_xor(s0, off);
      rs[r] = 1.f / s0;
    }
    // ---- P -> LDS (bf16) in A-fragment-friendly layout ----
    #pragma unroll
    for (int mt = 0; mt < 16; mt++)
      #pragma unroll
      for (int r = 0; r < 4; r++)
        plds[(4 * lg + r) * 264 + mt * 16 + lr] = f2bf(accs[mt][r]);
    __builtin_amdgcn_s_waitcnt(0);  // lgkm drain before re-read (same wave)
    // ---- A-fragments of P ----
    bf16x8 pa[8];
    #pragma unroll
    for (int mc = 0; mc < 8; mc++)
      pa[mc] = *reinterpret_cast<const bf16x8*>(&plds[lr * 264 + mc * 32 + lg * 8]);
    // ---- O = P @ W2 : 4 dh-tiles ----
    f32x4 acco[4];
    #pragma unroll
    for (int dt = 0; dt < 4; dt++) {
      f32x4 a = zf;
      #pragma unroll
      for (int mc = 0; mc < 8; mc++) {
        bf16x8 wf = *reinterpret_cast<const bf16x8*>(&w2bh[(size_t)(dt * 16 + lr) * M_ + mc * 32 + lg * 8]);
        a = __builtin_amdgcn_mfma_f32_16x16x32_bf16(pa[mc], wf, a, 0, 0, 0);
      }
      acco[dt] = a;
    }
    // ---- epilogue: divide by rowsum, store ----
    #pragma unroll
    for (int dt = 0; dt < 4; dt++)
      #pragma unroll
      for (int r = 0; r < 4; r++) {
        int n = n0 + 4 * lg + r;
        oh[((size_t)(b * N_ + n) << 9) + h * DH_ + dt * 16 + lr] = f2bf(acco[dt][r] * rs[r]);
      }
  }
}

// ---------------- depthwise conv residual: oh += conv(v) ----------------
__global__ __launch_bounds__(256) void conv_kernel(const unsigned short* __restrict__ vb,
    const float* __restrict__ rw, unsigned short* __restrict__ oh)
{
  long long idx = (long long)blockIdx.x * 256 + threadIdx.x;
  int c = (int)(idx & (INNER_ - 1));
  long long bn = idx >> 9;
  int n = (int)(bn & (N_ - 1));
  int b = (int)(bn >> 13);
  int h = c >> 6, d = c & 63;
  const unsigned short* vbb = vb + (((size_t)(b * H_ + h) * N_) << 6) + d;
  float acc = 0;
  #pragma unroll
  for (int j = 0; j < RESK_; j++) {
    int nn = n + j - RESK_ / 2;
    if (nn >= 0 && nn < N_) acc += rw[h * RESK_ + j] * bf2f(vbb[((size_t)nn) << 6]);
  }
  oh[idx] = f2bf(bf2f(oh[idx]) + acc);
}

// ---------------- final GEMM: out = oh(bf16) @ w_out + b_out + x ----------------
__global__ __launch_bounds__(256) void gemm_out(const unsigned short* __restrict__ oh,
    const float* __restrict__ wout, const float* __restrict__ bias,
    const float* __restrict__ resid, float* __restrict__ out)
{
  __shared__ float As[8][128];
  __shared__ float Bs[8][128];
  int tid = threadIdx.x;
  int bm = blockIdx.y * 128, bn = blockIdx.x * 128;
  int ty = tid >> 4, tx = tid & 15;
  int arow = (tid * 4) >> 3, akk = (tid * 4) & 7;
  int bkk = (tid * 4) >> 7, bcol = (tid * 4) & 127;
  float acc[8][8] = {};
  for (int k0 = 0; k0 < INNER_; k0 += 8) {
    ushort4 a4 = *reinterpret_cast<const ushort4*>(&oh[((size_t)(bm + arow) << 9) + k0 + akk]);
    float4 bv = *reinterpret_cast<const float4*>(&wout[(size_t)(k0 + bkk) * DIM_ + bn + bcol]);
    __syncthreads();
    As[akk + 0][arow] = bf2f(a4.x); As[akk + 1][arow] = bf2f(a4.y);
    As[akk + 2][arow] = bf2f(a4.z); As[akk + 3][arow] = bf2f(a4.w);
    *reinterpret_cast<float4*>(&Bs[bkk][bcol]) = bv;
    __syncthreads();
    #pragma unroll
    for (int kk = 0; kk < 8; kk++) {
      float ar[8], br[8];
      #pragma unroll
      for (int i = 0; i < 8; i++) ar[i] = As[kk][ty * 8 + i];
      #pragma unroll
      for (int j = 0; j < 8; j++) br[j] = Bs[kk][tx * 8 + j];
      #pragma unroll
      for (int i = 0; i < 8; i++)
        #pragma unroll
        for (int j = 0; j < 8; j++) acc[i][j] += ar[i] * br[j];
    }
  }
  for (int i = 0; i < 8; i++) {
    int r = bm + ty * 8 + i;
    int c0 = bn + tx * 8;
    float4 r0 = *reinterpret_cast<const float4*>(&resid[(size_t)r * DIM_ + c0]);
    float4 r1 = *reinterpret_cast<const float4*>(&resid[(size_t)r * DIM_ + c0 + 4]);
    float4 b0 = *reinterpret_cast<const float4*>(&bias[c0]);
    float4 b1 = *reinterpret_cast<const float4*>(&bias[c0 + 4]);
    float4 o0 = make_float4(acc[i][0] + b0.x + r0.x, acc[i][1] + b0.y + r0.y,
                            acc[i][2] + b0.z + r0.z, acc[i][3] + b0.w + r0.w);
    float4 o1 = make_float4(acc[i][4] + b1.x + r1.x, acc[i][5] + b1.y + r1.y,
                            acc[i][6] + b1.z + r1.z, acc[i][7] + b1.w + r1.w);
    *reinterpret_cast<float4*>(&out[(size_t)r * DIM_ + c0])     = o0;
    *reinterpret_cast<float4*>(&out[(size_t)r * DIM_ + c0 + 4]) = o1;
  }
}

extern "C" void kernel_launch(void* const* d_in, const int* in_sizes, int n_in,
                              void* d_out, int out_size, void* d_ws, size_t ws_size,
                              hipStream_t stream)
{
  const float* x     = (const float*)d_in[0];
  const float* ln_w  = (const float*)d_in[1];
  const float* ln_b  = (const float*)d_in[2];
  const float* w_qkv = (const float*)d_in[3];
  const float* w_out = (const float*)d_in[4];
  const float* b_out = (const float*)d_in[5];
  const float* res_w = (const float*)d_in[6];
  float* out = (float*)d_out;

  const size_t HEADEL = (size_t)B_ * H_ * N_ * DH_;     // 16,777,216
  const size_t SMALL  = (size_t)B_ * H_ * M_ * DH_;     // 524,288
  unsigned short* qb = (unsigned short*)d_ws;
  unsigned short* kb = qb + HEADEL;
  unsigned short* vb = kb + HEADEL;
  unsigned short* oh = vb + HEADEL;
  float* ql  = (float*)(oh + HEADEL);
  float* kl  = ql + SMALL;
  float* pvb = kl + SMALL;
  float* w2b = pvb + SMALL;
  unsigned short* klb = (unsigned short*)(w2b + SMALL);
  unsigned short* w2t = klb + SMALL;
  float2* stats = (float2*)(w2t + SMALL);               // B*N entries
  unsigned int* scal = (unsigned int*)(stats + (size_t)B_ * N_);
  size_t need = (size_t)((char*)(scal + 64) - (char*)d_ws);
  if (ws_size < need) return;

  const size_t SZ = (size_t)M_ * M_;
  float* a2 = (float*)d_out;
  float* z0 = a2 + (size_t)B_ * H_ * SZ;
  float* z1 = z0 + (size_t)B_ * H_ * SZ;
  float* z2 = z1 + (size_t)B_ * H_ * SZ;
  float* z3 = z2 + (size_t)B_ * H_ * SZ;

  ln_stats<<<B_ * N_, 256, 0, stream>>>(x, stats);
  gemm_qkv<<<dim3(K3_ / 128, (B_ * N_) / 128), 256, 0, stream>>>(
      x, stats, ln_w, ln_b, w_qkv, qb, kb, vb);
  landmark_kernel<<<B_ * H_ * M_, 64, 0, stream>>>(qb, kb, ql, kl);
  attn2_kernel<<<B_ * H_ * M_, 256, 0, stream>>>(ql, kl, a2);
  zero_scal<<<1, 2, 0, stream>>>(scal);
  pinv_scale_kernel<<<B_ * H_, 256, 0, stream>>>(a2, scal);
  zinit_kernel<<<B_ * H_, 256, 0, stream>>>(a2, scal, z0);
  pv_kernel<<<B_ * H_ * (M_ / 16), 256, 0, stream>>>(kb, vb, ql, pvb);

  const long long SZL = (long long)SZ;
  float* cur = z0; float* u = z1; float* vv = z2; float* wb = z3;
  for (int it = 0; it < 6; it++) {
    bgemm64<<<dim3(4, 4, B_ * H_), 256, 0, stream>>>(a2, cur, u, M_, M_, SZL, SZL, SZL, 0.f, 1.f, 0);
    bgemm64<<<dim3(4, 4, B_ * H_), 256, 0, stream>>>(u, u, vv, M_, M_, SZL, SZL, SZL, 7.f, 1.f, 1);
    bgemm64<<<dim3(4, 4, B_ * H_), 256, 0, stream>>>(u, vv, wb, M_, M_, SZL, SZL, SZL, 15.f, 1.f, 1);
    bgemm64<<<dim3(4, 4, B_ * H_), 256, 0, stream>>>(cur, wb, u, M_, M_, SZL, SZL, SZL, 13.f, 0.25f, 1);
    float* oc = cur; cur = u; u = vv; vv = wb; wb = oc;
  }

  bgemm64<<<dim3(1, 4, B_ * H_), 256, 0, stream>>>(cur, pvb, w2b, DH_, M_,
      SZL, (long long)M_ * DH_, (long long)M_ * DH_, 0.f, 1.f, 0);

  cvt_small<<<B_ * H_, 256, 0, stream>>>(kl, w2b, klb, w2t);
  attn1_kernel<<<B_ * H_ * (N_ / 256), 256, 0, stream>>>(qb, klb, w2t, oh);
  conv_kernel<<<(int)(((long long)B_ * N_ * INNER_) / 256), 256, 0, stream>>>(vb, res_w, oh);
  gemm_out<<<dim3(DIM_ / 128, (B_ * N_) / 128), 256, 0, stream>>>(oh, w_out, b_out, x, out);
}

// Round 4
// 1919.305 us; speedup vs baseline: 2.6902x; 1.3828x over previous
//
#include <hip/hip_runtime.h>
#include <cstdint>

#define B_ 4
#define N_ 8192
#define DIM_ 512
#define H_ 8
#define DH_ 64
#define M_ 256
#define L_ 32
#define INNER_ 512
#define K3_ 1536
#define RESK_ 33

struct __align__(16) ushort8_t { unsigned short u[8]; };
typedef short bf16x8 __attribute__((ext_vector_type(8)));
typedef float f32x4 __attribute__((ext_vector_type(4)));

__device__ __forceinline__ float bf2f(unsigned short u) {
  return __uint_as_float(((unsigned)u) << 16);
}
__device__ __forceinline__ unsigned short f2bf(float f) {
  unsigned x = __float_as_uint(f);
  return (unsigned short)((x + 0x7fffu + ((x >> 16) & 1u)) >> 16);  // RNE
}

// ---------------- LayerNorm row stats: mu, rsigma ----------------
__global__ __launch_bounds__(256) void ln_stats(const float* __restrict__ x,
                                                float2* __restrict__ st)
{
  int row = blockIdx.x;
  int tid = threadIdx.x;
  float2 v = reinterpret_cast<const float2*>(x + (size_t)row * DIM_)[tid];
  float s = v.x + v.y, s2 = v.x * v.x + v.y * v.y;
  #pragma unroll
  for (int off = 32; off; off >>= 1) { s += __shfl_down(s, off); s2 += __shfl_down(s2, off); }
  __shared__ float rs[4], rs2[4];
  int wid = tid >> 6, lane = tid & 63;
  if (lane == 0) { rs[wid] = s; rs2[wid] = s2; }
  __syncthreads();
  if (tid == 0) {
    float ts = rs[0] + rs[1] + rs[2] + rs[3];
    float ts2 = rs2[0] + rs2[1] + rs2[2] + rs2[3];
    float mu = ts * (1.f / DIM_);
    float var = ts2 * (1.f / DIM_) - mu * mu;
    st[row] = make_float2(mu, rsqrtf(var + 1e-5f));
  }
}

// ---------------- QKV GEMM with fused LN on A, bf16 head-major scatter out ----------------
__global__ __launch_bounds__(256) void gemm_qkv(const float* __restrict__ x,
    const float2* __restrict__ st, const float* __restrict__ lnw, const float* __restrict__ lnb,
    const float* __restrict__ wqkv,
    unsigned short* __restrict__ qb, unsigned short* __restrict__ kb, unsigned short* __restrict__ vb)
{
  __shared__ float As[8][128];
  __shared__ float Bs[8][128];
  int tid = threadIdx.x;
  int bm = blockIdx.y * 128, bn = blockIdx.x * 128;
  int ty = tid >> 4, tx = tid & 15;
  int arow = (tid * 4) >> 3, akk = (tid * 4) & 7;
  int bkk = (tid * 4) >> 7, bcol = (tid * 4) & 127;
  float2 stv = st[bm + arow];
  float acc[8][8] = {};
  for (int k0 = 0; k0 < DIM_; k0 += 8) {
    float4 av = *reinterpret_cast<const float4*>(&x[(size_t)(bm + arow) * DIM_ + k0 + akk]);
    float4 wv = *reinterpret_cast<const float4*>(&lnw[k0 + akk]);
    float4 bv2 = *reinterpret_cast<const float4*>(&lnb[k0 + akk]);
    av.x = (av.x - stv.x) * stv.y * wv.x + bv2.x;
    av.y = (av.y - stv.x) * stv.y * wv.y + bv2.y;
    av.z = (av.z - stv.x) * stv.y * wv.z + bv2.z;
    av.w = (av.w - stv.x) * stv.y * wv.w + bv2.w;
    float4 bv = *reinterpret_cast<const float4*>(&wqkv[(size_t)(k0 + bkk) * K3_ + bn + bcol]);
    __syncthreads();
    As[akk + 0][arow] = av.x; As[akk + 1][arow] = av.y;
    As[akk + 2][arow] = av.z; As[akk + 3][arow] = av.w;
    *reinterpret_cast<float4*>(&Bs[bkk][bcol]) = bv;
    __syncthreads();
    #pragma unroll
    for (int kk = 0; kk < 8; kk++) {
      float ar[8], br[8];
      #pragma unroll
      for (int i = 0; i < 8; i++) ar[i] = As[kk][ty * 8 + i];
      #pragma unroll
      for (int j = 0; j < 8; j++) br[j] = Bs[kk][tx * 8 + j];
      #pragma unroll
      for (int i = 0; i < 8; i++)
        #pragma unroll
        for (int j = 0; j < 8; j++) acc[i][j] += ar[i] * br[j];
    }
  }
  int c0 = bn + tx * 8;
  int which = c0 >> 9;
  int hh = (c0 >> 6) & (H_ - 1);
  int d0 = c0 & 63;
  unsigned short* dst = which == 0 ? qb : (which == 1 ? kb : vb);
  float qs = which == 0 ? 0.125f : 1.0f;
  for (int i = 0; i < 8; i++) {
    int r = bm + ty * 8 + i;
    int b = r >> 13, n = r & (N_ - 1);
    ushort8_t pk;
    #pragma unroll
    for (int j = 0; j < 8; j++) pk.u[j] = f2bf(acc[i][j] * qs);
    *reinterpret_cast<ushort8_t*>(&dst[(((size_t)(b * H_ + hh) * N_ + n) << 6) + d0]) = pk;
  }
}

// ---------------- landmark means (also emits bf16 q_l) ----------------
__global__ __launch_bounds__(64) void landmark_kernel(const unsigned short* __restrict__ qb,
    const unsigned short* __restrict__ kb, float* __restrict__ ql, float* __restrict__ kl,
    unsigned short* __restrict__ qlb)
{
  int id = blockIdx.x;
  int m = id & (M_ - 1);
  int bh = id >> 8;
  int d = threadIdx.x;
  size_t base = (((size_t)bh * N_ + m * L_) << 6) + d;
  float sq = 0, sk = 0;
  #pragma unroll 4
  for (int j = 0; j < L_; j++) {
    sq += bf2f(qb[base + ((size_t)j << 6)]);
    sk += bf2f(kb[base + ((size_t)j << 6)]);
  }
  float qv = sq * (1.f / L_);
  ql[((size_t)bh * M_ + m) * DH_ + d] = qv;
  kl[((size_t)bh * M_ + m) * DH_ + d] = sk * (1.f / L_);
  qlb[((size_t)bh * M_ + m) * DH_ + d] = f2bf(qv);
}

// ---------------- sim2 + softmax -> attn2 ----------------
__global__ __launch_bounds__(256) void attn2_kernel(const float* __restrict__ ql,
    const float* __restrict__ kl, float* __restrict__ a2)
{
  int id = blockIdx.x;
  int i = id & (M_ - 1);
  int bh = id >> 8;
  int j = threadIdx.x;
  __shared__ float qs[DH_];
  __shared__ float wred[4];
  if (j < DH_) qs[j] = ql[((size_t)bh * M_ + i) * DH_ + j];
  __syncthreads();
  const float* krow = kl + ((size_t)bh * M_ + j) * DH_;
  float s = 0;
  #pragma unroll
  for (int d = 0; d < DH_; d++) s += qs[d] * krow[d];
  float mx = s;
  #pragma unroll
  for (int off = 1; off < 64; off <<= 1) mx = fmaxf(mx, __shfl_xor(mx, off));
  int wid = j >> 6, lane = j & 63;
  if (lane == 0) wred[wid] = mx;
  __syncthreads();
  mx = fmaxf(fmaxf(wred[0], wred[1]), fmaxf(wred[2], wred[3]));
  float e = __expf(s - mx);
  float sum = e;
  #pragma unroll
  for (int off = 1; off < 64; off <<= 1) sum += __shfl_xor(sum, off);
  __syncthreads();
  if (lane == 0) wred[wid] = sum;
  __syncthreads();
  sum = wred[0] + wred[1] + wred[2] + wred[3];
  a2[((size_t)bh * M_ + i) * M_ + j] = e / sum;
}

// ---------------- pinv scale ----------------
__global__ void zero_scal(unsigned int* scal) { scal[threadIdx.x] = 0u; }

__global__ __launch_bounds__(256) void pinv_scale_kernel(const float* __restrict__ a2,
    unsigned int* __restrict__ scal)
{
  int bh = blockIdx.x;
  int t = threadIdx.x;
  const float* xb = a2 + (size_t)bh * M_ * M_;
  float rowsum = 0, colsum = 0;
  for (int j = 0; j < M_; j++) {
    rowsum += xb[(size_t)t * M_ + j];
    colsum += xb[(size_t)j * M_ + t];
  }
  #pragma unroll
  for (int off = 1; off < 64; off <<= 1) {
    rowsum = fmaxf(rowsum, __shfl_xor(rowsum, off));
    colsum = fmaxf(colsum, __shfl_xor(colsum, off));
  }
  __shared__ float wr[4], wc[4];
  int wid = t >> 6, lane = t & 63;
  if (lane == 0) { wr[wid] = rowsum; wc[wid] = colsum; }
  __syncthreads();
  if (t == 0) {
    float rm = fmaxf(fmaxf(wr[0], wr[1]), fmaxf(wr[2], wr[3]));
    float cm = fmaxf(fmaxf(wc[0], wc[1]), fmaxf(wc[2], wc[3]));
    atomicMax(&scal[0], __float_as_uint(rm));
    atomicMax(&scal[1], __float_as_uint(cm));
  }
}

__global__ __launch_bounds__(256) void zinit_kernel(const float* __restrict__ a2,
    const unsigned int* __restrict__ scal, float* __restrict__ z)
{
  int bh = blockIdx.x;
  int j = threadIdx.x;
  float inv = 1.f / (__uint_as_float(scal[0]) * __uint_as_float(scal[1]));
  const float* xb = a2 + (size_t)bh * M_ * M_;
  float* zr = z + (size_t)bh * M_ * M_ + (size_t)j * M_;
  for (int i = 0; i < M_; i++) zr[i] = xb[(size_t)i * M_ + j] * inv;
}

// ---------------- batched 64x64x16 SGEMM ----------------
__global__ __launch_bounds__(256) void bgemm64(const float* __restrict__ A,
    const float* __restrict__ Bm, float* __restrict__ C, int Nc, int Kd,
    long long sA, long long sB, long long sC, float aI, float scale, int useI)
{
  __shared__ float As[16][64];
  __shared__ float Bs[16][64];
  int batch = blockIdx.z;
  const float* Ab = A + (size_t)batch * sA;
  const float* Bb = Bm + (size_t)batch * sB;
  float* Cb = C + (size_t)batch * sC;
  int bm = blockIdx.y * 64, bn = blockIdx.x * 64;
  int tid = threadIdx.x;
  int ty = tid >> 4, tx = tid & 15;
  int arow = (tid * 4) >> 4, akk = (tid * 4) & 15;
  int bkk = (tid * 4) >> 6, bcol = (tid * 4) & 63;
  float acc[4][4] = {};
  for (int k0 = 0; k0 < Kd; k0 += 16) {
    float4 av = *reinterpret_cast<const float4*>(&Ab[(size_t)(bm + arow) * Kd + k0 + akk]);
    float4 bv = *reinterpret_cast<const float4*>(&Bb[(size_t)(k0 + bkk) * Nc + bn + bcol]);
    if (useI) {
      int kr = k0 + bkk, cc = bn + bcol;
      bv.x = (kr == cc + 0 ? aI : 0.f) - bv.x;
      bv.y = (kr == cc + 1 ? aI : 0.f) - bv.y;
      bv.z = (kr == cc + 2 ? aI : 0.f) - bv.z;
      bv.w = (kr == cc + 3 ? aI : 0.f) - bv.w;
    }
    __syncthreads();
    As[akk + 0][arow] = av.x; As[akk + 1][arow] = av.y;
    As[akk + 2][arow] = av.z; As[akk + 3][arow] = av.w;
    *reinterpret_cast<float4*>(&Bs[bkk][bcol]) = bv;
    __syncthreads();
    #pragma unroll
    for (int kk = 0; kk < 16; kk++) {
      float ar[4], br[4];
      #pragma unroll
      for (int i = 0; i < 4; i++) ar[i] = As[kk][ty * 4 + i];
      #pragma unroll
      for (int j = 0; j < 4; j++) br[j] = Bs[kk][tx * 4 + j];
      #pragma unroll
      for (int i = 0; i < 4; i++)
        #pragma unroll
        for (int j = 0; j < 4; j++) acc[i][j] += ar[i] * br[j];
    }
  }
  for (int i = 0; i < 4; i++)
    #pragma unroll
    for (int j = 0; j < 4; j++)
      Cb[(size_t)(bm + ty * 4 + i) * Nc + bn + tx * 4 + j] = scale * acc[i][j];
}

// ---------------- pv partials: softmax(q_l @ k^T) @ v via MFMA, split over N ----------------
// grid: (8 slices, 2 msplit, 32 bh); 256 thr = 4 waves x 32 landmark rows; chunk = 64 keys.
__global__ __launch_bounds__(256) void pv_mfma(
    const unsigned short* __restrict__ kb, const unsigned short* __restrict__ vb,
    const unsigned short* __restrict__ qlb,
    float* __restrict__ pvpart, float2* __restrict__ msbuf)
{
  int slice = blockIdx.x;
  int msp   = blockIdx.y;
  int bh    = blockIdx.z;
  int tid = threadIdx.x, wid = tid >> 6, lane = tid & 63;
  int lr = lane & 15, lg = lane >> 4;

  __shared__ unsigned short klds[64][72];
  __shared__ unsigned short vtld[64][72];
  __shared__ unsigned short plds_all[4][32][72];
  unsigned short (*plds)[72] = plds_all[wid];

  int mbase = msp * 128 + wid * 32;
  const unsigned short* qbase = qlb + (((size_t)bh * M_ + mbase) << 6);
  bf16x8 qf[2][2];
  #pragma unroll
  for (int rt = 0; rt < 2; rt++)
    #pragma unroll
    for (int h2 = 0; h2 < 2; h2++)
      qf[rt][h2] = *reinterpret_cast<const bf16x8*>(&qbase[((rt * 16 + lr) << 6) + h2 * 32 + lg * 8]);

  const f32x4 zf = {0.f, 0.f, 0.f, 0.f};
  f32x4 oacc[2][4];
  #pragma unroll
  for (int rt = 0; rt < 2; rt++)
    #pragma unroll
    for (int dt = 0; dt < 4; dt++) oacc[rt][dt] = zf;
  float mrun[8], srun[8];
  #pragma unroll
  for (int i = 0; i < 8; i++) { mrun[i] = -1e30f; srun[i] = 0.f; }

  const unsigned short* kgb = kb + (((size_t)bh * N_ + slice * 1024) << 6);
  const unsigned short* vgb = vb + (((size_t)bh * N_ + slice * 1024) << 6);

  for (int c = 0; c < 16; c++) {
    __syncthreads();
    // ---- stage k (row-major padded) and v (transposed, XOR-swizzled cols) ----
    for (int u = tid; u < 512; u += 256) {
      int key = u >> 3, seg = u & 7;
      size_t goff = (((size_t)(c * 64 + key)) << 6) + seg * 8;
      bf16x8 kv = *reinterpret_cast<const bf16x8*>(&kgb[goff]);
      *reinterpret_cast<bf16x8*>(&klds[key][seg * 8]) = kv;
      bf16x8 vv = *reinterpret_cast<const bf16x8*>(&vgb[goff]);
      int col = key ^ (seg << 3);
      #pragma unroll
      for (int j = 0; j < 8; j++) vtld[seg * 8 + j][col] = (unsigned short)vv[j];
    }
    __syncthreads();
    // ---- S = q_l @ k^T ----
    f32x4 sacc[2][4];
    #pragma unroll
    for (int rt = 0; rt < 2; rt++)
      #pragma unroll
      for (int ct = 0; ct < 4; ct++) {
        bf16x8 b0 = *reinterpret_cast<const bf16x8*>(&klds[ct * 16 + lr][lg * 8]);
        bf16x8 b1 = *reinterpret_cast<const bf16x8*>(&klds[ct * 16 + lr][32 + lg * 8]);
        f32x4 a = __builtin_amdgcn_mfma_f32_16x16x32_bf16(qf[rt][0], b0, zf, 0, 0, 0);
        sacc[rt][ct] = __builtin_amdgcn_mfma_f32_16x16x32_bf16(qf[rt][1], b1, a, 0, 0, 0);
      }
    // ---- online softmax (rows: rt*16 + 4*lg + r; cols: ct*16 + lr) ----
    #pragma unroll
    for (int rt = 0; rt < 2; rt++)
      #pragma unroll
      for (int r = 0; r < 4; r++) {
        int ri = rt * 4 + r;
        float mc = fmaxf(fmaxf(sacc[rt][0][r], sacc[rt][1][r]), fmaxf(sacc[rt][2][r], sacc[rt][3][r]));
        #pragma unroll
        for (int off = 1; off < 16; off <<= 1) mc = fmaxf(mc, __shfl_xor(mc, off));
        float mnew = fmaxf(mrun[ri], mc);
        float corr = __expf(mrun[ri] - mnew);
        float psum = 0.f;
        #pragma unroll
        for (int ct = 0; ct < 4; ct++) {
          float p = __expf(sacc[rt][ct][r] - mnew);
          sacc[rt][ct][r] = p;
          psum += p;
        }
        #pragma unroll
        for (int off = 1; off < 16; off <<= 1) psum += __shfl_xor(psum, off);
        srun[ri] = srun[ri] * corr + psum;
        mrun[ri] = mnew;
        #pragma unroll
        for (int dt = 0; dt < 4; dt++) oacc[rt][dt][r] *= corr;
        #pragma unroll
        for (int ct = 0; ct < 4; ct++)
          plds[rt * 16 + 4 * lg + r][ct * 16 + lr] = f2bf(sacc[rt][ct][r]);
      }
    __builtin_amdgcn_s_waitcnt(0);  // per-wave LDS roundtrip (attn1-proven pattern)
    // ---- A-frags of P ----
    bf16x8 pa[2][2];
    #pragma unroll
    for (int rt = 0; rt < 2; rt++)
      #pragma unroll
      for (int h = 0; h < 2; h++)
        pa[rt][h] = *reinterpret_cast<const bf16x8*>(&plds[rt * 16 + lr][h * 32 + lg * 8]);
    // ---- O += P @ V ----
    #pragma unroll
    for (int dt = 0; dt < 4; dt++) {
      int d = dt * 16 + lr;
      bf16x8 bv0 = *reinterpret_cast<const bf16x8*>(&vtld[d][(lg * 8) ^ (d & 0x38)]);
      bf16x8 bv1 = *reinterpret_cast<const bf16x8*>(&vtld[d][(32 + lg * 8) ^ (d & 0x38)]);
      #pragma unroll
      for (int rt = 0; rt < 2; rt++) {
        oacc[rt][dt] = __builtin_amdgcn_mfma_f32_16x16x32_bf16(pa[rt][0], bv0, oacc[rt][dt], 0, 0, 0);
        oacc[rt][dt] = __builtin_amdgcn_mfma_f32_16x16x32_bf16(pa[rt][1], bv1, oacc[rt][dt], 0, 0, 0);
      }
    }
  }
  // ---- store partials (un-normalized O, plus per-row m,s) ----
  size_t pbase = (((size_t)(bh * 8 + slice) * M_ + mbase) << 6);
  #pragma unroll
  for (int rt = 0; rt < 2; rt++)
    #pragma unroll
    for (int dt = 0; dt < 4; dt++)
      #pragma unroll
      for (int r = 0; r < 4; r++)
        pvpart[pbase + ((size_t)(rt * 16 + 4 * lg + r) << 6) + dt * 16 + lr] = oacc[rt][dt][r];
  if (lr == 0) {
    #pragma unroll
    for (int rt = 0; rt < 2; rt++)
      #pragma unroll
      for (int r = 0; r < 4; r++)
        msbuf[(size_t)(bh * 8 + slice) * M_ + mbase + rt * 16 + 4 * lg + r] =
            make_float2(mrun[rt * 4 + r], srun[rt * 4 + r]);
  }
}

// ---------------- combine split-N partials ----------------
__global__ __launch_bounds__(256) void pv_combine(const float* __restrict__ pvpart,
    const float2* __restrict__ msbuf, float* __restrict__ pvb)
{
  int row = blockIdx.x * 4 + (threadIdx.x >> 6);  // over 32*256 rows
  int bh = row >> 8, m = row & (M_ - 1);
  int d = threadIdx.x & 63;
  float2 ms[8];
  float mg = -1e30f;
  #pragma unroll
  for (int s = 0; s < 8; s++) {
    ms[s] = msbuf[(size_t)(bh * 8 + s) * M_ + m];
    mg = fmaxf(mg, ms[s].x);
  }
  float ssum = 0.f, o = 0.f;
  #pragma unroll
  for (int s = 0; s < 8; s++) {
    float w = __expf(ms[s].x - mg);
    ssum += ms[s].y * w;
    o += w * pvpart[(((size_t)(bh * 8 + s) * M_ + m) << 6) + d];
  }
  pvb[(((size_t)bh * M_ + m) << 6) + d] = o / ssum;
}

// ---------------- convert kl -> bf16 and W2 -> bf16 transposed ----------------
__global__ __launch_bounds__(256) void cvt_small(const float* __restrict__ kl,
    const float* __restrict__ w2b, unsigned short* __restrict__ klb, unsigned short* __restrict__ w2t)
{
  int bh = blockIdx.x;
  size_t base = (size_t)bh << 14;
  for (int e = threadIdx.x; e < M_ * DH_; e += 256) {
    klb[base + e] = f2bf(kl[base + e]);
    int m = e >> 6, dh = e & 63;
    w2t[base + (size_t)dh * M_ + m] = f2bf(w2b[base + e]);
  }
}

// ---------------- attn1: oh = softmax(q @ kl^T) @ W2 via MFMA ----------------
__global__ __launch_bounds__(256) void attn1_kernel(
    const unsigned short* __restrict__ qb,
    const unsigned short* __restrict__ klb,
    const unsigned short* __restrict__ w2t,
    unsigned short* __restrict__ oh)
{
  int ntile = blockIdx.x & 31;
  int bh = blockIdx.x >> 5;
  int h = bh & (H_ - 1), b = bh >> 3;
  int tid = threadIdx.x, wid = tid >> 6, lane = tid & 63;
  int lr = lane & 15, lg = lane >> 4;
  __shared__ unsigned short plds_all[4][16][264];
  unsigned short* plds = &plds_all[wid][0][0];

  const unsigned short* qbh  = qb  + (((size_t)bh * N_) << 6);
  const unsigned short* klbh = klb + ((size_t)bh << 14);
  const unsigned short* w2bh = w2t + ((size_t)bh << 14);

  const f32x4 zf = {0.f, 0.f, 0.f, 0.f};
  for (int sub = 0; sub < 4; sub++) {
    int n0 = ntile * 256 + sub * 64 + wid * 16;
    bf16x8 aq0 = *reinterpret_cast<const bf16x8*>(&qbh[((size_t)(n0 + lr) << 6) + lg * 8]);
    bf16x8 aq1 = *reinterpret_cast<const bf16x8*>(&qbh[((size_t)(n0 + lr) << 6) + 32 + lg * 8]);
    f32x4 accs[16];
    #pragma unroll
    for (int mt = 0; mt < 16; mt++) {
      bf16x8 b0 = *reinterpret_cast<const bf16x8*>(&klbh[((size_t)(mt * 16 + lr) << 6) + lg * 8]);
      bf16x8 b1 = *reinterpret_cast<const bf16x8*>(&klbh[((size_t)(mt * 16 + lr) << 6) + 32 + lg * 8]);
      f32x4 a = __builtin_amdgcn_mfma_f32_16x16x32_bf16(aq0, b0, zf, 0, 0, 0);
      accs[mt] = __builtin_amdgcn_mfma_f32_16x16x32_bf16(aq1, b1, a, 0, 0, 0);
    }
    float rs[4];
    #pragma unroll
    for (int r = 0; r < 4; r++) {
      float m0 = accs[0][r];
      #pragma unroll
      for (int mt = 1; mt < 16; mt++) m0 = fmaxf(m0, accs[mt][r]);
      #pragma unroll
      for (int off = 1; off < 16; off <<= 1) m0 = fmaxf(m0, __shfl_xor(m0, off));
      float s0 = 0.f;
      #pragma unroll
      for (int mt = 0; mt < 16; mt++) {
        float p = __expf(accs[mt][r] - m0);
        accs[mt][r] = p;
        s0 += p;
      }
      #pragma unroll
      for (int off = 1; off < 16; off <<= 1) s0 += __shfl_xor(s0, off);
      rs[r] = 1.f / s0;
    }
    #pragma unroll
    for (int mt = 0; mt < 16; mt++)
      #pragma unroll
      for (int r = 0; r < 4; r++)
        plds[(4 * lg + r) * 264 + mt * 16 + lr] = f2bf(accs[mt][r]);
    __builtin_amdgcn_s_waitcnt(0);
    bf16x8 pa[8];
    #pragma unroll
    for (int mc = 0; mc < 8; mc++)
      pa[mc] = *reinterpret_cast<const bf16x8*>(&plds[lr * 264 + mc * 32 + lg * 8]);
    f32x4 acco[4];
    #pragma unroll
    for (int dt = 0; dt < 4; dt++) {
      f32x4 a = zf;
      #pragma unroll
      for (int mc = 0; mc < 8; mc++) {
        bf16x8 wf = *reinterpret_cast<const bf16x8*>(&w2bh[(size_t)(dt * 16 + lr) * M_ + mc * 32 + lg * 8]);
        a = __builtin_amdgcn_mfma_f32_16x16x32_bf16(pa[mc], wf, a, 0, 0, 0);
      }
      acco[dt] = a;
    }
    #pragma unroll
    for (int dt = 0; dt < 4; dt++)
      #pragma unroll
      for (int r = 0; r < 4; r++) {
        int n = n0 + 4 * lg + r;
        oh[((size_t)(b * N_ + n) << 9) + h * DH_ + dt * 16 + lr] = f2bf(acco[dt][r] * rs[r]);
      }
  }
}

// ---------------- depthwise conv residual: oh += conv(v) ----------------
__global__ __launch_bounds__(256) void conv_kernel(const unsigned short* __restrict__ vb,
    const float* __restrict__ rw, unsigned short* __restrict__ oh)
{
  long long idx = (long long)blockIdx.x * 256 + threadIdx.x;
  int c = (int)(idx & (INNER_ - 1));
  long long bn = idx >> 9;
  int n = (int)(bn & (N_ - 1));
  int b = (int)(bn >> 13);
  int h = c >> 6, d = c & 63;
  const unsigned short* vbb = vb + (((size_t)(b * H_ + h) * N_) << 6) + d;
  float acc = 0;
  #pragma unroll
  for (int j = 0; j < RESK_; j++) {
    int nn = n + j - RESK_ / 2;
    if (nn >= 0 && nn < N_) acc += rw[h * RESK_ + j] * bf2f(vbb[((size_t)nn) << 6]);
  }
  oh[idx] = f2bf(bf2f(oh[idx]) + acc);
}

// ---------------- final GEMM: out = oh(bf16) @ w_out + b_out + x ----------------
__global__ __launch_bounds__(256) void gemm_out(const unsigned short* __restrict__ oh,
    const float* __restrict__ wout, const float* __restrict__ bias,
    const float* __restrict__ resid, float* __restrict__ out)
{
  __shared__ float As[8][128];
  __shared__ float Bs[8][128];
  int tid = threadIdx.x;
  int bm = blockIdx.y * 128, bn = blockIdx.x * 128;
  int ty = tid >> 4, tx = tid & 15;
  int arow = (tid * 4) >> 3, akk = (tid * 4) & 7;
  int bkk = (tid * 4) >> 7, bcol = (tid * 4) & 127;
  float acc[8][8] = {};
  for (int k0 = 0; k0 < INNER_; k0 += 8) {
    ushort4 a4 = *reinterpret_cast<const ushort4*>(&oh[((size_t)(bm + arow) << 9) + k0 + akk]);
    float4 bv = *reinterpret_cast<const float4*>(&wout[(size_t)(k0 + bkk) * DIM_ + bn + bcol]);
    __syncthreads();
    As[akk + 0][arow] = bf2f(a4.x); As[akk + 1][arow] = bf2f(a4.y);
    As[akk + 2][arow] = bf2f(a4.z); As[akk + 3][arow] = bf2f(a4.w);
    *reinterpret_cast<float4*>(&Bs[bkk][bcol]) = bv;
    __syncthreads();
    #pragma unroll
    for (int kk = 0; kk < 8; kk++) {
      float ar[8], br[8];
      #pragma unroll
      for (int i = 0; i < 8; i++) ar[i] = As[kk][ty * 8 + i];
      #pragma unroll
      for (int j = 0; j < 8; j++) br[j] = Bs[kk][tx * 8 + j];
      #pragma unroll
      for (int i = 0; i < 8; i++)
        #pragma unroll
        for (int j = 0; j < 8; j++) acc[i][j] += ar[i] * br[j];
    }
  }
  for (int i = 0; i < 8; i++) {
    int r = bm + ty * 8 + i;
    int c0 = bn + tx * 8;
    float4 r0 = *reinterpret_cast<const float4*>(&resid[(size_t)r * DIM_ + c0]);
    float4 r1 = *reinterpret_cast<const float4*>(&resid[(size_t)r * DIM_ + c0 + 4]);
    float4 b0 = *reinterpret_cast<const float4*>(&bias[c0]);
    float4 b1 = *reinterpret_cast<const float4*>(&bias[c0 + 4]);
    float4 o0 = make_float4(acc[i][0] + b0.x + r0.x, acc[i][1] + b0.y + r0.y,
                            acc[i][2] + b0.z + r0.z, acc[i][3] + b0.w + r0.w);
    float4 o1 = make_float4(acc[i][4] + b1.x + r1.x, acc[i][5] + b1.y + r1.y,
                            acc[i][6] + b1.z + r1.z, acc[i][7] + b1.w + r1.w);
    *reinterpret_cast<float4*>(&out[(size_t)r * DIM_ + c0])     = o0;
    *reinterpret_cast<float4*>(&out[(size_t)r * DIM_ + c0 + 4]) = o1;
  }
}

extern "C" void kernel_launch(void* const* d_in, const int* in_sizes, int n_in,
                              void* d_out, int out_size, void* d_ws, size_t ws_size,
                              hipStream_t stream)
{
  const float* x     = (const float*)d_in[0];
  const float* ln_w  = (const float*)d_in[1];
  const float* ln_b  = (const float*)d_in[2];
  const float* w_qkv = (const float*)d_in[3];
  const float* w_out = (const float*)d_in[4];
  const float* b_out = (const float*)d_in[5];
  const float* res_w = (const float*)d_in[6];
  float* out = (float*)d_out;

  const size_t HEADEL = (size_t)B_ * H_ * N_ * DH_;     // 16,777,216
  const size_t SMALL  = (size_t)B_ * H_ * M_ * DH_;     // 524,288
  unsigned short* qb = (unsigned short*)d_ws;
  unsigned short* kb = qb + HEADEL;
  unsigned short* vb = kb + HEADEL;
  unsigned short* oh = vb + HEADEL;
  float* ql  = (float*)(oh + HEADEL);
  float* kl  = ql + SMALL;
  float* pvb = kl + SMALL;
  float* w2b = pvb + SMALL;
  unsigned short* klb = (unsigned short*)(w2b + SMALL);
  unsigned short* w2t = klb + SMALL;
  unsigned short* qlb = w2t + SMALL;
  float* pvpart = (float*)(qlb + SMALL);                         // 32*8*256*64 f32
  float2* msbuf = (float2*)(pvpart + (size_t)B_ * H_ * 8 * M_ * DH_);  // 32*8*256
  float2* stats = (float2*)(msbuf + (size_t)B_ * H_ * 8 * M_);
  unsigned int* scal = (unsigned int*)(stats + (size_t)B_ * N_);
  size_t need = (size_t)((char*)(scal + 64) - (char*)d_ws);
  if (ws_size < need) return;

  const size_t SZ = (size_t)M_ * M_;
  float* a2 = (float*)d_out;
  float* z0 = a2 + (size_t)B_ * H_ * SZ;
  float* z1 = z0 + (size_t)B_ * H_ * SZ;
  float* z2 = z1 + (size_t)B_ * H_ * SZ;
  float* z3 = z2 + (size_t)B_ * H_ * SZ;

  ln_stats<<<B_ * N_, 256, 0, stream>>>(x, stats);
  gemm_qkv<<<dim3(K3_ / 128, (B_ * N_) / 128), 256, 0, stream>>>(
      x, stats, ln_w, ln_b, w_qkv, qb, kb, vb);
  landmark_kernel<<<B_ * H_ * M_, 64, 0, stream>>>(qb, kb, ql, kl, qlb);
  attn2_kernel<<<B_ * H_ * M_, 256, 0, stream>>>(ql, kl, a2);
  zero_scal<<<1, 2, 0, stream>>>(scal);
  pinv_scale_kernel<<<B_ * H_, 256, 0, stream>>>(a2, scal);
  zinit_kernel<<<B_ * H_, 256, 0, stream>>>(a2, scal, z0);
  pv_mfma<<<dim3(8, 2, B_ * H_), 256, 0, stream>>>(kb, vb, qlb, pvpart, msbuf);
  pv_combine<<<(B_ * H_ * M_) / 4, 256, 0, stream>>>(pvpart, msbuf, pvb);

  const long long SZL = (long long)SZ;
  float* cur = z0; float* u = z1; float* vv = z2; float* wb = z3;
  for (int it = 0; it < 6; it++) {
    bgemm64<<<dim3(4, 4, B_ * H_), 256, 0, stream>>>(a2, cur, u, M_, M_, SZL, SZL, SZL, 0.f, 1.f, 0);
    bgemm64<<<dim3(4, 4, B_ * H_), 256, 0, stream>>>(u, u, vv, M_, M_, SZL, SZL, SZL, 7.f, 1.f, 1);
    bgemm64<<<dim3(4, 4, B_ * H_), 256, 0, stream>>>(u, vv, wb, M_, M_, SZL, SZL, SZL, 15.f, 1.f, 1);
    bgemm64<<<dim3(4, 4, B_ * H_), 256, 0, stream>>>(cur, wb, u, M_, M_, SZL, SZL, SZL, 13.f, 0.25f, 1);
    float* oc = cur; cur = u; u = vv; vv = wb; wb = oc;
  }

  bgemm64<<<dim3(1, 4, B_ * H_), 256, 0, stream>>>(cur, pvb, w2b, DH_, M_,
      SZL, (long long)M_ * DH_, (long long)M_ * DH_, 0.f, 1.f, 0);

  cvt_small<<<B_ * H_, 256, 0, stream>>>(kl, w2b, klb, w2t);
  attn1_kernel<<<B_ * H_ * (N_ / 256), 256, 0, stream>>>(qb, klb, w2t, oh);
  conv_kernel<<<(int)(((long long)B_ * N_ * INNER_) / 256), 256, 0, stream>>>(vb, res_w, oh);
  gemm_out<<<dim3(DIM_ / 128, (B_ * N_) / 128), 256, 0, stream>>>(oh, w_out, b_out, x, out);
}

// Round 5
// 1295.566 us; speedup vs baseline: 3.9854x; 1.4814x over previous
//
#include <hip/hip_runtime.h>
#include <cstdint>

#define B_ 4
#define N_ 8192
#define DIM_ 512
#define H_ 8
#define DH_ 64
#define M_ 256
#define L_ 32
#define INNER_ 512
#define K3_ 1536
#define RESK_ 33

struct __align__(16) ushort8_t { unsigned short u[8]; };
typedef short bf16x8 __attribute__((ext_vector_type(8)));
typedef float f32x4 __attribute__((ext_vector_type(4)));

__device__ __forceinline__ float bf2f(unsigned short u) {
  return __uint_as_float(((unsigned)u) << 16);
}
__device__ __forceinline__ unsigned short f2bf(float f) {
  unsigned x = __float_as_uint(f);
  return (unsigned short)((x + 0x7fffu + ((x >> 16) & 1u)) >> 16);  // RNE
}

// ---------------- fused LayerNorm -> bf16 activations ----------------
__global__ __launch_bounds__(256) void ln_bf16(const float* __restrict__ x,
    const float* __restrict__ w, const float* __restrict__ bb, unsigned short* __restrict__ xnb)
{
  int row = blockIdx.x;
  int tid = threadIdx.x;
  float2 v = reinterpret_cast<const float2*>(x + (size_t)row * DIM_)[tid];
  float s = v.x + v.y, s2 = v.x * v.x + v.y * v.y;
  #pragma unroll
  for (int off = 32; off; off >>= 1) { s += __shfl_down(s, off); s2 += __shfl_down(s2, off); }
  __shared__ float rs[4], rs2[4];
  int wid = tid >> 6, lane = tid & 63;
  if (lane == 0) { rs[wid] = s; rs2[wid] = s2; }
  __syncthreads();
  float ts = rs[0] + rs[1] + rs[2] + rs[3];
  float ts2 = rs2[0] + rs2[1] + rs2[2] + rs2[3];
  float mu = ts * (1.f / DIM_);
  float var = ts2 * (1.f / DIM_) - mu * mu;
  float inv = rsqrtf(var + 1e-5f);
  int c = tid * 2;
  unsigned int p0 = f2bf((v.x - mu) * inv * w[c] + bb[c]);
  unsigned int p1 = f2bf((v.y - mu) * inv * w[c + 1] + bb[c + 1]);
  reinterpret_cast<unsigned int*>(xnb + (size_t)row * DIM_)[tid] = p0 | (p1 << 16);
}

// ---------------- transpose weights to bf16: dst[c][k] = src[k][c] * (c<qcols?qs:1) ----------------
__global__ __launch_bounds__(256) void transpose_w(const float* __restrict__ src,
    unsigned short* __restrict__ dst, int K, int C, int qcols, float qs)
{
  __shared__ float T[64][65];
  int c0 = blockIdx.x * 64, k0 = blockIdx.y * 64;
  #pragma unroll 4
  for (int it = 0; it < 16; it++) {
    int idx = it * 256 + threadIdx.x;
    int kk = idx >> 6, cc = idx & 63;
    T[kk][cc] = src[(size_t)(k0 + kk) * C + c0 + cc];
  }
  __syncthreads();
  #pragma unroll 4
  for (int it = 0; it < 16; it++) {
    int idx = it * 256 + threadIdx.x;
    int cc = idx >> 6, kk = idx & 63;
    float v = T[kk][cc];
    int c = c0 + cc;
    dst[(size_t)c * K + k0 + kk] = f2bf(c < qcols ? v * qs : v);
  }
}

// ---------------- MFMA GEMM: qkv = xnb @ wT^T, scatter to q/k/v head-major bf16 ----------------
// 128x128 tile, BK=64, 4 waves (2x2), wave tile 64x64 (4x4 frags of 16x16).
__global__ __launch_bounds__(256, 2) void mfma_qkv(const unsigned short* __restrict__ xnb,
    const unsigned short* __restrict__ wT,
    unsigned short* __restrict__ qb, unsigned short* __restrict__ kb, unsigned short* __restrict__ vb)
{
  __shared__ unsigned short As[128][72];
  __shared__ unsigned short Bs[128][72];
  int tid = threadIdx.x;
  int bn = blockIdx.x * 128, bm = blockIdx.y * 128;
  int wid = tid >> 6, lane = tid & 63;
  int wr = wid >> 1, wc = wid & 1;
  int lr = lane & 15, lg = lane >> 4;
  const f32x4 zf = {0.f, 0.f, 0.f, 0.f};
  f32x4 acc[4][4];
  #pragma unroll
  for (int mt = 0; mt < 4; mt++)
    #pragma unroll
    for (int nt = 0; nt < 4; nt++) acc[mt][nt] = zf;

  for (int k0 = 0; k0 < DIM_; k0 += 64) {
    __syncthreads();
    #pragma unroll
    for (int rnd = 0; rnd < 4; rnd++) {
      int idx = rnd * 2048 + tid * 8;
      int row = idx >> 6, col = idx & 63;
      *reinterpret_cast<bf16x8*>(&As[row][col]) =
          *reinterpret_cast<const bf16x8*>(&xnb[(size_t)(bm + row) * DIM_ + k0 + col]);
      *reinterpret_cast<bf16x8*>(&Bs[row][col]) =
          *reinterpret_cast<const bf16x8*>(&wT[(size_t)(bn + row) * DIM_ + k0 + col]);
    }
    __syncthreads();
    bf16x8 af[4][2], bfr[4][2];
    #pragma unroll
    for (int mt = 0; mt < 4; mt++) {
      af[mt][0] = *reinterpret_cast<const bf16x8*>(&As[wr * 64 + mt * 16 + lr][lg * 8]);
      af[mt][1] = *reinterpret_cast<const bf16x8*>(&As[wr * 64 + mt * 16 + lr][32 + lg * 8]);
    }
    #pragma unroll
    for (int nt = 0; nt < 4; nt++) {
      bfr[nt][0] = *reinterpret_cast<const bf16x8*>(&Bs[wc * 64 + nt * 16 + lr][lg * 8]);
      bfr[nt][1] = *reinterpret_cast<const bf16x8*>(&Bs[wc * 64 + nt * 16 + lr][32 + lg * 8]);
    }
    #pragma unroll
    for (int mt = 0; mt < 4; mt++)
      #pragma unroll
      for (int nt = 0; nt < 4; nt++) {
        acc[mt][nt] = __builtin_amdgcn_mfma_f32_16x16x32_bf16(af[mt][0], bfr[nt][0], acc[mt][nt], 0, 0, 0);
        acc[mt][nt] = __builtin_amdgcn_mfma_f32_16x16x32_bf16(af[mt][1], bfr[nt][1], acc[mt][nt], 0, 0, 0);
      }
  }
  // epilogue: scatter to head-major bf16 (C/D: row = 4*lg + r, col = lr)
  #pragma unroll
  for (int nt = 0; nt < 4; nt++) {
    int c = bn + wc * 64 + nt * 16 + lr;
    int which = c >> 9;
    int h = (c >> 6) & (H_ - 1);
    int d = c & 63;
    unsigned short* dst = which == 0 ? qb : (which == 1 ? kb : vb);
    #pragma unroll
    for (int mt = 0; mt < 4; mt++)
      #pragma unroll
      for (int r = 0; r < 4; r++) {
        int row = bm + wr * 64 + mt * 16 + 4 * lg + r;
        int b = row >> 13, n = row & (N_ - 1);
        dst[(((size_t)(b * H_ + h) * N_ + n) << 6) + d] = f2bf(acc[mt][nt][r]);
      }
  }
}

// ---------------- MFMA GEMM: out = oh @ woutT^T + bias + resid (f32 out) ----------------
__global__ __launch_bounds__(256, 2) void mfma_out(const unsigned short* __restrict__ oh,
    const unsigned short* __restrict__ wT, const float* __restrict__ bias,
    const float* __restrict__ resid, float* __restrict__ out)
{
  __shared__ unsigned short As[128][72];
  __shared__ unsigned short Bs[128][72];
  int tid = threadIdx.x;
  int bn = blockIdx.x * 128, bm = blockIdx.y * 128;
  int wid = tid >> 6, lane = tid & 63;
  int wr = wid >> 1, wc = wid & 1;
  int lr = lane & 15, lg = lane >> 4;
  const f32x4 zf = {0.f, 0.f, 0.f, 0.f};
  f32x4 acc[4][4];
  #pragma unroll
  for (int mt = 0; mt < 4; mt++)
    #pragma unroll
    for (int nt = 0; nt < 4; nt++) acc[mt][nt] = zf;

  for (int k0 = 0; k0 < INNER_; k0 += 64) {
    __syncthreads();
    #pragma unroll
    for (int rnd = 0; rnd < 4; rnd++) {
      int idx = rnd * 2048 + tid * 8;
      int row = idx >> 6, col = idx & 63;
      *reinterpret_cast<bf16x8*>(&As[row][col]) =
          *reinterpret_cast<const bf16x8*>(&oh[((size_t)(bm + row) << 9) + k0 + col]);
      *reinterpret_cast<bf16x8*>(&Bs[row][col]) =
          *reinterpret_cast<const bf16x8*>(&wT[(size_t)(bn + row) * INNER_ + k0 + col]);
    }
    __syncthreads();
    bf16x8 af[4][2], bfr[4][2];
    #pragma unroll
    for (int mt = 0; mt < 4; mt++) {
      af[mt][0] = *reinterpret_cast<const bf16x8*>(&As[wr * 64 + mt * 16 + lr][lg * 8]);
      af[mt][1] = *reinterpret_cast<const bf16x8*>(&As[wr * 64 + mt * 16 + lr][32 + lg * 8]);
    }
    #pragma unroll
    for (int nt = 0; nt < 4; nt++) {
      bfr[nt][0] = *reinterpret_cast<const bf16x8*>(&Bs[wc * 64 + nt * 16 + lr][lg * 8]);
      bfr[nt][1] = *reinterpret_cast<const bf16x8*>(&Bs[wc * 64 + nt * 16 + lr][32 + lg * 8]);
    }
    #pragma unroll
    for (int mt = 0; mt < 4; mt++)
      #pragma unroll
      for (int nt = 0; nt < 4; nt++) {
        acc[mt][nt] = __builtin_amdgcn_mfma_f32_16x16x32_bf16(af[mt][0], bfr[nt][0], acc[mt][nt], 0, 0, 0);
        acc[mt][nt] = __builtin_amdgcn_mfma_f32_16x16x32_bf16(af[mt][1], bfr[nt][1], acc[mt][nt], 0, 0, 0);
      }
  }
  #pragma unroll
  for (int nt = 0; nt < 4; nt++) {
    int c = bn + wc * 64 + nt * 16 + lr;
    float bias_c = bias[c];
    #pragma unroll
    for (int mt = 0; mt < 4; mt++)
      #pragma unroll
      for (int r = 0; r < 4; r++) {
        int row = bm + wr * 64 + mt * 16 + 4 * lg + r;
        out[(size_t)row * DIM_ + c] = acc[mt][nt][r] + bias_c + resid[(size_t)row * DIM_ + c];
      }
  }
}

// ---------------- landmark means (also emits bf16 q_l) ----------------
__global__ __launch_bounds__(64) void landmark_kernel(const unsigned short* __restrict__ qb,
    const unsigned short* __restrict__ kb, float* __restrict__ ql, float* __restrict__ kl,
    unsigned short* __restrict__ qlb)
{
  int id = blockIdx.x;
  int m = id & (M_ - 1);
  int bh = id >> 8;
  int d = threadIdx.x;
  size_t base = (((size_t)bh * N_ + m * L_) << 6) + d;
  float sq = 0, sk = 0;
  #pragma unroll 4
  for (int j = 0; j < L_; j++) {
    sq += bf2f(qb[base + ((size_t)j << 6)]);
    sk += bf2f(kb[base + ((size_t)j << 6)]);
  }
  float qv = sq * (1.f / L_);
  ql[((size_t)bh * M_ + m) * DH_ + d] = qv;
  kl[((size_t)bh * M_ + m) * DH_ + d] = sk * (1.f / L_);
  qlb[((size_t)bh * M_ + m) * DH_ + d] = f2bf(qv);
}

// ---------------- sim2 + softmax -> attn2 ----------------
__global__ __launch_bounds__(256) void attn2_kernel(const float* __restrict__ ql,
    const float* __restrict__ kl, float* __restrict__ a2)
{
  int id = blockIdx.x;
  int i = id & (M_ - 1);
  int bh = id >> 8;
  int j = threadIdx.x;
  __shared__ float qs[DH_];
  __shared__ float wred[4];
  if (j < DH_) qs[j] = ql[((size_t)bh * M_ + i) * DH_ + j];
  __syncthreads();
  const float* krow = kl + ((size_t)bh * M_ + j) * DH_;
  float s = 0;
  #pragma unroll
  for (int d = 0; d < DH_; d++) s += qs[d] * krow[d];
  float mx = s;
  #pragma unroll
  for (int off = 1; off < 64; off <<= 1) mx = fmaxf(mx, __shfl_xor(mx, off));
  int wid = j >> 6, lane = j & 63;
  if (lane == 0) wred[wid] = mx;
  __syncthreads();
  mx = fmaxf(fmaxf(wred[0], wred[1]), fmaxf(wred[2], wred[3]));
  float e = __expf(s - mx);
  float sum = e;
  #pragma unroll
  for (int off = 1; off < 64; off <<= 1) sum += __shfl_xor(sum, off);
  __syncthreads();
  if (lane == 0) wred[wid] = sum;
  __syncthreads();
  sum = wred[0] + wred[1] + wred[2] + wred[3];
  a2[((size_t)bh * M_ + i) * M_ + j] = e / sum;
}

// ---------------- pinv scale ----------------
__global__ void zero_scal(unsigned int* scal) { scal[threadIdx.x] = 0u; }

__global__ __launch_bounds__(256) void pinv_scale_kernel(const float* __restrict__ a2,
    unsigned int* __restrict__ scal)
{
  int bh = blockIdx.x;
  int t = threadIdx.x;
  const float* xb = a2 + (size_t)bh * M_ * M_;
  float rowsum = 0, colsum = 0;
  for (int j = 0; j < M_; j++) {
    rowsum += xb[(size_t)t * M_ + j];
    colsum += xb[(size_t)j * M_ + t];
  }
  #pragma unroll
  for (int off = 1; off < 64; off <<= 1) {
    rowsum = fmaxf(rowsum, __shfl_xor(rowsum, off));
    colsum = fmaxf(colsum, __shfl_xor(colsum, off));
  }
  __shared__ float wr[4], wc[4];
  int wid = t >> 6, lane = t & 63;
  if (lane == 0) { wr[wid] = rowsum; wc[wid] = colsum; }
  __syncthreads();
  if (t == 0) {
    float rm = fmaxf(fmaxf(wr[0], wr[1]), fmaxf(wr[2], wr[3]));
    float cm = fmaxf(fmaxf(wc[0], wc[1]), fmaxf(wc[2], wc[3]));
    atomicMax(&scal[0], __float_as_uint(rm));
    atomicMax(&scal[1], __float_as_uint(cm));
  }
}

__global__ __launch_bounds__(256) void zinit_kernel(const float* __restrict__ a2,
    const unsigned int* __restrict__ scal, float* __restrict__ z)
{
  int bh = blockIdx.x;
  int j = threadIdx.x;
  float inv = 1.f / (__uint_as_float(scal[0]) * __uint_as_float(scal[1]));
  const float* xb = a2 + (size_t)bh * M_ * M_;
  float* zr = z + (size_t)bh * M_ * M_ + (size_t)j * M_;
  for (int i = 0; i < M_; i++) zr[i] = xb[(size_t)i * M_ + j] * inv;
}

// ---------------- batched 64x64x16 SGEMM ----------------
__global__ __launch_bounds__(256) void bgemm64(const float* __restrict__ A,
    const float* __restrict__ Bm, float* __restrict__ C, int Nc, int Kd,
    long long sA, long long sB, long long sC, float aI, float scale, int useI)
{
  __shared__ float As[16][64];
  __shared__ float Bs[16][64];
  int batch = blockIdx.z;
  const float* Ab = A + (size_t)batch * sA;
  const float* Bb = Bm + (size_t)batch * sB;
  float* Cb = C + (size_t)batch * sC;
  int bm = blockIdx.y * 64, bn = blockIdx.x * 64;
  int tid = threadIdx.x;
  int ty = tid >> 4, tx = tid & 15;
  int arow = (tid * 4) >> 4, akk = (tid * 4) & 15;
  int bkk = (tid * 4) >> 6, bcol = (tid * 4) & 63;
  float acc[4][4] = {};
  for (int k0 = 0; k0 < Kd; k0 += 16) {
    float4 av = *reinterpret_cast<const float4*>(&Ab[(size_t)(bm + arow) * Kd + k0 + akk]);
    float4 bv = *reinterpret_cast<const float4*>(&Bb[(size_t)(k0 + bkk) * Nc + bn + bcol]);
    if (useI) {
      int kr = k0 + bkk, cc = bn + bcol;
      bv.x = (kr == cc + 0 ? aI : 0.f) - bv.x;
      bv.y = (kr == cc + 1 ? aI : 0.f) - bv.y;
      bv.z = (kr == cc + 2 ? aI : 0.f) - bv.z;
      bv.w = (kr == cc + 3 ? aI : 0.f) - bv.w;
    }
    __syncthreads();
    As[akk + 0][arow] = av.x; As[akk + 1][arow] = av.y;
    As[akk + 2][arow] = av.z; As[akk + 3][arow] = av.w;
    *reinterpret_cast<float4*>(&Bs[bkk][bcol]) = bv;
    __syncthreads();
    #pragma unroll
    for (int kk = 0; kk < 16; kk++) {
      float ar[4], br[4];
      #pragma unroll
      for (int i = 0; i < 4; i++) ar[i] = As[kk][ty * 4 + i];
      #pragma unroll
      for (int j = 0; j < 4; j++) br[j] = Bs[kk][tx * 4 + j];
      #pragma unroll
      for (int i = 0; i < 4; i++)
        #pragma unroll
        for (int j = 0; j < 4; j++) acc[i][j] += ar[i] * br[j];
    }
  }
  for (int i = 0; i < 4; i++)
    #pragma unroll
    for (int j = 0; j < 4; j++)
      Cb[(size_t)(bm + ty * 4 + i) * Nc + bn + tx * 4 + j] = scale * acc[i][j];
}

// ---------------- pv partials: softmax(q_l @ k^T) @ v via MFMA, split over N ----------------
__global__ __launch_bounds__(256) void pv_mfma(
    const unsigned short* __restrict__ kb, const unsigned short* __restrict__ vb,
    const unsigned short* __restrict__ qlb,
    float* __restrict__ pvpart, float2* __restrict__ msbuf)
{
  int slice = blockIdx.x;
  int msp   = blockIdx.y;
  int bh    = blockIdx.z;
  int tid = threadIdx.x, wid = tid >> 6, lane = tid & 63;
  int lr = lane & 15, lg = lane >> 4;

  __shared__ unsigned short klds[64][72];
  __shared__ unsigned short vtld[64][72];
  __shared__ unsigned short plds_all[4][32][72];
  unsigned short (*plds)[72] = plds_all[wid];

  int mbase = msp * 128 + wid * 32;
  const unsigned short* qbase = qlb + (((size_t)bh * M_ + mbase) << 6);
  bf16x8 qf[2][2];
  #pragma unroll
  for (int rt = 0; rt < 2; rt++)
    #pragma unroll
    for (int h2 = 0; h2 < 2; h2++)
      qf[rt][h2] = *reinterpret_cast<const bf16x8*>(&qbase[((rt * 16 + lr) << 6) + h2 * 32 + lg * 8]);

  const f32x4 zf = {0.f, 0.f, 0.f, 0.f};
  f32x4 oacc[2][4];
  #pragma unroll
  for (int rt = 0; rt < 2; rt++)
    #pragma unroll
    for (int dt = 0; dt < 4; dt++) oacc[rt][dt] = zf;
  float mrun[8], srun[8];
  #pragma unroll
  for (int i = 0; i < 8; i++) { mrun[i] = -1e30f; srun[i] = 0.f; }

  const unsigned short* kgb = kb + (((size_t)bh * N_ + slice * 1024) << 6);
  const unsigned short* vgb = vb + (((size_t)bh * N_ + slice * 1024) << 6);

  for (int c = 0; c < 16; c++) {
    __syncthreads();
    for (int u = tid; u < 512; u += 256) {
      int key = u >> 3, seg = u & 7;
      size_t goff = (((size_t)(c * 64 + key)) << 6) + seg * 8;
      bf16x8 kv = *reinterpret_cast<const bf16x8*>(&kgb[goff]);
      *reinterpret_cast<bf16x8*>(&klds[key][seg * 8]) = kv;
      bf16x8 vv = *reinterpret_cast<const bf16x8*>(&vgb[goff]);
      int col = key ^ (seg << 3);
      #pragma unroll
      for (int j = 0; j < 8; j++) vtld[seg * 8 + j][col] = (unsigned short)vv[j];
    }
    __syncthreads();
    f32x4 sacc[2][4];
    #pragma unroll
    for (int rt = 0; rt < 2; rt++)
      #pragma unroll
      for (int ct = 0; ct < 4; ct++) {
        bf16x8 b0 = *reinterpret_cast<const bf16x8*>(&klds[ct * 16 + lr][lg * 8]);
        bf16x8 b1 = *reinterpret_cast<const bf16x8*>(&klds[ct * 16 + lr][32 + lg * 8]);
        f32x4 a = __builtin_amdgcn_mfma_f32_16x16x32_bf16(qf[rt][0], b0, zf, 0, 0, 0);
        sacc[rt][ct] = __builtin_amdgcn_mfma_f32_16x16x32_bf16(qf[rt][1], b1, a, 0, 0, 0);
      }
    #pragma unroll
    for (int rt = 0; rt < 2; rt++)
      #pragma unroll
      for (int r = 0; r < 4; r++) {
        int ri = rt * 4 + r;
        float mc = fmaxf(fmaxf(sacc[rt][0][r], sacc[rt][1][r]), fmaxf(sacc[rt][2][r], sacc[rt][3][r]));
        #pragma unroll
        for (int off = 1; off < 16; off <<= 1) mc = fmaxf(mc, __shfl_xor(mc, off));
        float mnew = fmaxf(mrun[ri], mc);
        float corr = __expf(mrun[ri] - mnew);
        float psum = 0.f;
        #pragma unroll
        for (int ct = 0; ct < 4; ct++) {
          float p = __expf(sacc[rt][ct][r] - mnew);
          sacc[rt][ct][r] = p;
          psum += p;
        }
        #pragma unroll
        for (int off = 1; off < 16; off <<= 1) psum += __shfl_xor(psum, off);
        srun[ri] = srun[ri] * corr + psum;
        mrun[ri] = mnew;
        #pragma unroll
        for (int dt = 0; dt < 4; dt++) oacc[rt][dt][r] *= corr;
        #pragma unroll
        for (int ct = 0; ct < 4; ct++)
          plds[rt * 16 + 4 * lg + r][ct * 16 + lr] = f2bf(sacc[rt][ct][r]);
      }
    __builtin_amdgcn_s_waitcnt(0);
    bf16x8 pa[2][2];
    #pragma unroll
    for (int rt = 0; rt < 2; rt++)
      #pragma unroll
      for (int h = 0; h < 2; h++)
        pa[rt][h] = *reinterpret_cast<const bf16x8*>(&plds[rt * 16 + lr][h * 32 + lg * 8]);
    #pragma unroll
    for (int dt = 0; dt < 4; dt++) {
      int d = dt * 16 + lr;
      bf16x8 bv0 = *reinterpret_cast<const bf16x8*>(&vtld[d][(lg * 8) ^ (d & 0x38)]);
      bf16x8 bv1 = *reinterpret_cast<const bf16x8*>(&vtld[d][(32 + lg * 8) ^ (d & 0x38)]);
      #pragma unroll
      for (int rt = 0; rt < 2; rt++) {
        oacc[rt][dt] = __builtin_amdgcn_mfma_f32_16x16x32_bf16(pa[rt][0], bv0, oacc[rt][dt], 0, 0, 0);
        oacc[rt][dt] = __builtin_amdgcn_mfma_f32_16x16x32_bf16(pa[rt][1], bv1, oacc[rt][dt], 0, 0, 0);
      }
    }
  }
  size_t pbase = (((size_t)(bh * 8 + slice) * M_ + mbase) << 6);
  #pragma unroll
  for (int rt = 0; rt < 2; rt++)
    #pragma unroll
    for (int dt = 0; dt < 4; dt++)
      #pragma unroll
      for (int r = 0; r < 4; r++)
        pvpart[pbase + ((size_t)(rt * 16 + 4 * lg + r) << 6) + dt * 16 + lr] = oacc[rt][dt][r];
  if (lr == 0) {
    #pragma unroll
    for (int rt = 0; rt < 2; rt++)
      #pragma unroll
      for (int r = 0; r < 4; r++)
        msbuf[(size_t)(bh * 8 + slice) * M_ + mbase + rt * 16 + 4 * lg + r] =
            make_float2(mrun[rt * 4 + r], srun[rt * 4 + r]);
  }
}

// ---------------- combine split-N partials ----------------
__global__ __launch_bounds__(256) void pv_combine(const float* __restrict__ pvpart,
    const float2* __restrict__ msbuf, float* __restrict__ pvb)
{
  int row = blockIdx.x * 4 + (threadIdx.x >> 6);
  int bh = row >> 8, m = row & (M_ - 1);
  int d = threadIdx.x & 63;
  float2 ms[8];
  float mg = -1e30f;
  #pragma unroll
  for (int s = 0; s < 8; s++) {
    ms[s] = msbuf[(size_t)(bh * 8 + s) * M_ + m];
    mg = fmaxf(mg, ms[s].x);
  }
  float ssum = 0.f, o = 0.f;
  #pragma unroll
  for (int s = 0; s < 8; s++) {
    float w = __expf(ms[s].x - mg);
    ssum += ms[s].y * w;
    o += w * pvpart[(((size_t)(bh * 8 + s) * M_ + m) << 6) + d];
  }
  pvb[(((size_t)bh * M_ + m) << 6) + d] = o / ssum;
}

// ---------------- convert kl -> bf16 and W2 -> bf16 transposed ----------------
__global__ __launch_bounds__(256) void cvt_small(const float* __restrict__ kl,
    const float* __restrict__ w2b, unsigned short* __restrict__ klb, unsigned short* __restrict__ w2t)
{
  int bh = blockIdx.x;
  size_t base = (size_t)bh << 14;
  for (int e = threadIdx.x; e < M_ * DH_; e += 256) {
    klb[base + e] = f2bf(kl[base + e]);
    int m = e >> 6, dh = e & 63;
    w2t[base + (size_t)dh * M_ + m] = f2bf(w2b[base + e]);
  }
}

// ---------------- attn1: oh = softmax(q @ kl^T) @ W2 via MFMA ----------------
__global__ __launch_bounds__(256) void attn1_kernel(
    const unsigned short* __restrict__ qb,
    const unsigned short* __restrict__ klb,
    const unsigned short* __restrict__ w2t,
    unsigned short* __restrict__ oh)
{
  int ntile = blockIdx.x & 31;
  int bh = blockIdx.x >> 5;
  int h = bh & (H_ - 1), b = bh >> 3;
  int tid = threadIdx.x, wid = tid >> 6, lane = tid & 63;
  int lr = lane & 15, lg = lane >> 4;
  __shared__ unsigned short plds_all[4][16][264];
  unsigned short* plds = &plds_all[wid][0][0];

  const unsigned short* qbh  = qb  + (((size_t)bh * N_) << 6);
  const unsigned short* klbh = klb + ((size_t)bh << 14);
  const unsigned short* w2bh = w2t + ((size_t)bh << 14);

  const f32x4 zf = {0.f, 0.f, 0.f, 0.f};
  for (int sub = 0; sub < 4; sub++) {
    int n0 = ntile * 256 + sub * 64 + wid * 16;
    bf16x8 aq0 = *reinterpret_cast<const bf16x8*>(&qbh[((size_t)(n0 + lr) << 6) + lg * 8]);
    bf16x8 aq1 = *reinterpret_cast<const bf16x8*>(&qbh[((size_t)(n0 + lr) << 6) + 32 + lg * 8]);
    f32x4 accs[16];
    #pragma unroll
    for (int mt = 0; mt < 16; mt++) {
      bf16x8 b0 = *reinterpret_cast<const bf16x8*>(&klbh[((size_t)(mt * 16 + lr) << 6) + lg * 8]);
      bf16x8 b1 = *reinterpret_cast<const bf16x8*>(&klbh[((size_t)(mt * 16 + lr) << 6) + 32 + lg * 8]);
      f32x4 a = __builtin_amdgcn_mfma_f32_16x16x32_bf16(aq0, b0, zf, 0, 0, 0);
      accs[mt] = __builtin_amdgcn_mfma_f32_16x16x32_bf16(aq1, b1, a, 0, 0, 0);
    }
    float rs[4];
    #pragma unroll
    for (int r = 0; r < 4; r++) {
      float m0 = accs[0][r];
      #pragma unroll
      for (int mt = 1; mt < 16; mt++) m0 = fmaxf(m0, accs[mt][r]);
      #pragma unroll
      for (int off = 1; off < 16; off <<= 1) m0 = fmaxf(m0, __shfl_xor(m0, off));
      float s0 = 0.f;
      #pragma unroll
      for (int mt = 0; mt < 16; mt++) {
        float p = __expf(accs[mt][r] - m0);
        accs[mt][r] = p;
        s0 += p;
      }
      #pragma unroll
      for (int off = 1; off < 16; off <<= 1) s0 += __shfl_xor(s0, off);
      rs[r] = 1.f / s0;
    }
    #pragma unroll
    for (int mt = 0; mt < 16; mt++)
      #pragma unroll
      for (int r = 0; r < 4; r++)
        plds[(4 * lg + r) * 264 + mt * 16 + lr] = f2bf(accs[mt][r]);
    __builtin_amdgcn_s_waitcnt(0);
    bf16x8 pa[8];
    #pragma unroll
    for (int mc = 0; mc < 8; mc++)
      pa[mc] = *reinterpret_cast<const bf16x8*>(&plds[lr * 264 + mc * 32 + lg * 8]);
    f32x4 acco[4];
    #pragma unroll
    for (int dt = 0; dt < 4; dt++) {
      f32x4 a = zf;
      #pragma unroll
      for (int mc = 0; mc < 8; mc++) {
        bf16x8 wf = *reinterpret_cast<const bf16x8*>(&w2bh[(size_t)(dt * 16 + lr) * M_ + mc * 32 + lg * 8]);
        a = __builtin_amdgcn_mfma_f32_16x16x32_bf16(pa[mc], wf, a, 0, 0, 0);
      }
      acco[dt] = a;
    }
    #pragma unroll
    for (int dt = 0; dt < 4; dt++)
      #pragma unroll
      for (int r = 0; r < 4; r++) {
        int n = n0 + 4 * lg + r;
        oh[((size_t)(b * N_ + n) << 9) + h * DH_ + dt * 16 + lr] = f2bf(acco[dt][r] * rs[r]);
      }
  }
}

// ---------------- depthwise conv residual: oh += conv(v) ----------------
__global__ __launch_bounds__(256) void conv_kernel(const unsigned short* __restrict__ vb,
    const float* __restrict__ rw, unsigned short* __restrict__ oh)
{
  long long idx = (long long)blockIdx.x * 256 + threadIdx.x;
  int c = (int)(idx & (INNER_ - 1));
  long long bn = idx >> 9;
  int n = (int)(bn & (N_ - 1));
  int b = (int)(bn >> 13);
  int h = c >> 6, d = c & 63;
  const unsigned short* vbb = vb + (((size_t)(b * H_ + h) * N_) << 6) + d;
  float acc = 0;
  #pragma unroll
  for (int j = 0; j < RESK_; j++) {
    int nn = n + j - RESK_ / 2;
    if (nn >= 0 && nn < N_) acc += rw[h * RESK_ + j] * bf2f(vbb[((size_t)nn) << 6]);
  }
  oh[idx] = f2bf(bf2f(oh[idx]) + acc);
}

extern "C" void kernel_launch(void* const* d_in, const int* in_sizes, int n_in,
                              void* d_out, int out_size, void* d_ws, size_t ws_size,
                              hipStream_t stream)
{
  const float* x     = (const float*)d_in[0];
  const float* ln_w  = (const float*)d_in[1];
  const float* ln_b  = (const float*)d_in[2];
  const float* w_qkv = (const float*)d_in[3];
  const float* w_out = (const float*)d_in[4];
  const float* b_out = (const float*)d_in[5];
  const float* res_w = (const float*)d_in[6];
  float* out = (float*)d_out;

  const size_t HEADEL = (size_t)B_ * H_ * N_ * DH_;     // 16,777,216
  const size_t SMALL  = (size_t)B_ * H_ * M_ * DH_;     // 524,288
  unsigned short* qb = (unsigned short*)d_ws;
  unsigned short* kb = qb + HEADEL;
  unsigned short* vb = kb + HEADEL;
  unsigned short* oh = vb + HEADEL;
  unsigned short* xnb = oh + HEADEL;                    // [B*N][512] bf16
  unsigned short* wqkvT = xnb + (size_t)B_ * N_ * DIM_; // [1536][512] bf16
  unsigned short* woutT = wqkvT + (size_t)K3_ * DIM_;   // [512][512] bf16
  float* ql  = (float*)(woutT + (size_t)DIM_ * INNER_);
  float* kl  = ql + SMALL;
  float* pvb = kl + SMALL;
  float* w2b = pvb + SMALL;
  unsigned short* klb = (unsigned short*)(w2b + SMALL);
  unsigned short* w2t = klb + SMALL;
  unsigned short* qlb = w2t + SMALL;
  float* pvpart = (float*)(qlb + SMALL);
  float2* msbuf = (float2*)(pvpart + (size_t)B_ * H_ * 8 * M_ * DH_);
  unsigned int* scal = (unsigned int*)(msbuf + (size_t)B_ * H_ * 8 * M_);
  size_t need = (size_t)((char*)(scal + 64) - (char*)d_ws);
  if (ws_size < need) return;

  const size_t SZ = (size_t)M_ * M_;
  float* a2 = (float*)d_out;
  float* z0 = a2 + (size_t)B_ * H_ * SZ;
  float* z1 = z0 + (size_t)B_ * H_ * SZ;
  float* z2 = z1 + (size_t)B_ * H_ * SZ;
  float* z3 = z2 + (size_t)B_ * H_ * SZ;

  ln_bf16<<<B_ * N_, 256, 0, stream>>>(x, ln_w, ln_b, xnb);
  transpose_w<<<dim3(K3_ / 64, DIM_ / 64), 256, 0, stream>>>(w_qkv, wqkvT, DIM_, K3_, INNER_, 0.125f);
  transpose_w<<<dim3(DIM_ / 64, INNER_ / 64), 256, 0, stream>>>(w_out, woutT, INNER_, DIM_, 0, 1.f);
  mfma_qkv<<<dim3(K3_ / 128, (B_ * N_) / 128), 256, 0, stream>>>(xnb, wqkvT, qb, kb, vb);
  landmark_kernel<<<B_ * H_ * M_, 64, 0, stream>>>(qb, kb, ql, kl, qlb);
  attn2_kernel<<<B_ * H_ * M_, 256, 0, stream>>>(ql, kl, a2);
  zero_scal<<<1, 2, 0, stream>>>(scal);
  pinv_scale_kernel<<<B_ * H_, 256, 0, stream>>>(a2, scal);
  zinit_kernel<<<B_ * H_, 256, 0, stream>>>(a2, scal, z0);
  pv_mfma<<<dim3(8, 2, B_ * H_), 256, 0, stream>>>(kb, vb, qlb, pvpart, msbuf);
  pv_combine<<<(B_ * H_ * M_) / 4, 256, 0, stream>>>(pvpart, msbuf, pvb);

  const long long SZL = (long long)SZ;
  float* cur = z0; float* u = z1; float* vv = z2; float* wb = z3;
  for (int it = 0; it < 6; it++) {
    bgemm64<<<dim3(4, 4, B_ * H_), 256, 0, stream>>>(a2, cur, u, M_, M_, SZL, SZL, SZL, 0.f, 1.f, 0);
    bgemm64<<<dim3(4, 4, B_ * H_), 256, 0, stream>>>(u, u, vv, M_, M_, SZL, SZL, SZL, 7.f, 1.f, 1);
    bgemm64<<<dim3(4, 4, B_ * H_), 256, 0, stream>>>(u, vv, wb, M_, M_, SZL, SZL, SZL, 15.f, 1.f, 1);
    bgemm64<<<dim3(4, 4, B_ * H_), 256, 0, stream>>>(cur, wb, u, M_, M_, SZL, SZL, SZL, 13.f, 0.25f, 1);
    float* oc = cur; cur = u; u = vv; vv = wb; wb = oc;
  }

  bgemm64<<<dim3(1, 4, B_ * H_), 256, 0, stream>>>(cur, pvb, w2b, DH_, M_,
      SZL, (long long)M_ * DH_, (long long)M_ * DH_, 0.f, 1.f, 0);

  cvt_small<<<B_ * H_, 256, 0, stream>>>(kl, w2b, klb, w2t);
  attn1_kernel<<<B_ * H_ * (N_ / 256), 256, 0, stream>>>(qb, klb, w2t, oh);
  conv_kernel<<<(int)(((long long)B_ * N_ * INNER_) / 256), 256, 0, stream>>>(vb, res_w, oh);
  mfma_out<<<dim3(DIM_ / 128, (B_ * N_) / 128), 256, 0, stream>>>(oh, woutT, b_out, x, out);
}

// Round 6
// 1222.131 us; speedup vs baseline: 4.2249x; 1.0601x over previous
//
#include <hip/hip_runtime.h>
#include <cstdint>

#define B_ 4
#define N_ 8192
#define DIM_ 512
#define H_ 8
#define DH_ 64
#define M_ 256
#define L_ 32
#define INNER_ 512
#define K3_ 1536
#define RESK_ 33

struct __align__(16) ushort8_t { unsigned short u[8]; };
typedef short bf16x8 __attribute__((ext_vector_type(8)));
typedef float f32x4 __attribute__((ext_vector_type(4)));

__device__ __forceinline__ float bf2f(unsigned short u) {
  return __uint_as_float(((unsigned)u) << 16);
}
__device__ __forceinline__ unsigned short f2bf(float f) {
  unsigned x = __float_as_uint(f);
  return (unsigned short)((x + 0x7fffu + ((x >> 16) & 1u)) >> 16);  // RNE
}
__device__ __forceinline__ void split2(float x, unsigned short& h, unsigned short& l) {
  h = f2bf(x);
  l = f2bf(x - bf2f(h));
}

// ---------------- fused LayerNorm -> bf16 activations ----------------
__global__ __launch_bounds__(256) void ln_bf16(const float* __restrict__ x,
    const float* __restrict__ w, const float* __restrict__ bb, unsigned short* __restrict__ xnb)
{
  int row = blockIdx.x;
  int tid = threadIdx.x;
  float2 v = reinterpret_cast<const float2*>(x + (size_t)row * DIM_)[tid];
  float s = v.x + v.y, s2 = v.x * v.x + v.y * v.y;
  #pragma unroll
  for (int off = 32; off; off >>= 1) { s += __shfl_down(s, off); s2 += __shfl_down(s2, off); }
  __shared__ float rs[4], rs2[4];
  int wid = tid >> 6, lane = tid & 63;
  if (lane == 0) { rs[wid] = s; rs2[wid] = s2; }
  __syncthreads();
  float ts = rs[0] + rs[1] + rs[2] + rs[3];
  float ts2 = rs2[0] + rs2[1] + rs2[2] + rs2[3];
  float mu = ts * (1.f / DIM_);
  float var = ts2 * (1.f / DIM_) - mu * mu;
  float inv = rsqrtf(var + 1e-5f);
  int c = tid * 2;
  unsigned int p0 = f2bf((v.x - mu) * inv * w[c] + bb[c]);
  unsigned int p1 = f2bf((v.y - mu) * inv * w[c + 1] + bb[c + 1]);
  reinterpret_cast<unsigned int*>(xnb + (size_t)row * DIM_)[tid] = p0 | (p1 << 16);
}

// ---------------- transpose weights to bf16 ----------------
__global__ __launch_bounds__(256) void transpose_w(const float* __restrict__ src,
    unsigned short* __restrict__ dst, int K, int C, int qcols, float qs)
{
  __shared__ float T[64][65];
  int c0 = blockIdx.x * 64, k0 = blockIdx.y * 64;
  #pragma unroll 4
  for (int it = 0; it < 16; it++) {
    int idx = it * 256 + threadIdx.x;
    int kk = idx >> 6, cc = idx & 63;
    T[kk][cc] = src[(size_t)(k0 + kk) * C + c0 + cc];
  }
  __syncthreads();
  #pragma unroll 4
  for (int it = 0; it < 16; it++) {
    int idx = it * 256 + threadIdx.x;
    int cc = idx >> 6, kk = idx & 63;
    float v = T[kk][cc];
    int c = c0 + cc;
    dst[(size_t)c * K + k0 + kk] = f2bf(c < qcols ? v * qs : v);
  }
}

// ---------------- MFMA GEMM: qkv = xnb @ wT^T, scatter head-major bf16 ----------------
__global__ __launch_bounds__(256, 2) void mfma_qkv(const unsigned short* __restrict__ xnb,
    const unsigned short* __restrict__ wT,
    unsigned short* __restrict__ qb, unsigned short* __restrict__ kb, unsigned short* __restrict__ vb)
{
  __shared__ unsigned short As[128][72];
  __shared__ unsigned short Bs[128][72];
  int tid = threadIdx.x;
  int bn = blockIdx.x * 128, bm = blockIdx.y * 128;
  int wid = tid >> 6, lane = tid & 63;
  int wr = wid >> 1, wc = wid & 1;
  int lr = lane & 15, lg = lane >> 4;
  const f32x4 zf = {0.f, 0.f, 0.f, 0.f};
  f32x4 acc[4][4];
  #pragma unroll
  for (int mt = 0; mt < 4; mt++)
    #pragma unroll
    for (int nt = 0; nt < 4; nt++) acc[mt][nt] = zf;

  for (int k0 = 0; k0 < DIM_; k0 += 64) {
    __syncthreads();
    #pragma unroll
    for (int rnd = 0; rnd < 4; rnd++) {
      int idx = rnd * 2048 + tid * 8;
      int row = idx >> 6, col = idx & 63;
      *reinterpret_cast<bf16x8*>(&As[row][col]) =
          *reinterpret_cast<const bf16x8*>(&xnb[(size_t)(bm + row) * DIM_ + k0 + col]);
      *reinterpret_cast<bf16x8*>(&Bs[row][col]) =
          *reinterpret_cast<const bf16x8*>(&wT[(size_t)(bn + row) * DIM_ + k0 + col]);
    }
    __syncthreads();
    bf16x8 af[4][2], bfr[4][2];
    #pragma unroll
    for (int mt = 0; mt < 4; mt++) {
      af[mt][0] = *reinterpret_cast<const bf16x8*>(&As[wr * 64 + mt * 16 + lr][lg * 8]);
      af[mt][1] = *reinterpret_cast<const bf16x8*>(&As[wr * 64 + mt * 16 + lr][32 + lg * 8]);
    }
    #pragma unroll
    for (int nt = 0; nt < 4; nt++) {
      bfr[nt][0] = *reinterpret_cast<const bf16x8*>(&Bs[wc * 64 + nt * 16 + lr][lg * 8]);
      bfr[nt][1] = *reinterpret_cast<const bf16x8*>(&Bs[wc * 64 + nt * 16 + lr][32 + lg * 8]);
    }
    #pragma unroll
    for (int mt = 0; mt < 4; mt++)
      #pragma unroll
      for (int nt = 0; nt < 4; nt++) {
        acc[mt][nt] = __builtin_amdgcn_mfma_f32_16x16x32_bf16(af[mt][0], bfr[nt][0], acc[mt][nt], 0, 0, 0);
        acc[mt][nt] = __builtin_amdgcn_mfma_f32_16x16x32_bf16(af[mt][1], bfr[nt][1], acc[mt][nt], 0, 0, 0);
      }
  }
  #pragma unroll
  for (int nt = 0; nt < 4; nt++) {
    int c = bn + wc * 64 + nt * 16 + lr;
    int which = c >> 9;
    int h = (c >> 6) & (H_ - 1);
    int d = c & 63;
    unsigned short* dst = which == 0 ? qb : (which == 1 ? kb : vb);
    #pragma unroll
    for (int mt = 0; mt < 4; mt++)
      #pragma unroll
      for (int r = 0; r < 4; r++) {
        int row = bm + wr * 64 + mt * 16 + 4 * lg + r;
        int b = row >> 13, n = row & (N_ - 1);
        dst[(((size_t)(b * H_ + h) * N_ + n) << 6) + d] = f2bf(acc[mt][nt][r]);
      }
  }
}

// ---------------- MFMA GEMM: out = oh @ woutT^T + bias + resid (f32 out) ----------------
__global__ __launch_bounds__(256, 2) void mfma_out(const unsigned short* __restrict__ oh,
    const unsigned short* __restrict__ wT, const float* __restrict__ bias,
    const float* __restrict__ resid, float* __restrict__ out)
{
  __shared__ unsigned short As[128][72];
  __shared__ unsigned short Bs[128][72];
  int tid = threadIdx.x;
  int bn = blockIdx.x * 128, bm = blockIdx.y * 128;
  int wid = tid >> 6, lane = tid & 63;
  int wr = wid >> 1, wc = wid & 1;
  int lr = lane & 15, lg = lane >> 4;
  const f32x4 zf = {0.f, 0.f, 0.f, 0.f};
  f32x4 acc[4][4];
  #pragma unroll
  for (int mt = 0; mt < 4; mt++)
    #pragma unroll
    for (int nt = 0; nt < 4; nt++) acc[mt][nt] = zf;

  for (int k0 = 0; k0 < INNER_; k0 += 64) {
    __syncthreads();
    #pragma unroll
    for (int rnd = 0; rnd < 4; rnd++) {
      int idx = rnd * 2048 + tid * 8;
      int row = idx >> 6, col = idx & 63;
      *reinterpret_cast<bf16x8*>(&As[row][col]) =
          *reinterpret_cast<const bf16x8*>(&oh[((size_t)(bm + row) << 9) + k0 + col]);
      *reinterpret_cast<bf16x8*>(&Bs[row][col]) =
          *reinterpret_cast<const bf16x8*>(&wT[(size_t)(bn + row) * INNER_ + k0 + col]);
    }
    __syncthreads();
    bf16x8 af[4][2], bfr[4][2];
    #pragma unroll
    for (int mt = 0; mt < 4; mt++) {
      af[mt][0] = *reinterpret_cast<const bf16x8*>(&As[wr * 64 + mt * 16 + lr][lg * 8]);
      af[mt][1] = *reinterpret_cast<const bf16x8*>(&As[wr * 64 + mt * 16 + lr][32 + lg * 8]);
    }
    #pragma unroll
    for (int nt = 0; nt < 4; nt++) {
      bfr[nt][0] = *reinterpret_cast<const bf16x8*>(&Bs[wc * 64 + nt * 16 + lr][lg * 8]);
      bfr[nt][1] = *reinterpret_cast<const bf16x8*>(&Bs[wc * 64 + nt * 16 + lr][32 + lg * 8]);
    }
    #pragma unroll
    for (int mt = 0; mt < 4; mt++)
      #pragma unroll
      for (int nt = 0; nt < 4; nt++) {
        acc[mt][nt] = __builtin_amdgcn_mfma_f32_16x16x32_bf16(af[mt][0], bfr[nt][0], acc[mt][nt], 0, 0, 0);
        acc[mt][nt] = __builtin_amdgcn_mfma_f32_16x16x32_bf16(af[mt][1], bfr[nt][1], acc[mt][nt], 0, 0, 0);
      }
  }
  #pragma unroll
  for (int nt = 0; nt < 4; nt++) {
    int c = bn + wc * 64 + nt * 16 + lr;
    float bias_c = bias[c];
    #pragma unroll
    for (int mt = 0; mt < 4; mt++)
      #pragma unroll
      for (int r = 0; r < 4; r++) {
        int row = bm + wr * 64 + mt * 16 + 4 * lg + r;
        out[(size_t)row * DIM_ + c] = acc[mt][nt][r] + bias_c + resid[(size_t)row * DIM_ + c];
      }
  }
}

// ---------------- landmark means (f32 + bf16 q_l, bf16 k_l) ----------------
__global__ __launch_bounds__(64) void landmark_kernel(const unsigned short* __restrict__ qb,
    const unsigned short* __restrict__ kb, float* __restrict__ ql, float* __restrict__ kl,
    unsigned short* __restrict__ qlb, unsigned short* __restrict__ klb)
{
  int id = blockIdx.x;
  int m = id & (M_ - 1);
  int bh = id >> 8;
  int d = threadIdx.x;
  size_t base = (((size_t)bh * N_ + m * L_) << 6) + d;
  float sq = 0, sk = 0;
  #pragma unroll 4
  for (int j = 0; j < L_; j++) {
    sq += bf2f(qb[base + ((size_t)j << 6)]);
    sk += bf2f(kb[base + ((size_t)j << 6)]);
  }
  float qv = sq * (1.f / L_);
  float kv = sk * (1.f / L_);
  size_t o = ((size_t)bh * M_ + m) * DH_ + d;
  ql[o] = qv;
  kl[o] = kv;
  qlb[o] = f2bf(qv);
  klb[o] = f2bf(kv);
}

// ---------------- sim2 + softmax -> attn2 (f32 + hi/lo split) ----------------
__global__ __launch_bounds__(256) void attn2_kernel(const float* __restrict__ ql,
    const float* __restrict__ kl, float* __restrict__ a2,
    unsigned short* __restrict__ a2h, unsigned short* __restrict__ a2l)
{
  int id = blockIdx.x;
  int i = id & (M_ - 1);
  int bh = id >> 8;
  int j = threadIdx.x;
  __shared__ float qs[DH_];
  __shared__ float wred[4];
  if (j < DH_) qs[j] = ql[((size_t)bh * M_ + i) * DH_ + j];
  __syncthreads();
  const float* krow = kl + ((size_t)bh * M_ + j) * DH_;
  float s = 0;
  #pragma unroll
  for (int d = 0; d < DH_; d++) s += qs[d] * krow[d];
  float mx = s;
  #pragma unroll
  for (int off = 1; off < 64; off <<= 1) mx = fmaxf(mx, __shfl_xor(mx, off));
  int wid = j >> 6, lane = j & 63;
  if (lane == 0) wred[wid] = mx;
  __syncthreads();
  mx = fmaxf(fmaxf(wred[0], wred[1]), fmaxf(wred[2], wred[3]));
  float e = __expf(s - mx);
  float sum = e;
  #pragma unroll
  for (int off = 1; off < 64; off <<= 1) sum += __shfl_xor(sum, off);
  __syncthreads();
  if (lane == 0) wred[wid] = sum;
  __syncthreads();
  sum = wred[0] + wred[1] + wred[2] + wred[3];
  float p = e / sum;
  size_t o = ((size_t)bh * M_ + i) * M_ + j;
  a2[o] = p;
  unsigned short h, l;
  split2(p, h, l);
  a2h[o] = h;
  a2l[o] = l;
}

// ---------------- pinv scale ----------------
__global__ void zero_scal(unsigned int* scal) { scal[threadIdx.x] = 0u; }

__global__ __launch_bounds__(256) void pinv_scale_kernel(const float* __restrict__ a2,
    unsigned int* __restrict__ scal)
{
  int bh = blockIdx.x;
  int t = threadIdx.x;
  const float* xb = a2 + (size_t)bh * M_ * M_;
  float rowsum = 0, colsum = 0;
  for (int j = 0; j < M_; j++) {
    rowsum += xb[(size_t)t * M_ + j];
    colsum += xb[(size_t)j * M_ + t];
  }
  #pragma unroll
  for (int off = 1; off < 64; off <<= 1) {
    rowsum = fmaxf(rowsum, __shfl_xor(rowsum, off));
    colsum = fmaxf(colsum, __shfl_xor(colsum, off));
  }
  __shared__ float wr[4], wc[4];
  int wid = t >> 6, lane = t & 63;
  if (lane == 0) { wr[wid] = rowsum; wc[wid] = colsum; }
  __syncthreads();
  if (t == 0) {
    float rm = fmaxf(fmaxf(wr[0], wr[1]), fmaxf(wr[2], wr[3]));
    float cm = fmaxf(fmaxf(wc[0], wc[1]), fmaxf(wc[2], wc[3]));
    atomicMax(&scal[0], __float_as_uint(rm));
    atomicMax(&scal[1], __float_as_uint(cm));
  }
}

// ---------------- z0 = a2^T / s, emitted as row-split (A-form) and T-split (B-form) ----------------
__global__ __launch_bounds__(256) void zinit_kernel(const float* __restrict__ a2,
    const unsigned int* __restrict__ scal,
    unsigned short* __restrict__ zRh, unsigned short* __restrict__ zRl,
    unsigned short* __restrict__ zTh, unsigned short* __restrict__ zTl)
{
  int bh = blockIdx.x;
  int j = threadIdx.x;
  float inv = 1.f / (__uint_as_float(scal[0]) * __uint_as_float(scal[1]));
  size_t base = (size_t)bh * M_ * M_;
  for (int i = 0; i < M_; i++) {
    float v = a2[base + (size_t)i * M_ + j] * inv;   // z0[j][i] = a2[i][j]*inv
    unsigned short h, l;
    split2(v, h, l);
    // zT storage[n][k] = z0^T[n][k] = z0[k][n] = a2[n][k]*inv  (coalesced)
    zTh[base + (size_t)i * M_ + j] = h;
    zTl[base + (size_t)i * M_ + j] = l;
    // zR storage[m][k] = z0[m][k]  (scattered)
    zRh[base + (size_t)j * M_ + i] = h;
    zRl[base + (size_t)j * M_ + i] = l;
  }
}

// ---------------- batched split-bf16 MFMA GEMM for Newton-Schulz ----------------
// C = A @ B; A: row-split [b][256][256]; B: T-split storage [b][n][k] (holds B^T).
// Optional outputs: R = split(sR*C) row-major; T = split(aT*I + sT*C) stored transposed.
__global__ __launch_bounds__(256) void bgemm_ns(
    const unsigned short* __restrict__ Ah, const unsigned short* __restrict__ Al,
    const unsigned short* __restrict__ Bh, const unsigned short* __restrict__ Bl,
    unsigned short* __restrict__ Rh, unsigned short* __restrict__ Rl,
    unsigned short* __restrict__ Th, unsigned short* __restrict__ Tl,
    float aT, float sT, float sR)
{
  int bn = blockIdx.x * 64, bm = blockIdx.y * 64;
  size_t bb = (size_t)blockIdx.z * (M_ * M_);
  int tid = threadIdx.x, wid = tid >> 6, lane = tid & 63;
  int lr = lane & 15, lg = lane >> 4;
  int r0 = bm + wid * 16;
  const f32x4 zf = {0.f, 0.f, 0.f, 0.f};
  f32x4 acc[4];
  #pragma unroll
  for (int nt = 0; nt < 4; nt++) acc[nt] = zf;

  #pragma unroll
  for (int k0 = 0; k0 < M_; k0 += 32) {
    bf16x8 ah = *reinterpret_cast<const bf16x8*>(&Ah[bb + (size_t)(r0 + lr) * M_ + k0 + lg * 8]);
    bf16x8 al = *reinterpret_cast<const bf16x8*>(&Al[bb + (size_t)(r0 + lr) * M_ + k0 + lg * 8]);
    #pragma unroll
    for (int nt = 0; nt < 4; nt++) {
      size_t boff = bb + (size_t)(bn + nt * 16 + lr) * M_ + k0 + lg * 8;
      bf16x8 bh = *reinterpret_cast<const bf16x8*>(&Bh[boff]);
      bf16x8 bl = *reinterpret_cast<const bf16x8*>(&Bl[boff]);
      acc[nt] = __builtin_amdgcn_mfma_f32_16x16x32_bf16(ah, bh, acc[nt], 0, 0, 0);
      acc[nt] = __builtin_amdgcn_mfma_f32_16x16x32_bf16(ah, bl, acc[nt], 0, 0, 0);
      acc[nt] = __builtin_amdgcn_mfma_f32_16x16x32_bf16(al, bh, acc[nt], 0, 0, 0);
    }
  }
  #pragma unroll
  for (int nt = 0; nt < 4; nt++) {
    int col = bn + nt * 16 + lr;
    #pragma unroll
    for (int r = 0; r < 4; r++) {
      int row = r0 + 4 * lg + r;
      float v = acc[nt][r];
      if (Rh) {
        unsigned short h, l;
        split2(sR * v, h, l);
        Rh[bb + (size_t)row * M_ + col] = h;
        Rl[bb + (size_t)row * M_ + col] = l;
      }
      if (Th) {
        float t = sT * v + (row == col ? aT : 0.f);
        unsigned short h, l;
        split2(t, h, l);
        Th[bb + (size_t)col * M_ + row] = h;
        Tl[bb + (size_t)col * M_ + row] = l;
      }
    }
  }
}

// ---------------- W2 = pinv @ pv -> w2t bf16 [bh][64][256] ----------------
__global__ __launch_bounds__(256) void gemm_w2(
    const unsigned short* __restrict__ zRh, const unsigned short* __restrict__ zRl,
    const unsigned short* __restrict__ pvTh, const unsigned short* __restrict__ pvTl,
    unsigned short* __restrict__ w2t)
{
  int bm = blockIdx.x * 64;
  int batch = blockIdx.y;
  size_t bz = (size_t)batch * (M_ * M_);
  size_t bp = (size_t)batch << 14;
  int tid = threadIdx.x, wid = tid >> 6, lane = tid & 63;
  int lr = lane & 15, lg = lane >> 4;
  int r0 = bm + wid * 16;
  const f32x4 zf = {0.f, 0.f, 0.f, 0.f};
  f32x4 acc[4];
  #pragma unroll
  for (int nt = 0; nt < 4; nt++) acc[nt] = zf;

  #pragma unroll
  for (int k0 = 0; k0 < M_; k0 += 32) {
    bf16x8 ah = *reinterpret_cast<const bf16x8*>(&zRh[bz + (size_t)(r0 + lr) * M_ + k0 + lg * 8]);
    bf16x8 al = *reinterpret_cast<const bf16x8*>(&zRl[bz + (size_t)(r0 + lr) * M_ + k0 + lg * 8]);
    #pragma unroll
    for (int nt = 0; nt < 4; nt++) {
      size_t boff = bp + (size_t)(nt * 16 + lr) * M_ + k0 + lg * 8;
      bf16x8 bh = *reinterpret_cast<const bf16x8*>(&pvTh[boff]);
      bf16x8 bl = *reinterpret_cast<const bf16x8*>(&pvTl[boff]);
      acc[nt] = __builtin_amdgcn_mfma_f32_16x16x32_bf16(ah, bh, acc[nt], 0, 0, 0);
      acc[nt] = __builtin_amdgcn_mfma_f32_16x16x32_bf16(ah, bl, acc[nt], 0, 0, 0);
      acc[nt] = __builtin_amdgcn_mfma_f32_16x16x32_bf16(al, bh, acc[nt], 0, 0, 0);
    }
  }
  #pragma unroll
  for (int nt = 0; nt < 4; nt++) {
    int col = nt * 16 + lr;   // dh
    #pragma unroll
    for (int r = 0; r < 4; r++) {
      int row = r0 + 4 * lg + r;   // m
      w2t[bp + (size_t)col * M_ + row] = f2bf(acc[nt][r]);
    }
  }
}

// ---------------- pv partials: softmax(q_l @ k^T) @ v via MFMA, split over N ----------------
__global__ __launch_bounds__(256) void pv_mfma(
    const unsigned short* __restrict__ kb, const unsigned short* __restrict__ vb,
    const unsigned short* __restrict__ qlb,
    float* __restrict__ pvpart, float2* __restrict__ msbuf)
{
  int slice = blockIdx.x;
  int msp   = blockIdx.y;
  int bh    = blockIdx.z;
  int tid = threadIdx.x, wid = tid >> 6, lane = tid & 63;
  int lr = lane & 15, lg = lane >> 4;

  __shared__ unsigned short klds[64][72];
  __shared__ unsigned short vtld[64][72];
  __shared__ unsigned short plds_all[4][32][72];
  unsigned short (*plds)[72] = plds_all[wid];

  int mbase = msp * 128 + wid * 32;
  const unsigned short* qbase = qlb + (((size_t)bh * M_ + mbase) << 6);
  bf16x8 qf[2][2];
  #pragma unroll
  for (int rt = 0; rt < 2; rt++)
    #pragma unroll
    for (int h2 = 0; h2 < 2; h2++)
      qf[rt][h2] = *reinterpret_cast<const bf16x8*>(&qbase[((rt * 16 + lr) << 6) + h2 * 32 + lg * 8]);

  const f32x4 zf = {0.f, 0.f, 0.f, 0.f};
  f32x4 oacc[2][4];
  #pragma unroll
  for (int rt = 0; rt < 2; rt++)
    #pragma unroll
    for (int dt = 0; dt < 4; dt++) oacc[rt][dt] = zf;
  float mrun[8], srun[8];
  #pragma unroll
  for (int i = 0; i < 8; i++) { mrun[i] = -1e30f; srun[i] = 0.f; }

  const unsigned short* kgb = kb + (((size_t)bh * N_ + slice * 1024) << 6);
  const unsigned short* vgb = vb + (((size_t)bh * N_ + slice * 1024) << 6);

  for (int c = 0; c < 16; c++) {
    __syncthreads();
    for (int u = tid; u < 512; u += 256) {
      int key = u >> 3, seg = u & 7;
      size_t goff = (((size_t)(c * 64 + key)) << 6) + seg * 8;
      bf16x8 kv = *reinterpret_cast<const bf16x8*>(&kgb[goff]);
      *reinterpret_cast<bf16x8*>(&klds[key][seg * 8]) = kv;
      bf16x8 vv = *reinterpret_cast<const bf16x8*>(&vgb[goff]);
      int col = key ^ (seg << 3);
      #pragma unroll
      for (int j = 0; j < 8; j++) vtld[seg * 8 + j][col] = (unsigned short)vv[j];
    }
    __syncthreads();
    f32x4 sacc[2][4];
    #pragma unroll
    for (int rt = 0; rt < 2; rt++)
      #pragma unroll
      for (int ct = 0; ct < 4; ct++) {
        bf16x8 b0 = *reinterpret_cast<const bf16x8*>(&klds[ct * 16 + lr][lg * 8]);
        bf16x8 b1 = *reinterpret_cast<const bf16x8*>(&klds[ct * 16 + lr][32 + lg * 8]);
        f32x4 a = __builtin_amdgcn_mfma_f32_16x16x32_bf16(qf[rt][0], b0, zf, 0, 0, 0);
        sacc[rt][ct] = __builtin_amdgcn_mfma_f32_16x16x32_bf16(qf[rt][1], b1, a, 0, 0, 0);
      }
    #pragma unroll
    for (int rt = 0; rt < 2; rt++)
      #pragma unroll
      for (int r = 0; r < 4; r++) {
        int ri = rt * 4 + r;
        float mc = fmaxf(fmaxf(sacc[rt][0][r], sacc[rt][1][r]), fmaxf(sacc[rt][2][r], sacc[rt][3][r]));
        #pragma unroll
        for (int off = 1; off < 16; off <<= 1) mc = fmaxf(mc, __shfl_xor(mc, off));
        float mnew = fmaxf(mrun[ri], mc);
        float corr = __expf(mrun[ri] - mnew);
        float psum = 0.f;
        #pragma unroll
        for (int ct = 0; ct < 4; ct++) {
          float p = __expf(sacc[rt][ct][r] - mnew);
          sacc[rt][ct][r] = p;
          psum += p;
        }
        #pragma unroll
        for (int off = 1; off < 16; off <<= 1) psum += __shfl_xor(psum, off);
        srun[ri] = srun[ri] * corr + psum;
        mrun[ri] = mnew;
        #pragma unroll
        for (int dt = 0; dt < 4; dt++) oacc[rt][dt][r] *= corr;
        #pragma unroll
        for (int ct = 0; ct < 4; ct++)
          plds[rt * 16 + 4 * lg + r][ct * 16 + lr] = f2bf(sacc[rt][ct][r]);
      }
    __builtin_amdgcn_s_waitcnt(0);
    bf16x8 pa[2][2];
    #pragma unroll
    for (int rt = 0; rt < 2; rt++)
      #pragma unroll
      for (int h = 0; h < 2; h++)
        pa[rt][h] = *reinterpret_cast<const bf16x8*>(&plds[rt * 16 + lr][h * 32 + lg * 8]);
    #pragma unroll
    for (int dt = 0; dt < 4; dt++) {
      int d = dt * 16 + lr;
      bf16x8 bv0 = *reinterpret_cast<const bf16x8*>(&vtld[d][(lg * 8) ^ (d & 0x38)]);
      bf16x8 bv1 = *reinterpret_cast<const bf16x8*>(&vtld[d][(32 + lg * 8) ^ (d & 0x38)]);
      #pragma unroll
      for (int rt = 0; rt < 2; rt++) {
        oacc[rt][dt] = __builtin_amdgcn_mfma_f32_16x16x32_bf16(pa[rt][0], bv0, oacc[rt][dt], 0, 0, 0);
        oacc[rt][dt] = __builtin_amdgcn_mfma_f32_16x16x32_bf16(pa[rt][1], bv1, oacc[rt][dt], 0, 0, 0);
      }
    }
  }
  size_t pbase = (((size_t)(bh * 8 + slice) * M_ + mbase) << 6);
  #pragma unroll
  for (int rt = 0; rt < 2; rt++)
    #pragma unroll
    for (int dt = 0; dt < 4; dt++)
      #pragma unroll
      for (int r = 0; r < 4; r++)
        pvpart[pbase + ((size_t)(rt * 16 + 4 * lg + r) << 6) + dt * 16 + lr] = oacc[rt][dt][r];
  if (lr == 0) {
    #pragma unroll
    for (int rt = 0; rt < 2; rt++)
      #pragma unroll
      for (int r = 0; r < 4; r++)
        msbuf[(size_t)(bh * 8 + slice) * M_ + mbase + rt * 16 + 4 * lg + r] =
            make_float2(mrun[rt * 4 + r], srun[rt * 4 + r]);
  }
}

// ---------------- combine split-N partials -> pv^T split bf16 [bh][64][256] ----------------
__global__ __launch_bounds__(256) void pv_combine(const float* __restrict__ pvpart,
    const float2* __restrict__ msbuf,
    unsigned short* __restrict__ pvTh, unsigned short* __restrict__ pvTl)
{
  int row = blockIdx.x * 4 + (threadIdx.x >> 6);
  int bh = row >> 8, m = row & (M_ - 1);
  int d = threadIdx.x & 63;
  float2 ms[8];
  float mg = -1e30f;
  #pragma unroll
  for (int s = 0; s < 8; s++) {
    ms[s] = msbuf[(size_t)(bh * 8 + s) * M_ + m];
    mg = fmaxf(mg, ms[s].x);
  }
  float ssum = 0.f, o = 0.f;
  #pragma unroll
  for (int s = 0; s < 8; s++) {
    float w = __expf(ms[s].x - mg);
    ssum += ms[s].y * w;
    o += w * pvpart[(((size_t)(bh * 8 + s) * M_ + m) << 6) + d];
  }
  float val = o / ssum;
  unsigned short h, l;
  split2(val, h, l);
  size_t oi = ((size_t)bh << 14) + (size_t)d * M_ + m;
  pvTh[oi] = h;
  pvTl[oi] = l;
}

// ---------------- attn1: oh = softmax(q @ kl^T) @ W2 via MFMA ----------------
__global__ __launch_bounds__(256) void attn1_kernel(
    const unsigned short* __restrict__ qb,
    const unsigned short* __restrict__ klb,
    const unsigned short* __restrict__ w2t,
    unsigned short* __restrict__ oh)
{
  int ntile = blockIdx.x & 31;
  int bh = blockIdx.x >> 5;
  int h = bh & (H_ - 1), b = bh >> 3;
  int tid = threadIdx.x, wid = tid >> 6, lane = tid & 63;
  int lr = lane & 15, lg = lane >> 4;
  __shared__ unsigned short plds_all[4][16][264];
  unsigned short* plds = &plds_all[wid][0][0];

  const unsigned short* qbh  = qb  + (((size_t)bh * N_) << 6);
  const unsigned short* klbh = klb + ((size_t)bh << 14);
  const unsigned short* w2bh = w2t + ((size_t)bh << 14);

  const f32x4 zf = {0.f, 0.f, 0.f, 0.f};
  for (int sub = 0; sub < 4; sub++) {
    int n0 = ntile * 256 + sub * 64 + wid * 16;
    bf16x8 aq0 = *reinterpret_cast<const bf16x8*>(&qbh[((size_t)(n0 + lr) << 6) + lg * 8]);
    bf16x8 aq1 = *reinterpret_cast<const bf16x8*>(&qbh[((size_t)(n0 + lr) << 6) + 32 + lg * 8]);
    f32x4 accs[16];
    #pragma unroll
    for (int mt = 0; mt < 16; mt++) {
      bf16x8 b0 = *reinterpret_cast<const bf16x8*>(&klbh[((size_t)(mt * 16 + lr) << 6) + lg * 8]);
      bf16x8 b1 = *reinterpret_cast<const bf16x8*>(&klbh[((size_t)(mt * 16 + lr) << 6) + 32 + lg * 8]);
      f32x4 a = __builtin_amdgcn_mfma_f32_16x16x32_bf16(aq0, b0, zf, 0, 0, 0);
      accs[mt] = __builtin_amdgcn_mfma_f32_16x16x32_bf16(aq1, b1, a, 0, 0, 0);
    }
    float rs[4];
    #pragma unroll
    for (int r = 0; r < 4; r++) {
      float m0 = accs[0][r];
      #pragma unroll
      for (int mt = 1; mt < 16; mt++) m0 = fmaxf(m0, accs[mt][r]);
      #pragma unroll
      for (int off = 1; off < 16; off <<= 1) m0 = fmaxf(m0, __shfl_xor(m0, off));
      float s0 = 0.f;
      #pragma unroll
      for (int mt = 0; mt < 16; mt++) {
        float p = __expf(accs[mt][r] - m0);
        accs[mt][r] = p;
        s0 += p;
      }
      #pragma unroll
      for (int off = 1; off < 16; off <<= 1) s0 += __shfl_xor(s0, off);
      rs[r] = 1.f / s0;
    }
    #pragma unroll
    for (int mt = 0; mt < 16; mt++)
      #pragma unroll
      for (int r = 0; r < 4; r++)
        plds[(4 * lg + r) * 264 + mt * 16 + lr] = f2bf(accs[mt][r]);
    __builtin_amdgcn_s_waitcnt(0);
    bf16x8 pa[8];
    #pragma unroll
    for (int mc = 0; mc < 8; mc++)
      pa[mc] = *reinterpret_cast<const bf16x8*>(&plds[lr * 264 + mc * 32 + lg * 8]);
    f32x4 acco[4];
    #pragma unroll
    for (int dt = 0; dt < 4; dt++) {
      f32x4 a = zf;
      #pragma unroll
      for (int mc = 0; mc < 8; mc++) {
        bf16x8 wf = *reinterpret_cast<const bf16x8*>(&w2bh[(size_t)(dt * 16 + lr) * M_ + mc * 32 + lg * 8]);
        a = __builtin_amdgcn_mfma_f32_16x16x32_bf16(pa[mc], wf, a, 0, 0, 0);
      }
      acco[dt] = a;
    }
    #pragma unroll
    for (int dt = 0; dt < 4; dt++)
      #pragma unroll
      for (int r = 0; r < 4; r++) {
        int n = n0 + 4 * lg + r;
        oh[((size_t)(b * N_ + n) << 9) + h * DH_ + dt * 16 + lr] = f2bf(acco[dt][r] * rs[r]);
      }
  }
}

// ---------------- depthwise conv residual: register sliding window ----------------
__global__ __launch_bounds__(256) void conv_kernel(const unsigned short* __restrict__ vb,
    const float* __restrict__ rw, unsigned short* __restrict__ oh)
{
  int bh = blockIdx.y;
  int h = bh & (H_ - 1), b = bh >> 3;
  int d = threadIdx.x & 63, g = threadIdx.x >> 6;
  int n0 = blockIdx.x * 128 + g * 32;
  const unsigned short* vbb = vb + (((size_t)bh * N_) << 6) + d;
  float w[64];
  #pragma unroll
  for (int j = 0; j < 64; j++) {
    int nn = n0 - 16 + j;
    w[j] = (nn >= 0 && nn < N_) ? bf2f(vbb[(size_t)nn << 6]) : 0.f;
  }
  float rwr[RESK_];
  #pragma unroll
  for (int j = 0; j < RESK_; j++) rwr[j] = rw[h * RESK_ + j];
  size_t obase = (((size_t)(b * N_ + n0)) << 9) + h * 64 + d;
  #pragma unroll
  for (int t = 0; t < 32; t++) {
    float acc = 0.f;
    #pragma unroll
    for (int j = 0; j < RESK_; j++) acc += rwr[j] * w[t + j];
    size_t oi = obase + ((size_t)t << 9);
    oh[oi] = f2bf(bf2f(oh[oi]) + acc);
  }
}

extern "C" void kernel_launch(void* const* d_in, const int* in_sizes, int n_in,
                              void* d_out, int out_size, void* d_ws, size_t ws_size,
                              hipStream_t stream)
{
  const float* x     = (const float*)d_in[0];
  const float* ln_w  = (const float*)d_in[1];
  const float* ln_b  = (const float*)d_in[2];
  const float* w_qkv = (const float*)d_in[3];
  const float* w_out = (const float*)d_in[4];
  const float* b_out = (const float*)d_in[5];
  const float* res_w = (const float*)d_in[6];
  float* out = (float*)d_out;

  const size_t HEADEL = (size_t)B_ * H_ * N_ * DH_;   // 16,777,216
  const size_t SMALL  = (size_t)B_ * H_ * M_ * DH_;   // 524,288
  const size_t MSQ    = (size_t)B_ * H_ * M_ * M_;    // 2,097,152

  char* p = (char*)d_ws;
  auto alloc = [&](size_t bytes) { char* r = p; p += (bytes + 255) & ~(size_t)255; return r; };

  unsigned short* qb  = (unsigned short*)alloc(HEADEL * 2);
  unsigned short* kb  = (unsigned short*)alloc(HEADEL * 2);
  unsigned short* vb  = (unsigned short*)alloc(HEADEL * 2);
  unsigned short* oh  = (unsigned short*)alloc(HEADEL * 2);
  // union A: xnb (32 MB) then z ping-pong splits (8 x 4 MB)
  char* unA = alloc(HEADEL * 2);
  unsigned short* xnb  = (unsigned short*)unA;
  unsigned short* z0Rh = (unsigned short*)unA;
  unsigned short* z0Rl = z0Rh + MSQ;
  unsigned short* z0Th = z0Rl + MSQ;
  unsigned short* z0Tl = z0Th + MSQ;
  unsigned short* z1Rh = z0Tl + MSQ;
  unsigned short* z1Rl = z1Rh + MSQ;
  unsigned short* z1Th = z1Rl + MSQ;
  unsigned short* z1Tl = z1Th + MSQ;
  // union B: pvpart f32 (16 MB) + msbuf (0.5 MB) then u/v/w/y splits (8 x 4 MB)
  char* unB = alloc(HEADEL * 2);
  float*  pvpart = (float*)unB;
  float2* msbuf  = (float2*)(unB + (size_t)B_ * H_ * 8 * M_ * DH_ * 4);
  unsigned short* uh = (unsigned short*)unB;
  unsigned short* ul = uh + MSQ;
  unsigned short* vh = ul + MSQ;
  unsigned short* vl = vh + MSQ;
  unsigned short* wh = vl + MSQ;
  unsigned short* wl = wh + MSQ;
  unsigned short* yh = wl + MSQ;
  unsigned short* yl = yh + MSQ;

  unsigned short* wqkvT = (unsigned short*)alloc((size_t)K3_ * DIM_ * 2);
  unsigned short* woutT = (unsigned short*)alloc((size_t)DIM_ * INNER_ * 2);
  float* ql  = (float*)alloc(SMALL * 4);
  float* kl  = (float*)alloc(SMALL * 4);
  unsigned short* qlb  = (unsigned short*)alloc(SMALL * 2);
  unsigned short* klb  = (unsigned short*)alloc(SMALL * 2);
  unsigned short* pvTh = (unsigned short*)alloc(SMALL * 2);
  unsigned short* pvTl = (unsigned short*)alloc(SMALL * 2);
  unsigned short* w2t  = (unsigned short*)alloc(SMALL * 2);
  unsigned short* a2h  = (unsigned short*)alloc(MSQ * 2);
  unsigned short* a2l  = (unsigned short*)alloc(MSQ * 2);
  unsigned int* scal   = (unsigned int*)alloc(256);
  if ((size_t)(p - (char*)d_ws) > ws_size) return;

  float* a2 = (float*)d_out;   // 8 MB, dead before mfma_out overwrites d_out

  ln_bf16<<<B_ * N_, 256, 0, stream>>>(x, ln_w, ln_b, xnb);
  transpose_w<<<dim3(K3_ / 64, DIM_ / 64), 256, 0, stream>>>(w_qkv, wqkvT, DIM_, K3_, INNER_, 0.125f);
  transpose_w<<<dim3(DIM_ / 64, INNER_ / 64), 256, 0, stream>>>(w_out, woutT, INNER_, DIM_, 0, 1.f);
  mfma_qkv<<<dim3(K3_ / 128, (B_ * N_) / 128), 256, 0, stream>>>(xnb, wqkvT, qb, kb, vb);
  landmark_kernel<<<B_ * H_ * M_, 64, 0, stream>>>(qb, kb, ql, kl, qlb, klb);
  attn2_kernel<<<B_ * H_ * M_, 256, 0, stream>>>(ql, kl, a2, a2h, a2l);
  zero_scal<<<1, 2, 0, stream>>>(scal);
  pinv_scale_kernel<<<B_ * H_, 256, 0, stream>>>(a2, scal);
  pv_mfma<<<dim3(8, 2, B_ * H_), 256, 0, stream>>>(kb, vb, qlb, pvpart, msbuf);
  pv_combine<<<(B_ * H_ * M_) / 4, 256, 0, stream>>>(pvpart, msbuf, pvTh, pvTl);
  // zinit AFTER mfma_qkv (xnb dead) — writes z0 over xnb region
  zinit_kernel<<<B_ * H_, 256, 0, stream>>>(a2, scal, z0Rh, z0Rl, z0Th, z0Tl);

  // Newton-Schulz chain, split-bf16 MFMA (u/v/w/y overwrite pvpart region — pv done)
  unsigned short *cRh = z0Rh, *cRl = z0Rl, *cTh = z0Th, *cTl = z0Tl;
  unsigned short *nRh = z1Rh, *nRl = z1Rl, *nTh = z1Th, *nTl = z1Tl;
  dim3 g44(4, 4, B_ * H_);
  for (int it = 0; it < 6; it++) {
    // u = a2 @ z ; v = 7I - u
    bgemm_ns<<<g44, 256, 0, stream>>>(a2h, a2l, cTh, cTl, uh, ul, vh, vl, 7.f, -1.f, 1.f);
    // t = u @ v ; w = 15I - t
    bgemm_ns<<<g44, 256, 0, stream>>>(uh, ul, vh, vl, nullptr, nullptr, wh, wl, 15.f, -1.f, 0.f);
    // t2 = u @ w ; y = 13I - t2
    bgemm_ns<<<g44, 256, 0, stream>>>(uh, ul, wh, wl, nullptr, nullptr, yh, yl, 13.f, -1.f, 0.f);
    // z' = 0.25 * z @ y (both row and T splits)
    bgemm_ns<<<g44, 256, 0, stream>>>(cRh, cRl, yh, yl, nRh, nRl, nTh, nTl, 0.f, 0.25f, 0.25f);
    unsigned short* t;
    t = cRh; cRh = nRh; nRh = t;  t = cRl; cRl = nRl; nRl = t;
    t = cTh; cTh = nTh; nTh = t;  t = cTl; cTl = nTl; nTl = t;
  }

  gemm_w2<<<dim3(4, B_ * H_), 256, 0, stream>>>(cRh, cRl, pvTh, pvTl, w2t);

  attn1_kernel<<<B_ * H_ * (N_ / 256), 256, 0, stream>>>(qb, klb, w2t, oh);
  conv_kernel<<<dim3(N_ / 128, B_ * H_), 256, 0, stream>>>(vb, res_w, oh);
  mfma_out<<<dim3(DIM_ / 128, (B_ * N_) / 128), 256, 0, stream>>>(oh, woutT, b_out, x, out);
}

// Round 7
// 886.183 us; speedup vs baseline: 5.8265x; 1.3791x over previous
//
#include <hip/hip_runtime.h>
#include <cstdint>

#define B_ 4
#define N_ 8192
#define DIM_ 512
#define H_ 8
#define DH_ 64
#define M_ 256
#define L_ 32
#define INNER_ 512
#define K3_ 1536
#define RESK_ 33

struct __align__(16) ushort8_t { unsigned short u[8]; };
typedef short bf16x8 __attribute__((ext_vector_type(8)));
typedef float f32x4 __attribute__((ext_vector_type(4)));

__device__ __forceinline__ float bf2f(unsigned short u) {
  return __uint_as_float(((unsigned)u) << 16);
}
__device__ __forceinline__ unsigned short f2bf(float f) {
  unsigned x = __float_as_uint(f);
  return (unsigned short)((x + 0x7fffu + ((x >> 16) & 1u)) >> 16);  // RNE
}
__device__ __forceinline__ void split2(float x, unsigned short& h, unsigned short& l) {
  h = f2bf(x);
  l = f2bf(x - bf2f(h));
}

// ---------------- fused LayerNorm -> bf16 activations ----------------
__global__ __launch_bounds__(256) void ln_bf16(const float* __restrict__ x,
    const float* __restrict__ w, const float* __restrict__ bb, unsigned short* __restrict__ xnb)
{
  int row = blockIdx.x;
  int tid = threadIdx.x;
  float2 v = reinterpret_cast<const float2*>(x + (size_t)row * DIM_)[tid];
  float s = v.x + v.y, s2 = v.x * v.x + v.y * v.y;
  #pragma unroll
  for (int off = 32; off; off >>= 1) { s += __shfl_down(s, off); s2 += __shfl_down(s2, off); }
  __shared__ float rs[4], rs2[4];
  int wid = tid >> 6, lane = tid & 63;
  if (lane == 0) { rs[wid] = s; rs2[wid] = s2; }
  __syncthreads();
  float ts = rs[0] + rs[1] + rs[2] + rs[3];
  float ts2 = rs2[0] + rs2[1] + rs2[2] + rs2[3];
  float mu = ts * (1.f / DIM_);
  float var = ts2 * (1.f / DIM_) - mu * mu;
  float inv = rsqrtf(var + 1e-5f);
  int c = tid * 2;
  unsigned int p0 = f2bf((v.x - mu) * inv * w[c] + bb[c]);
  unsigned int p1 = f2bf((v.y - mu) * inv * w[c + 1] + bb[c + 1]);
  reinterpret_cast<unsigned int*>(xnb + (size_t)row * DIM_)[tid] = p0 | (p1 << 16);
}

// ---------------- transpose weights to bf16 ----------------
__global__ __launch_bounds__(256) void transpose_w(const float* __restrict__ src,
    unsigned short* __restrict__ dst, int K, int C, int qcols, float qs)
{
  __shared__ float T[64][65];
  int c0 = blockIdx.x * 64, k0 = blockIdx.y * 64;
  #pragma unroll 4
  for (int it = 0; it < 16; it++) {
    int idx = it * 256 + threadIdx.x;
    int kk = idx >> 6, cc = idx & 63;
    T[kk][cc] = src[(size_t)(k0 + kk) * C + c0 + cc];
  }
  __syncthreads();
  #pragma unroll 4
  for (int it = 0; it < 16; it++) {
    int idx = it * 256 + threadIdx.x;
    int cc = idx >> 6, kk = idx & 63;
    float v = T[kk][cc];
    int c = c0 + cc;
    dst[(size_t)c * K + k0 + kk] = f2bf(c < qcols ? v * qs : v);
  }
}

// ---------------- MFMA GEMM: qkv = xnb @ wT^T, scatter head-major bf16 ----------------
__global__ __launch_bounds__(256, 2) void mfma_qkv(const unsigned short* __restrict__ xnb,
    const unsigned short* __restrict__ wT,
    unsigned short* __restrict__ qb, unsigned short* __restrict__ kb, unsigned short* __restrict__ vb)
{
  __shared__ unsigned short As[128][72];
  __shared__ unsigned short Bs[128][72];
  int tid = threadIdx.x;
  int bn = blockIdx.x * 128, bm = blockIdx.y * 128;
  int wid = tid >> 6, lane = tid & 63;
  int wr = wid >> 1, wc = wid & 1;
  int lr = lane & 15, lg = lane >> 4;
  const f32x4 zf = {0.f, 0.f, 0.f, 0.f};
  f32x4 acc[4][4];
  #pragma unroll
  for (int mt = 0; mt < 4; mt++)
    #pragma unroll
    for (int nt = 0; nt < 4; nt++) acc[mt][nt] = zf;

  for (int k0 = 0; k0 < DIM_; k0 += 64) {
    __syncthreads();
    #pragma unroll
    for (int rnd = 0; rnd < 4; rnd++) {
      int idx = rnd * 2048 + tid * 8;
      int row = idx >> 6, col = idx & 63;
      *reinterpret_cast<bf16x8*>(&As[row][col]) =
          *reinterpret_cast<const bf16x8*>(&xnb[(size_t)(bm + row) * DIM_ + k0 + col]);
      *reinterpret_cast<bf16x8*>(&Bs[row][col]) =
          *reinterpret_cast<const bf16x8*>(&wT[(size_t)(bn + row) * DIM_ + k0 + col]);
    }
    __syncthreads();
    bf16x8 af[4][2], bfr[4][2];
    #pragma unroll
    for (int mt = 0; mt < 4; mt++) {
      af[mt][0] = *reinterpret_cast<const bf16x8*>(&As[wr * 64 + mt * 16 + lr][lg * 8]);
      af[mt][1] = *reinterpret_cast<const bf16x8*>(&As[wr * 64 + mt * 16 + lr][32 + lg * 8]);
    }
    #pragma unroll
    for (int nt = 0; nt < 4; nt++) {
      bfr[nt][0] = *reinterpret_cast<const bf16x8*>(&Bs[wc * 64 + nt * 16 + lr][lg * 8]);
      bfr[nt][1] = *reinterpret_cast<const bf16x8*>(&Bs[wc * 64 + nt * 16 + lr][32 + lg * 8]);
    }
    #pragma unroll
    for (int mt = 0; mt < 4; mt++)
      #pragma unroll
      for (int nt = 0; nt < 4; nt++) {
        acc[mt][nt] = __builtin_amdgcn_mfma_f32_16x16x32_bf16(af[mt][0], bfr[nt][0], acc[mt][nt], 0, 0, 0);
        acc[mt][nt] = __builtin_amdgcn_mfma_f32_16x16x32_bf16(af[mt][1], bfr[nt][1], acc[mt][nt], 0, 0, 0);
      }
  }
  #pragma unroll
  for (int nt = 0; nt < 4; nt++) {
    int c = bn + wc * 64 + nt * 16 + lr;
    int which = c >> 9;
    int h = (c >> 6) & (H_ - 1);
    int d = c & 63;
    unsigned short* dst = which == 0 ? qb : (which == 1 ? kb : vb);
    #pragma unroll
    for (int mt = 0; mt < 4; mt++)
      #pragma unroll
      for (int r = 0; r < 4; r++) {
        int row = bm + wr * 64 + mt * 16 + 4 * lg + r;
        int b = row >> 13, n = row & (N_ - 1);
        dst[(((size_t)(b * H_ + h) * N_ + n) << 6) + d] = f2bf(acc[mt][nt][r]);
      }
  }
}

// ---------------- MFMA GEMM: out = oh @ woutT^T + bias + resid (f32 out) ----------------
__global__ __launch_bounds__(256, 2) void mfma_out(const unsigned short* __restrict__ oh,
    const unsigned short* __restrict__ wT, const float* __restrict__ bias,
    const float* __restrict__ resid, float* __restrict__ out)
{
  __shared__ unsigned short As[128][72];
  __shared__ unsigned short Bs[128][72];
  int tid = threadIdx.x;
  int bn = blockIdx.x * 128, bm = blockIdx.y * 128;
  int wid = tid >> 6, lane = tid & 63;
  int wr = wid >> 1, wc = wid & 1;
  int lr = lane & 15, lg = lane >> 4;
  const f32x4 zf = {0.f, 0.f, 0.f, 0.f};
  f32x4 acc[4][4];
  #pragma unroll
  for (int mt = 0; mt < 4; mt++)
    #pragma unroll
    for (int nt = 0; nt < 4; nt++) acc[mt][nt] = zf;

  for (int k0 = 0; k0 < INNER_; k0 += 64) {
    __syncthreads();
    #pragma unroll
    for (int rnd = 0; rnd < 4; rnd++) {
      int idx = rnd * 2048 + tid * 8;
      int row = idx >> 6, col = idx & 63;
      *reinterpret_cast<bf16x8*>(&As[row][col]) =
          *reinterpret_cast<const bf16x8*>(&oh[((size_t)(bm + row) << 9) + k0 + col]);
      *reinterpret_cast<bf16x8*>(&Bs[row][col]) =
          *reinterpret_cast<const bf16x8*>(&wT[(size_t)(bn + row) * INNER_ + k0 + col]);
    }
    __syncthreads();
    bf16x8 af[4][2], bfr[4][2];
    #pragma unroll
    for (int mt = 0; mt < 4; mt++) {
      af[mt][0] = *reinterpret_cast<const bf16x8*>(&As[wr * 64 + mt * 16 + lr][lg * 8]);
      af[mt][1] = *reinterpret_cast<const bf16x8*>(&As[wr * 64 + mt * 16 + lr][32 + lg * 8]);
    }
    #pragma unroll
    for (int nt = 0; nt < 4; nt++) {
      bfr[nt][0] = *reinterpret_cast<const bf16x8*>(&Bs[wc * 64 + nt * 16 + lr][lg * 8]);
      bfr[nt][1] = *reinterpret_cast<const bf16x8*>(&Bs[wc * 64 + nt * 16 + lr][32 + lg * 8]);
    }
    #pragma unroll
    for (int mt = 0; mt < 4; mt++)
      #pragma unroll
      for (int nt = 0; nt < 4; nt++) {
        acc[mt][nt] = __builtin_amdgcn_mfma_f32_16x16x32_bf16(af[mt][0], bfr[nt][0], acc[mt][nt], 0, 0, 0);
        acc[mt][nt] = __builtin_amdgcn_mfma_f32_16x16x32_bf16(af[mt][1], bfr[nt][1], acc[mt][nt], 0, 0, 0);
      }
  }
  #pragma unroll
  for (int nt = 0; nt < 4; nt++) {
    int c = bn + wc * 64 + nt * 16 + lr;
    float bias_c = bias[c];
    #pragma unroll
    for (int mt = 0; mt < 4; mt++)
      #pragma unroll
      for (int r = 0; r < 4; r++) {
        int row = bm + wr * 64 + mt * 16 + 4 * lg + r;
        out[(size_t)row * DIM_ + c] = acc[mt][nt][r] + bias_c + resid[(size_t)row * DIM_ + c];
      }
  }
}

// ---------------- landmark means (f32 + bf16 q_l, bf16 k_l) ----------------
__global__ __launch_bounds__(64) void landmark_kernel(const unsigned short* __restrict__ qb,
    const unsigned short* __restrict__ kb, float* __restrict__ ql, float* __restrict__ kl,
    unsigned short* __restrict__ qlb, unsigned short* __restrict__ klb)
{
  int id = blockIdx.x;
  int m = id & (M_ - 1);
  int bh = id >> 8;
  int d = threadIdx.x;
  size_t base = (((size_t)bh * N_ + m * L_) << 6) + d;
  float sq = 0, sk = 0;
  #pragma unroll 4
  for (int j = 0; j < L_; j++) {
    sq += bf2f(qb[base + ((size_t)j << 6)]);
    sk += bf2f(kb[base + ((size_t)j << 6)]);
  }
  float qv = sq * (1.f / L_);
  float kv = sk * (1.f / L_);
  size_t o = ((size_t)bh * M_ + m) * DH_ + d;
  ql[o] = qv;
  kl[o] = kv;
  qlb[o] = f2bf(qv);
  klb[o] = f2bf(kv);
}

// ---------------- sim2 + softmax -> attn2 (f32 + hi/lo split) ----------------
__global__ __launch_bounds__(256) void attn2_kernel(const float* __restrict__ ql,
    const float* __restrict__ kl, float* __restrict__ a2,
    unsigned short* __restrict__ a2h, unsigned short* __restrict__ a2l)
{
  int id = blockIdx.x;
  int i = id & (M_ - 1);
  int bh = id >> 8;
  int j = threadIdx.x;
  __shared__ float qs[DH_];
  __shared__ float wred[4];
  if (j < DH_) qs[j] = ql[((size_t)bh * M_ + i) * DH_ + j];
  __syncthreads();
  const float* krow = kl + ((size_t)bh * M_ + j) * DH_;
  float s = 0;
  #pragma unroll
  for (int d = 0; d < DH_; d++) s += qs[d] * krow[d];
  float mx = s;
  #pragma unroll
  for (int off = 1; off < 64; off <<= 1) mx = fmaxf(mx, __shfl_xor(mx, off));
  int wid = j >> 6, lane = j & 63;
  if (lane == 0) wred[wid] = mx;
  __syncthreads();
  mx = fmaxf(fmaxf(wred[0], wred[1]), fmaxf(wred[2], wred[3]));
  float e = __expf(s - mx);
  float sum = e;
  #pragma unroll
  for (int off = 1; off < 64; off <<= 1) sum += __shfl_xor(sum, off);
  __syncthreads();
  if (lane == 0) wred[wid] = sum;
  __syncthreads();
  sum = wred[0] + wred[1] + wred[2] + wred[3];
  float p = e / sum;
  size_t o = ((size_t)bh * M_ + i) * M_ + j;
  a2[o] = p;
  unsigned short h, l;
  split2(p, h, l);
  a2h[o] = h;
  a2l[o] = l;
}

// ---------------- pinv scale ----------------
__global__ void zero_scal(unsigned int* scal) { scal[threadIdx.x] = 0u; }

__global__ __launch_bounds__(256) void pinv_scale_kernel(const float* __restrict__ a2,
    unsigned int* __restrict__ scal)
{
  int bh = blockIdx.x;
  int t = threadIdx.x;
  const float* xb = a2 + (size_t)bh * M_ * M_;
  float rowsum = 0, colsum = 0;
  for (int j = 0; j < M_; j++) {
    rowsum += xb[(size_t)t * M_ + j];
    colsum += xb[(size_t)j * M_ + t];
  }
  #pragma unroll
  for (int off = 1; off < 64; off <<= 1) {
    rowsum = fmaxf(rowsum, __shfl_xor(rowsum, off));
    colsum = fmaxf(colsum, __shfl_xor(colsum, off));
  }
  __shared__ float wr[4], wc[4];
  int wid = t >> 6, lane = t & 63;
  if (lane == 0) { wr[wid] = rowsum; wc[wid] = colsum; }
  __syncthreads();
  if (t == 0) {
    float rm = fmaxf(fmaxf(wr[0], wr[1]), fmaxf(wr[2], wr[3]));
    float cm = fmaxf(fmaxf(wc[0], wc[1]), fmaxf(wc[2], wc[3]));
    atomicMax(&scal[0], __float_as_uint(rm));
    atomicMax(&scal[1], __float_as_uint(cm));
  }
}

// ---------------- z0 = a2^T / s -> row-split via LDS tile transpose (coalesced) ----------------
__global__ __launch_bounds__(256) void zinit_kernel(const float* __restrict__ a2,
    const unsigned int* __restrict__ scal,
    unsigned short* __restrict__ zRh, unsigned short* __restrict__ zRl)
{
  __shared__ float T[64][65];
  int j0 = blockIdx.x * 64, i0 = blockIdx.y * 64;
  size_t bb = (size_t)blockIdx.z * (M_ * M_);
  float inv = 1.f / (__uint_as_float(scal[0]) * __uint_as_float(scal[1]));
  int tid = threadIdx.x;
  #pragma unroll 4
  for (int pass = 0; pass < 16; pass++) {
    int idx = pass * 256 + tid;
    int ii = idx >> 6, jj = idx & 63;
    T[ii][jj] = a2[bb + (size_t)(i0 + ii) * M_ + j0 + jj];
  }
  __syncthreads();
  #pragma unroll 4
  for (int pass = 0; pass < 16; pass++) {
    int idx = pass * 256 + tid;
    int jj = idx >> 6, ii = idx & 63;
    float v = T[ii][jj] * inv;   // z0[j][i] = a2[i][j] * inv
    unsigned short h, l;
    split2(v, h, l);
    zRh[bb + (size_t)(j0 + jj) * M_ + i0 + ii] = h;
    zRl[bb + (size_t)(j0 + jj) * M_ + i0 + ii] = l;
  }
}

// ---------------- batched split-bf16 MFMA GEMM (all row-major, LDS-staged) ----------------
// C = A @ B. Outputs (both optional, row-split): R = sR*C ; Y = aY*I + sY*C.
__global__ __launch_bounds__(256, 2) void bgemm_ns(
    const unsigned short* __restrict__ Ah, const unsigned short* __restrict__ Al,
    const unsigned short* __restrict__ Bh, const unsigned short* __restrict__ Bl,
    unsigned short* __restrict__ Rh, unsigned short* __restrict__ Rl,
    unsigned short* __restrict__ Yh, unsigned short* __restrict__ Yl,
    float aY, float sY, float sR)
{
  __shared__ unsigned short Ash[64][72], Asl[64][72];   // [row][k]
  __shared__ unsigned short Bsh[64][72], Bsl[64][72];   // [col][k] (transposed at stage)
  int bn = blockIdx.x * 64, bm = blockIdx.y * 64;
  size_t bb = (size_t)blockIdx.z * (M_ * M_);
  int tid = threadIdx.x, wid = tid >> 6, lane = tid & 63;
  int lr = lane & 15, lg = lane >> 4;
  int r0 = wid * 16;
  const f32x4 zf = {0.f, 0.f, 0.f, 0.f};
  f32x4 acc[4];
  #pragma unroll
  for (int nt = 0; nt < 4; nt++) acc[nt] = zf;

  for (int k0 = 0; k0 < M_; k0 += 64) {
    __syncthreads();
    #pragma unroll
    for (int pass = 0; pass < 2; pass++) {
      int idx = pass * 2048 + tid * 8;
      int row = idx >> 6, col = idx & 63;
      *reinterpret_cast<bf16x8*>(&Ash[row][col]) =
          *reinterpret_cast<const bf16x8*>(&Ah[bb + (size_t)(bm + row) * M_ + k0 + col]);
      *reinterpret_cast<bf16x8*>(&Asl[row][col]) =
          *reinterpret_cast<const bf16x8*>(&Al[bb + (size_t)(bm + row) * M_ + k0 + col]);
      bf16x8 bh = *reinterpret_cast<const bf16x8*>(&Bh[bb + (size_t)(k0 + row) * M_ + bn + col]);
      bf16x8 bl = *reinterpret_cast<const bf16x8*>(&Bl[bb + (size_t)(k0 + row) * M_ + bn + col]);
      #pragma unroll
      for (int j = 0; j < 8; j++) {
        Bsh[col + j][row] = (unsigned short)bh[j];
        Bsl[col + j][row] = (unsigned short)bl[j];
      }
    }
    __syncthreads();
    #pragma unroll
    for (int kk = 0; kk < 64; kk += 32) {
      bf16x8 ah = *reinterpret_cast<const bf16x8*>(&Ash[r0 + lr][kk + lg * 8]);
      bf16x8 al = *reinterpret_cast<const bf16x8*>(&Asl[r0 + lr][kk + lg * 8]);
      #pragma unroll
      for (int nt = 0; nt < 4; nt++) {
        bf16x8 bh = *reinterpret_cast<const bf16x8*>(&Bsh[nt * 16 + lr][kk + lg * 8]);
        bf16x8 bl = *reinterpret_cast<const bf16x8*>(&Bsl[nt * 16 + lr][kk + lg * 8]);
        acc[nt] = __builtin_amdgcn_mfma_f32_16x16x32_bf16(ah, bh, acc[nt], 0, 0, 0);
        acc[nt] = __builtin_amdgcn_mfma_f32_16x16x32_bf16(ah, bl, acc[nt], 0, 0, 0);
        acc[nt] = __builtin_amdgcn_mfma_f32_16x16x32_bf16(al, bh, acc[nt], 0, 0, 0);
      }
    }
  }
  #pragma unroll
  for (int nt = 0; nt < 4; nt++) {
    int col = bn + nt * 16 + lr;
    #pragma unroll
    for (int r = 0; r < 4; r++) {
      int row = bm + r0 + 4 * lg + r;
      float v = acc[nt][r];
      if (Rh) {
        unsigned short h, l;
        split2(sR * v, h, l);
        Rh[bb + (size_t)row * M_ + col] = h;
        Rl[bb + (size_t)row * M_ + col] = l;
      }
      if (Yh) {
        float t = sY * v + (row == col ? aY : 0.f);
        unsigned short h, l;
        split2(t, h, l);
        Yh[bb + (size_t)row * M_ + col] = h;
        Yl[bb + (size_t)row * M_ + col] = l;
      }
    }
  }
}

// ---------------- W2 = pinv @ pv -> w2t bf16 [bh][64][256] ----------------
__global__ __launch_bounds__(256) void gemm_w2(
    const unsigned short* __restrict__ zRh, const unsigned short* __restrict__ zRl,
    const unsigned short* __restrict__ pvTh, const unsigned short* __restrict__ pvTl,
    unsigned short* __restrict__ w2t)
{
  int bm = blockIdx.x * 64;
  int batch = blockIdx.y;
  size_t bz = (size_t)batch * (M_ * M_);
  size_t bp = (size_t)batch << 14;
  int tid = threadIdx.x, wid = tid >> 6, lane = tid & 63;
  int lr = lane & 15, lg = lane >> 4;
  int r0 = bm + wid * 16;
  const f32x4 zf = {0.f, 0.f, 0.f, 0.f};
  f32x4 acc[4];
  #pragma unroll
  for (int nt = 0; nt < 4; nt++) acc[nt] = zf;

  #pragma unroll
  for (int k0 = 0; k0 < M_; k0 += 32) {
    bf16x8 ah = *reinterpret_cast<const bf16x8*>(&zRh[bz + (size_t)(r0 + lr) * M_ + k0 + lg * 8]);
    bf16x8 al = *reinterpret_cast<const bf16x8*>(&zRl[bz + (size_t)(r0 + lr) * M_ + k0 + lg * 8]);
    #pragma unroll
    for (int nt = 0; nt < 4; nt++) {
      size_t boff = bp + (size_t)(nt * 16 + lr) * M_ + k0 + lg * 8;
      bf16x8 bh = *reinterpret_cast<const bf16x8*>(&pvTh[boff]);
      bf16x8 bl = *reinterpret_cast<const bf16x8*>(&pvTl[boff]);
      acc[nt] = __builtin_amdgcn_mfma_f32_16x16x32_bf16(ah, bh, acc[nt], 0, 0, 0);
      acc[nt] = __builtin_amdgcn_mfma_f32_16x16x32_bf16(ah, bl, acc[nt], 0, 0, 0);
      acc[nt] = __builtin_amdgcn_mfma_f32_16x16x32_bf16(al, bh, acc[nt], 0, 0, 0);
    }
  }
  #pragma unroll
  for (int nt = 0; nt < 4; nt++) {
    int col = nt * 16 + lr;   // dh
    #pragma unroll
    for (int r = 0; r < 4; r++) {
      int row = r0 + 4 * lg + r;   // m
      w2t[bp + (size_t)col * M_ + row] = f2bf(acc[nt][r]);
    }
  }
}

// ---------------- pv partials: softmax(q_l @ k^T) @ v via MFMA, split over N ----------------
__global__ __launch_bounds__(256) void pv_mfma(
    const unsigned short* __restrict__ kb, const unsigned short* __restrict__ vb,
    const unsigned short* __restrict__ qlb,
    float* __restrict__ pvpart, float2* __restrict__ msbuf)
{
  int slice = blockIdx.x;
  int msp   = blockIdx.y;
  int bh    = blockIdx.z;
  int tid = threadIdx.x, wid = tid >> 6, lane = tid & 63;
  int lr = lane & 15, lg = lane >> 4;

  __shared__ unsigned short klds[64][72];
  __shared__ unsigned short vtld[64][72];
  __shared__ unsigned short plds_all[4][32][72];
  unsigned short (*plds)[72] = plds_all[wid];

  int mbase = msp * 128 + wid * 32;
  const unsigned short* qbase = qlb + (((size_t)bh * M_ + mbase) << 6);
  bf16x8 qf[2][2];
  #pragma unroll
  for (int rt = 0; rt < 2; rt++)
    #pragma unroll
    for (int h2 = 0; h2 < 2; h2++)
      qf[rt][h2] = *reinterpret_cast<const bf16x8*>(&qbase[((rt * 16 + lr) << 6) + h2 * 32 + lg * 8]);

  const f32x4 zf = {0.f, 0.f, 0.f, 0.f};
  f32x4 oacc[2][4];
  #pragma unroll
  for (int rt = 0; rt < 2; rt++)
    #pragma unroll
    for (int dt = 0; dt < 4; dt++) oacc[rt][dt] = zf;
  float mrun[8], srun[8];
  #pragma unroll
  for (int i = 0; i < 8; i++) { mrun[i] = -1e30f; srun[i] = 0.f; }

  const unsigned short* kgb = kb + (((size_t)bh * N_ + slice * 1024) << 6);
  const unsigned short* vgb = vb + (((size_t)bh * N_ + slice * 1024) << 6);

  for (int c = 0; c < 16; c++) {
    __syncthreads();
    for (int u = tid; u < 512; u += 256) {
      int key = u >> 3, seg = u & 7;
      size_t goff = (((size_t)(c * 64 + key)) << 6) + seg * 8;
      bf16x8 kv = *reinterpret_cast<const bf16x8*>(&kgb[goff]);
      *reinterpret_cast<bf16x8*>(&klds[key][seg * 8]) = kv;
      bf16x8 vv = *reinterpret_cast<const bf16x8*>(&vgb[goff]);
      int col = key ^ (seg << 3);
      #pragma unroll
      for (int j = 0; j < 8; j++) vtld[seg * 8 + j][col] = (unsigned short)vv[j];
    }
    __syncthreads();
    f32x4 sacc[2][4];
    #pragma unroll
    for (int rt = 0; rt < 2; rt++)
      #pragma unroll
      for (int ct = 0; ct < 4; ct++) {
        bf16x8 b0 = *reinterpret_cast<const bf16x8*>(&klds[ct * 16 + lr][lg * 8]);
        bf16x8 b1 = *reinterpret_cast<const bf16x8*>(&klds[ct * 16 + lr][32 + lg * 8]);
        f32x4 a = __builtin_amdgcn_mfma_f32_16x16x32_bf16(qf[rt][0], b0, zf, 0, 0, 0);
        sacc[rt][ct] = __builtin_amdgcn_mfma_f32_16x16x32_bf16(qf[rt][1], b1, a, 0, 0, 0);
      }
    #pragma unroll
    for (int rt = 0; rt < 2; rt++)
      #pragma unroll
      for (int r = 0; r < 4; r++) {
        int ri = rt * 4 + r;
        float mc = fmaxf(fmaxf(sacc[rt][0][r], sacc[rt][1][r]), fmaxf(sacc[rt][2][r], sacc[rt][3][r]));
        #pragma unroll
        for (int off = 1; off < 16; off <<= 1) mc = fmaxf(mc, __shfl_xor(mc, off));
        float mnew = fmaxf(mrun[ri], mc);
        float corr = __expf(mrun[ri] - mnew);
        float psum = 0.f;
        #pragma unroll
        for (int ct = 0; ct < 4; ct++) {
          float p = __expf(sacc[rt][ct][r] - mnew);
          sacc[rt][ct][r] = p;
          psum += p;
        }
        #pragma unroll
        for (int off = 1; off < 16; off <<= 1) psum += __shfl_xor(psum, off);
        srun[ri] = srun[ri] * corr + psum;
        mrun[ri] = mnew;
        #pragma unroll
        for (int dt = 0; dt < 4; dt++) oacc[rt][dt][r] *= corr;
        #pragma unroll
        for (int ct = 0; ct < 4; ct++)
          plds[rt * 16 + 4 * lg + r][ct * 16 + lr] = f2bf(sacc[rt][ct][r]);
      }
    __builtin_amdgcn_s_waitcnt(0);
    bf16x8 pa[2][2];
    #pragma unroll
    for (int rt = 0; rt < 2; rt++)
      #pragma unroll
      for (int h = 0; h < 2; h++)
        pa[rt][h] = *reinterpret_cast<const bf16x8*>(&plds[rt * 16 + lr][h * 32 + lg * 8]);
    #pragma unroll
    for (int dt = 0; dt < 4; dt++) {
      int d = dt * 16 + lr;
      bf16x8 bv0 = *reinterpret_cast<const bf16x8*>(&vtld[d][(lg * 8) ^ (d & 0x38)]);
      bf16x8 bv1 = *reinterpret_cast<const bf16x8*>(&vtld[d][(32 + lg * 8) ^ (d & 0x38)]);
      #pragma unroll
      for (int rt = 0; rt < 2; rt++) {
        oacc[rt][dt] = __builtin_amdgcn_mfma_f32_16x16x32_bf16(pa[rt][0], bv0, oacc[rt][dt], 0, 0, 0);
        oacc[rt][dt] = __builtin_amdgcn_mfma_f32_16x16x32_bf16(pa[rt][1], bv1, oacc[rt][dt], 0, 0, 0);
      }
    }
  }
  size_t pbase = (((size_t)(bh * 8 + slice) * M_ + mbase) << 6);
  #pragma unroll
  for (int rt = 0; rt < 2; rt++)
    #pragma unroll
    for (int dt = 0; dt < 4; dt++)
      #pragma unroll
      for (int r = 0; r < 4; r++)
        pvpart[pbase + ((size_t)(rt * 16 + 4 * lg + r) << 6) + dt * 16 + lr] = oacc[rt][dt][r];
  if (lr == 0) {
    #pragma unroll
    for (int rt = 0; rt < 2; rt++)
      #pragma unroll
      for (int r = 0; r < 4; r++)
        msbuf[(size_t)(bh * 8 + slice) * M_ + mbase + rt * 16 + 4 * lg + r] =
            make_float2(mrun[rt * 4 + r], srun[rt * 4 + r]);
  }
}

// ---------------- combine split-N partials -> pv^T split bf16 [bh][64][256] ----------------
__global__ __launch_bounds__(256) void pv_combine(const float* __restrict__ pvpart,
    const float2* __restrict__ msbuf,
    unsigned short* __restrict__ pvTh, unsigned short* __restrict__ pvTl)
{
  int row = blockIdx.x * 4 + (threadIdx.x >> 6);
  int bh = row >> 8, m = row & (M_ - 1);
  int d = threadIdx.x & 63;
  float2 ms[8];
  float mg = -1e30f;
  #pragma unroll
  for (int s = 0; s < 8; s++) {
    ms[s] = msbuf[(size_t)(bh * 8 + s) * M_ + m];
    mg = fmaxf(mg, ms[s].x);
  }
  float ssum = 0.f, o = 0.f;
  #pragma unroll
  for (int s = 0; s < 8; s++) {
    float w = __expf(ms[s].x - mg);
    ssum += ms[s].y * w;
    o += w * pvpart[(((size_t)(bh * 8 + s) * M_ + m) << 6) + d];
  }
  float val = o / ssum;
  unsigned short h, l;
  split2(val, h, l);
  size_t oi = ((size_t)bh << 14) + (size_t)d * M_ + m;
  pvTh[oi] = h;
  pvTl[oi] = l;
}

// ---------------- attn1: oh = softmax(q @ kl^T) @ W2 via MFMA ----------------
__global__ __launch_bounds__(256) void attn1_kernel(
    const unsigned short* __restrict__ qb,
    const unsigned short* __restrict__ klb,
    const unsigned short* __restrict__ w2t,
    unsigned short* __restrict__ oh)
{
  int ntile = blockIdx.x & 31;
  int bh = blockIdx.x >> 5;
  int h = bh & (H_ - 1), b = bh >> 3;
  int tid = threadIdx.x, wid = tid >> 6, lane = tid & 63;
  int lr = lane & 15, lg = lane >> 4;
  __shared__ unsigned short plds_all[4][16][264];
  unsigned short* plds = &plds_all[wid][0][0];

  const unsigned short* qbh  = qb  + (((size_t)bh * N_) << 6);
  const unsigned short* klbh = klb + ((size_t)bh << 14);
  const unsigned short* w2bh = w2t + ((size_t)bh << 14);

  const f32x4 zf = {0.f, 0.f, 0.f, 0.f};
  for (int sub = 0; sub < 4; sub++) {
    int n0 = ntile * 256 + sub * 64 + wid * 16;
    bf16x8 aq0 = *reinterpret_cast<const bf16x8*>(&qbh[((size_t)(n0 + lr) << 6) + lg * 8]);
    bf16x8 aq1 = *reinterpret_cast<const bf16x8*>(&qbh[((size_t)(n0 + lr) << 6) + 32 + lg * 8]);
    f32x4 accs[16];
    #pragma unroll
    for (int mt = 0; mt < 16; mt++) {
      bf16x8 b0 = *reinterpret_cast<const bf16x8*>(&klbh[((size_t)(mt * 16 + lr) << 6) + lg * 8]);
      bf16x8 b1 = *reinterpret_cast<const bf16x8*>(&klbh[((size_t)(mt * 16 + lr) << 6) + 32 + lg * 8]);
      f32x4 a = __builtin_amdgcn_mfma_f32_16x16x32_bf16(aq0, b0, zf, 0, 0, 0);
      accs[mt] = __builtin_amdgcn_mfma_f32_16x16x32_bf16(aq1, b1, a, 0, 0, 0);
    }
    float rs[4];
    #pragma unroll
    for (int r = 0; r < 4; r++) {
      float m0 = accs[0][r];
      #pragma unroll
      for (int mt = 1; mt < 16; mt++) m0 = fmaxf(m0, accs[mt][r]);
      #pragma unroll
      for (int off = 1; off < 16; off <<= 1) m0 = fmaxf(m0, __shfl_xor(m0, off));
      float s0 = 0.f;
      #pragma unroll
      for (int mt = 0; mt < 16; mt++) {
        float p = __expf(accs[mt][r] - m0);
        accs[mt][r] = p;
        s0 += p;
      }
      #pragma unroll
      for (int off = 1; off < 16; off <<= 1) s0 += __shfl_xor(s0, off);
      rs[r] = 1.f / s0;
    }
    #pragma unroll
    for (int mt = 0; mt < 16; mt++)
      #pragma unroll
      for (int r = 0; r < 4; r++)
        plds[(4 * lg + r) * 264 + mt * 16 + lr] = f2bf(accs[mt][r]);
    __builtin_amdgcn_s_waitcnt(0);
    bf16x8 pa[8];
    #pragma unroll
    for (int mc = 0; mc < 8; mc++)
      pa[mc] = *reinterpret_cast<const bf16x8*>(&plds[lr * 264 + mc * 32 + lg * 8]);
    f32x4 acco[4];
    #pragma unroll
    for (int dt = 0; dt < 4; dt++) {
      f32x4 a = zf;
      #pragma unroll
      for (int mc = 0; mc < 8; mc++) {
        bf16x8 wf = *reinterpret_cast<const bf16x8*>(&w2bh[(size_t)(dt * 16 + lr) * M_ + mc * 32 + lg * 8]);
        a = __builtin_amdgcn_mfma_f32_16x16x32_bf16(pa[mc], wf, a, 0, 0, 0);
      }
      acco[dt] = a;
    }
    #pragma unroll
    for (int dt = 0; dt < 4; dt++)
      #pragma unroll
      for (int r = 0; r < 4; r++) {
        int n = n0 + 4 * lg + r;
        oh[((size_t)(b * N_ + n) << 9) + h * DH_ + dt * 16 + lr] = f2bf(acco[dt][r] * rs[r]);
      }
  }
}

// ---------------- depthwise conv residual: register sliding window ----------------
__global__ __launch_bounds__(256) void conv_kernel(const unsigned short* __restrict__ vb,
    const float* __restrict__ rw, unsigned short* __restrict__ oh)
{
  int bh = blockIdx.y;
  int h = bh & (H_ - 1), b = bh >> 3;
  int d = threadIdx.x & 63, g = threadIdx.x >> 6;
  int n0 = blockIdx.x * 128 + g * 32;
  const unsigned short* vbb = vb + (((size_t)bh * N_) << 6) + d;
  float w[64];
  #pragma unroll
  for (int j = 0; j < 64; j++) {
    int nn = n0 - 16 + j;
    w[j] = (nn >= 0 && nn < N_) ? bf2f(vbb[(size_t)nn << 6]) : 0.f;
  }
  float rwr[RESK_];
  #pragma unroll
  for (int j = 0; j < RESK_; j++) rwr[j] = rw[h * RESK_ + j];
  size_t obase = (((size_t)(b * N_ + n0)) << 9) + h * 64 + d;
  #pragma unroll
  for (int t = 0; t < 32; t++) {
    float acc = 0.f;
    #pragma unroll
    for (int j = 0; j < RESK_; j++) acc += rwr[j] * w[t + j];
    size_t oi = obase + ((size_t)t << 9);
    oh[oi] = f2bf(bf2f(oh[oi]) + acc);
  }
}

extern "C" void kernel_launch(void* const* d_in, const int* in_sizes, int n_in,
                              void* d_out, int out_size, void* d_ws, size_t ws_size,
                              hipStream_t stream)
{
  const float* x     = (const float*)d_in[0];
  const float* ln_w  = (const float*)d_in[1];
  const float* ln_b  = (const float*)d_in[2];
  const float* w_qkv = (const float*)d_in[3];
  const float* w_out = (const float*)d_in[4];
  const float* b_out = (const float*)d_in[5];
  const float* res_w = (const float*)d_in[6];
  float* out = (float*)d_out;

  const size_t HEADEL = (size_t)B_ * H_ * N_ * DH_;   // 16,777,216
  const size_t SMALL  = (size_t)B_ * H_ * M_ * DH_;   // 524,288
  const size_t MSQ    = (size_t)B_ * H_ * M_ * M_;    // 2,097,152

  char* p = (char*)d_ws;
  auto alloc = [&](size_t bytes) { char* r = p; p += (bytes + 255) & ~(size_t)255; return r; };

  unsigned short* qb  = (unsigned short*)alloc(HEADEL * 2);
  unsigned short* kb  = (unsigned short*)alloc(HEADEL * 2);
  unsigned short* vb  = (unsigned short*)alloc(HEADEL * 2);
  unsigned short* oh  = (unsigned short*)alloc(HEADEL * 2);
  // union A: xnb (32 MB) then z ping-pong row-splits (4 x 4 MB)
  char* unA = alloc(HEADEL * 2);
  unsigned short* xnb  = (unsigned short*)unA;
  unsigned short* z0Rh = (unsigned short*)unA;
  unsigned short* z0Rl = z0Rh + MSQ;
  unsigned short* z1Rh = z0Rl + MSQ;
  unsigned short* z1Rl = z1Rh + MSQ;
  // union B: pvpart f32 (16 MB) + msbuf then u/v/w/y row-splits (8 x 4 MB)
  char* unB = alloc(HEADEL * 2);
  float*  pvpart = (float*)unB;
  float2* msbuf  = (float2*)(unB + (size_t)B_ * H_ * 8 * M_ * DH_ * 4);
  unsigned short* uh = (unsigned short*)unB;
  unsigned short* ul = uh + MSQ;
  unsigned short* vh = ul + MSQ;
  unsigned short* vl = vh + MSQ;
  unsigned short* wh = vl + MSQ;
  unsigned short* wl = wh + MSQ;
  unsigned short* yh = wl + MSQ;
  unsigned short* yl = yh + MSQ;

  unsigned short* wqkvT = (unsigned short*)alloc((size_t)K3_ * DIM_ * 2);
  unsigned short* woutT = (unsigned short*)alloc((size_t)DIM_ * INNER_ * 2);
  float* ql  = (float*)alloc(SMALL * 4);
  float* kl  = (float*)alloc(SMALL * 4);
  unsigned short* qlb  = (unsigned short*)alloc(SMALL * 2);
  unsigned short* klb  = (unsigned short*)alloc(SMALL * 2);
  unsigned short* pvTh = (unsigned short*)alloc(SMALL * 2);
  unsigned short* pvTl = (unsigned short*)alloc(SMALL * 2);
  unsigned short* w2t  = (unsigned short*)alloc(SMALL * 2);
  unsigned short* a2h  = (unsigned short*)alloc(MSQ * 2);
  unsigned short* a2l  = (unsigned short*)alloc(MSQ * 2);
  unsigned int* scal   = (unsigned int*)alloc(256);
  if ((size_t)(p - (char*)d_ws) > ws_size) return;

  float* a2 = (float*)d_out;   // 8 MB, dead before mfma_out overwrites d_out

  ln_bf16<<<B_ * N_, 256, 0, stream>>>(x, ln_w, ln_b, xnb);
  transpose_w<<<dim3(K3_ / 64, DIM_ / 64), 256, 0, stream>>>(w_qkv, wqkvT, DIM_, K3_, INNER_, 0.125f);
  transpose_w<<<dim3(DIM_ / 64, INNER_ / 64), 256, 0, stream>>>(w_out, woutT, INNER_, DIM_, 0, 1.f);
  mfma_qkv<<<dim3(K3_ / 128, (B_ * N_) / 128), 256, 0, stream>>>(xnb, wqkvT, qb, kb, vb);
  landmark_kernel<<<B_ * H_ * M_, 64, 0, stream>>>(qb, kb, ql, kl, qlb, klb);
  attn2_kernel<<<B_ * H_ * M_, 256, 0, stream>>>(ql, kl, a2, a2h, a2l);
  zero_scal<<<1, 2, 0, stream>>>(scal);
  pinv_scale_kernel<<<B_ * H_, 256, 0, stream>>>(a2, scal);
  pv_mfma<<<dim3(8, 2, B_ * H_), 256, 0, stream>>>(kb, vb, qlb, pvpart, msbuf);
  pv_combine<<<(B_ * H_ * M_) / 4, 256, 0, stream>>>(pvpart, msbuf, pvTh, pvTl);
  // zinit AFTER mfma_qkv (xnb dead) — writes z0 over xnb region
  zinit_kernel<<<dim3(4, 4, B_ * H_), 256, 0, stream>>>(a2, scal, z0Rh, z0Rl);

  // Newton-Schulz chain, all row-major split-bf16 (u/v/w/y overwrite pvpart — pv done)
  unsigned short *cRh = z0Rh, *cRl = z0Rl;
  unsigned short *nRh = z1Rh, *nRl = z1Rl;
  dim3 g44(4, 4, B_ * H_);
  for (int it = 0; it < 6; it++) {
    // u = a2 @ z ; v = 7I - u
    bgemm_ns<<<g44, 256, 0, stream>>>(a2h, a2l, cRh, cRl, uh, ul, vh, vl, 7.f, -1.f, 1.f);
    // t = u @ v ; w = 15I - t
    bgemm_ns<<<g44, 256, 0, stream>>>(uh, ul, vh, vl, nullptr, nullptr, wh, wl, 15.f, -1.f, 0.f);
    // t2 = u @ w ; y = 13I - t2
    bgemm_ns<<<g44, 256, 0, stream>>>(uh, ul, wh, wl, nullptr, nullptr, yh, yl, 13.f, -1.f, 0.f);
    // z' = 0.25 * z @ y
    bgemm_ns<<<g44, 256, 0, stream>>>(cRh, cRl, yh, yl, nRh, nRl, nullptr, nullptr, 0.f, 0.f, 0.25f);
    unsigned short* t;
    t = cRh; cRh = nRh; nRh = t;  t = cRl; cRl = nRl; nRl = t;
  }

  gemm_w2<<<dim3(4, B_ * H_), 256, 0, stream>>>(cRh, cRl, pvTh, pvTl, w2t);

  attn1_kernel<<<B_ * H_ * (N_ / 256), 256, 0, stream>>>(qb, klb, w2t, oh);
  conv_kernel<<<dim3(N_ / 128, B_ * H_), 256, 0, stream>>>(vb, res_w, oh);
  mfma_out<<<dim3(DIM_ / 128, (B_ * N_) / 128), 256, 0, stream>>>(oh, woutT, b_out, x, out);
}

// Round 8
// 786.716 us; speedup vs baseline: 6.5631x; 1.1264x over previous
//
#include <hip/hip_runtime.h>
#include <cstdint>

#define B_ 4
#define N_ 8192
#define DIM_ 512
#define H_ 8
#define DH_ 64
#define M_ 256
#define L_ 32
#define INNER_ 512
#define K3_ 1536
#define RESK_ 33

struct __align__(16) ushort8_t { unsigned short u[8]; };
typedef short bf16x8 __attribute__((ext_vector_type(8)));
typedef float f32x4 __attribute__((ext_vector_type(4)));

__device__ __forceinline__ float bf2f(unsigned short u) {
  return __uint_as_float(((unsigned)u) << 16);
}
__device__ __forceinline__ unsigned short f2bf(float f) {
  unsigned x = __float_as_uint(f);
  return (unsigned short)((x + 0x7fffu + ((x >> 16) & 1u)) >> 16);  // RNE
}
__device__ __forceinline__ void split2(float x, unsigned short& h, unsigned short& l) {
  h = f2bf(x);
  l = f2bf(x - bf2f(h));
}

// ---------------- fused LayerNorm -> bf16 activations ----------------
__global__ __launch_bounds__(256) void ln_bf16(const float* __restrict__ x,
    const float* __restrict__ w, const float* __restrict__ bb, unsigned short* __restrict__ xnb)
{
  int row = blockIdx.x;
  int tid = threadIdx.x;
  float2 v = reinterpret_cast<const float2*>(x + (size_t)row * DIM_)[tid];
  float s = v.x + v.y, s2 = v.x * v.x + v.y * v.y;
  #pragma unroll
  for (int off = 32; off; off >>= 1) { s += __shfl_down(s, off); s2 += __shfl_down(s2, off); }
  __shared__ float rs[4], rs2[4];
  int wid = tid >> 6, lane = tid & 63;
  if (lane == 0) { rs[wid] = s; rs2[wid] = s2; }
  __syncthreads();
  float ts = rs[0] + rs[1] + rs[2] + rs[3];
  float ts2 = rs2[0] + rs2[1] + rs2[2] + rs2[3];
  float mu = ts * (1.f / DIM_);
  float var = ts2 * (1.f / DIM_) - mu * mu;
  float inv = rsqrtf(var + 1e-5f);
  int c = tid * 2;
  unsigned int p0 = f2bf((v.x - mu) * inv * w[c] + bb[c]);
  unsigned int p1 = f2bf((v.y - mu) * inv * w[c + 1] + bb[c + 1]);
  reinterpret_cast<unsigned int*>(xnb + (size_t)row * DIM_)[tid] = p0 | (p1 << 16);
}

// ---------------- transpose weights to bf16 ----------------
__global__ __launch_bounds__(256) void transpose_w(const float* __restrict__ src,
    unsigned short* __restrict__ dst, int K, int C, int qcols, float qs)
{
  __shared__ float T[64][65];
  int c0 = blockIdx.x * 64, k0 = blockIdx.y * 64;
  #pragma unroll 4
  for (int it = 0; it < 16; it++) {
    int idx = it * 256 + threadIdx.x;
    int kk = idx >> 6, cc = idx & 63;
    T[kk][cc] = src[(size_t)(k0 + kk) * C + c0 + cc];
  }
  __syncthreads();
  #pragma unroll 4
  for (int it = 0; it < 16; it++) {
    int idx = it * 256 + threadIdx.x;
    int cc = idx >> 6, kk = idx & 63;
    float v = T[kk][cc];
    int c = c0 + cc;
    dst[(size_t)c * K + k0 + kk] = f2bf(c < qcols ? v * qs : v);
  }
}

// ---------------- MFMA GEMM: qkv = xnb @ wT^T, scatter head-major bf16 ----------------
__global__ __launch_bounds__(256, 2) void mfma_qkv(const unsigned short* __restrict__ xnb,
    const unsigned short* __restrict__ wT,
    unsigned short* __restrict__ qb, unsigned short* __restrict__ kb, unsigned short* __restrict__ vb)
{
  __shared__ unsigned short As[128][72];
  __shared__ unsigned short Bs[128][72];
  int tid = threadIdx.x;
  int bn = blockIdx.x * 128, bm = blockIdx.y * 128;
  int wid = tid >> 6, lane = tid & 63;
  int wr = wid >> 1, wc = wid & 1;
  int lr = lane & 15, lg = lane >> 4;
  const f32x4 zf = {0.f, 0.f, 0.f, 0.f};
  f32x4 acc[4][4];
  #pragma unroll
  for (int mt = 0; mt < 4; mt++)
    #pragma unroll
    for (int nt = 0; nt < 4; nt++) acc[mt][nt] = zf;

  for (int k0 = 0; k0 < DIM_; k0 += 64) {
    __syncthreads();
    #pragma unroll
    for (int rnd = 0; rnd < 4; rnd++) {
      int idx = rnd * 2048 + tid * 8;
      int row = idx >> 6, col = idx & 63;
      *reinterpret_cast<bf16x8*>(&As[row][col]) =
          *reinterpret_cast<const bf16x8*>(&xnb[(size_t)(bm + row) * DIM_ + k0 + col]);
      *reinterpret_cast<bf16x8*>(&Bs[row][col]) =
          *reinterpret_cast<const bf16x8*>(&wT[(size_t)(bn + row) * DIM_ + k0 + col]);
    }
    __syncthreads();
    bf16x8 af[4][2], bfr[4][2];
    #pragma unroll
    for (int mt = 0; mt < 4; mt++) {
      af[mt][0] = *reinterpret_cast<const bf16x8*>(&As[wr * 64 + mt * 16 + lr][lg * 8]);
      af[mt][1] = *reinterpret_cast<const bf16x8*>(&As[wr * 64 + mt * 16 + lr][32 + lg * 8]);
    }
    #pragma unroll
    for (int nt = 0; nt < 4; nt++) {
      bfr[nt][0] = *reinterpret_cast<const bf16x8*>(&Bs[wc * 64 + nt * 16 + lr][lg * 8]);
      bfr[nt][1] = *reinterpret_cast<const bf16x8*>(&Bs[wc * 64 + nt * 16 + lr][32 + lg * 8]);
    }
    #pragma unroll
    for (int mt = 0; mt < 4; mt++)
      #pragma unroll
      for (int nt = 0; nt < 4; nt++) {
        acc[mt][nt] = __builtin_amdgcn_mfma_f32_16x16x32_bf16(af[mt][0], bfr[nt][0], acc[mt][nt], 0, 0, 0);
        acc[mt][nt] = __builtin_amdgcn_mfma_f32_16x16x32_bf16(af[mt][1], bfr[nt][1], acc[mt][nt], 0, 0, 0);
      }
  }
  #pragma unroll
  for (int nt = 0; nt < 4; nt++) {
    int c = bn + wc * 64 + nt * 16 + lr;
    int which = c >> 9;
    int h = (c >> 6) & (H_ - 1);
    int d = c & 63;
    unsigned short* dst = which == 0 ? qb : (which == 1 ? kb : vb);
    #pragma unroll
    for (int mt = 0; mt < 4; mt++)
      #pragma unroll
      for (int r = 0; r < 4; r++) {
        int row = bm + wr * 64 + mt * 16 + 4 * lg + r;
        int b = row >> 13, n = row & (N_ - 1);
        dst[(((size_t)(b * H_ + h) * N_ + n) << 6) + d] = f2bf(acc[mt][nt][r]);
      }
  }
}

// ---------------- MFMA GEMM: out = oh @ woutT^T + bias + resid (f32 out) ----------------
__global__ __launch_bounds__(256, 2) void mfma_out(const unsigned short* __restrict__ oh,
    const unsigned short* __restrict__ wT, const float* __restrict__ bias,
    const float* __restrict__ resid, float* __restrict__ out)
{
  __shared__ unsigned short As[128][72];
  __shared__ unsigned short Bs[128][72];
  int tid = threadIdx.x;
  int bn = blockIdx.x * 128, bm = blockIdx.y * 128;
  int wid = tid >> 6, lane = tid & 63;
  int wr = wid >> 1, wc = wid & 1;
  int lr = lane & 15, lg = lane >> 4;
  const f32x4 zf = {0.f, 0.f, 0.f, 0.f};
  f32x4 acc[4][4];
  #pragma unroll
  for (int mt = 0; mt < 4; mt++)
    #pragma unroll
    for (int nt = 0; nt < 4; nt++) acc[mt][nt] = zf;

  for (int k0 = 0; k0 < INNER_; k0 += 64) {
    __syncthreads();
    #pragma unroll
    for (int rnd = 0; rnd < 4; rnd++) {
      int idx = rnd * 2048 + tid * 8;
      int row = idx >> 6, col = idx & 63;
      *reinterpret_cast<bf16x8*>(&As[row][col]) =
          *reinterpret_cast<const bf16x8*>(&oh[((size_t)(bm + row) << 9) + k0 + col]);
      *reinterpret_cast<bf16x8*>(&Bs[row][col]) =
          *reinterpret_cast<const bf16x8*>(&wT[(size_t)(bn + row) * INNER_ + k0 + col]);
    }
    __syncthreads();
    bf16x8 af[4][2], bfr[4][2];
    #pragma unroll
    for (int mt = 0; mt < 4; mt++) {
      af[mt][0] = *reinterpret_cast<const bf16x8*>(&As[wr * 64 + mt * 16 + lr][lg * 8]);
      af[mt][1] = *reinterpret_cast<const bf16x8*>(&As[wr * 64 + mt * 16 + lr][32 + lg * 8]);
    }
    #pragma unroll
    for (int nt = 0; nt < 4; nt++) {
      bfr[nt][0] = *reinterpret_cast<const bf16x8*>(&Bs[wc * 64 + nt * 16 + lr][lg * 8]);
      bfr[nt][1] = *reinterpret_cast<const bf16x8*>(&Bs[wc * 64 + nt * 16 + lr][32 + lg * 8]);
    }
    #pragma unroll
    for (int mt = 0; mt < 4; mt++)
      #pragma unroll
      for (int nt = 0; nt < 4; nt++) {
        acc[mt][nt] = __builtin_amdgcn_mfma_f32_16x16x32_bf16(af[mt][0], bfr[nt][0], acc[mt][nt], 0, 0, 0);
        acc[mt][nt] = __builtin_amdgcn_mfma_f32_16x16x32_bf16(af[mt][1], bfr[nt][1], acc[mt][nt], 0, 0, 0);
      }
  }
  #pragma unroll
  for (int nt = 0; nt < 4; nt++) {
    int c = bn + wc * 64 + nt * 16 + lr;
    float bias_c = bias[c];
    #pragma unroll
    for (int mt = 0; mt < 4; mt++)
      #pragma unroll
      for (int r = 0; r < 4; r++) {
        int row = bm + wr * 64 + mt * 16 + 4 * lg + r;
        out[(size_t)row * DIM_ + c] = acc[mt][nt][r] + bias_c + resid[(size_t)row * DIM_ + c];
      }
  }
}

// ---------------- landmark means (f32 + bf16 q_l, bf16 k_l) ----------------
__global__ __launch_bounds__(64) void landmark_kernel(const unsigned short* __restrict__ qb,
    const unsigned short* __restrict__ kb, float* __restrict__ ql, float* __restrict__ kl,
    unsigned short* __restrict__ qlb, unsigned short* __restrict__ klb)
{
  int id = blockIdx.x;
  int m = id & (M_ - 1);
  int bh = id >> 8;
  int d = threadIdx.x;
  size_t base = (((size_t)bh * N_ + m * L_) << 6) + d;
  float sq = 0, sk = 0;
  #pragma unroll 4
  for (int j = 0; j < L_; j++) {
    sq += bf2f(qb[base + ((size_t)j << 6)]);
    sk += bf2f(kb[base + ((size_t)j << 6)]);
  }
  float qv = sq * (1.f / L_);
  float kv = sk * (1.f / L_);
  size_t o = ((size_t)bh * M_ + m) * DH_ + d;
  ql[o] = qv;
  kl[o] = kv;
  qlb[o] = f2bf(qv);
  klb[o] = f2bf(kv);
}

// ---------------- sim2 + softmax -> attn2 (f32 + hi/lo split) ----------------
__global__ __launch_bounds__(256) void attn2_kernel(const float* __restrict__ ql,
    const float* __restrict__ kl, float* __restrict__ a2,
    unsigned short* __restrict__ a2h, unsigned short* __restrict__ a2l)
{
  int id = blockIdx.x;
  int i = id & (M_ - 1);
  int bh = id >> 8;
  int j = threadIdx.x;
  __shared__ float qs[DH_];
  __shared__ float wred[4];
  if (j < DH_) qs[j] = ql[((size_t)bh * M_ + i) * DH_ + j];
  __syncthreads();
  const float* krow = kl + ((size_t)bh * M_ + j) * DH_;
  float s = 0;
  #pragma unroll
  for (int d = 0; d < DH_; d++) s += qs[d] * krow[d];
  float mx = s;
  #pragma unroll
  for (int off = 1; off < 64; off <<= 1) mx = fmaxf(mx, __shfl_xor(mx, off));
  int wid = j >> 6, lane = j & 63;
  if (lane == 0) wred[wid] = mx;
  __syncthreads();
  mx = fmaxf(fmaxf(wred[0], wred[1]), fmaxf(wred[2], wred[3]));
  float e = __expf(s - mx);
  float sum = e;
  #pragma unroll
  for (int off = 1; off < 64; off <<= 1) sum += __shfl_xor(sum, off);
  __syncthreads();
  if (lane == 0) wred[wid] = sum;
  __syncthreads();
  sum = wred[0] + wred[1] + wred[2] + wred[3];
  float p = e / sum;
  size_t o = ((size_t)bh * M_ + i) * M_ + j;
  a2[o] = p;
  unsigned short h, l;
  split2(p, h, l);
  a2h[o] = h;
  a2l[o] = l;
}

// ---------------- pinv scale ----------------
__global__ void zero_scal(unsigned int* scal) { scal[threadIdx.x] = 0u; }

__global__ __launch_bounds__(256) void pinv_scale_kernel(const float* __restrict__ a2,
    unsigned int* __restrict__ scal)
{
  int bh = blockIdx.x;
  int t = threadIdx.x;
  const float* xb = a2 + (size_t)bh * M_ * M_;
  float rowsum = 0, colsum = 0;
  for (int j = 0; j < M_; j++) {
    rowsum += xb[(size_t)t * M_ + j];
    colsum += xb[(size_t)j * M_ + t];
  }
  #pragma unroll
  for (int off = 1; off < 64; off <<= 1) {
    rowsum = fmaxf(rowsum, __shfl_xor(rowsum, off));
    colsum = fmaxf(colsum, __shfl_xor(colsum, off));
  }
  __shared__ float wr[4], wc[4];
  int wid = t >> 6, lane = t & 63;
  if (lane == 0) { wr[wid] = rowsum; wc[wid] = colsum; }
  __syncthreads();
  if (t == 0) {
    float rm = fmaxf(fmaxf(wr[0], wr[1]), fmaxf(wr[2], wr[3]));
    float cm = fmaxf(fmaxf(wc[0], wc[1]), fmaxf(wc[2], wc[3]));
    atomicMax(&scal[0], __float_as_uint(rm));
    atomicMax(&scal[1], __float_as_uint(cm));
  }
}

// ---------------- z0 = a2^T/s: row-split (LDS transpose) + T-split (direct copy) ----------------
// z0[m][k] = a2[k][m]*inv ; zT stores z0^T = a2*inv directly (coalesced both ways).
__global__ __launch_bounds__(256) void zinit_kernel(const float* __restrict__ a2,
    const unsigned int* __restrict__ scal,
    unsigned short* __restrict__ zRh, unsigned short* __restrict__ zRl,
    unsigned short* __restrict__ zTh, unsigned short* __restrict__ zTl)
{
  __shared__ float T[64][65];
  int j0 = blockIdx.x * 64, i0 = blockIdx.y * 64;
  size_t bb = (size_t)blockIdx.z * (M_ * M_);
  float inv = 1.f / (__uint_as_float(scal[0]) * __uint_as_float(scal[1]));
  int tid = threadIdx.x;
  #pragma unroll 4
  for (int pass = 0; pass < 16; pass++) {
    int idx = pass * 256 + tid;
    int ii = idx >> 6, jj = idx & 63;
    float v = a2[bb + (size_t)(i0 + ii) * M_ + j0 + jj];
    T[ii][jj] = v;
    unsigned short h, l;
    split2(v * inv, h, l);
    zTh[bb + (size_t)(i0 + ii) * M_ + j0 + jj] = h;   // zT[n][k] = z0[k][n] = a2[n][k]*inv
    zTl[bb + (size_t)(i0 + ii) * M_ + j0 + jj] = l;
  }
  __syncthreads();
  #pragma unroll 4
  for (int pass = 0; pass < 16; pass++) {
    int idx = pass * 256 + tid;
    int jj = idx >> 6, ii = idx & 63;
    float v = T[ii][jj] * inv;   // z0[j][i] = a2[i][j]*inv
    unsigned short h, l;
    split2(v, h, l);
    zRh[bb + (size_t)(j0 + jj) * M_ + i0 + ii] = h;
    zRl[bb + (size_t)(j0 + jj) * M_ + i0 + ii] = l;
  }
}

// ---------------- batched split-bf16 MFMA GEMM, B pre-transposed (T-form [n][k]) ----------------
// C = A @ B. Outputs: R (row-split) = sR*C ; Y (T-split, via LDS bounce) = aY*I + sY*C.
__global__ __launch_bounds__(256, 2) void bgemm_ns(
    const unsigned short* __restrict__ Ah, const unsigned short* __restrict__ Al,
    const unsigned short* __restrict__ BTh, const unsigned short* __restrict__ BTl,
    unsigned short* __restrict__ Rh, unsigned short* __restrict__ Rl,
    unsigned short* __restrict__ YTh, unsigned short* __restrict__ YTl,
    float aY, float sY, float sR)
{
  __shared__ unsigned short Ash[64][72], Asl[64][72];   // [row][k]
  __shared__ unsigned short Bsh[64][72], Bsl[64][72];   // [col][k] (T-form, linear stage)
  int bn = blockIdx.x * 64, bm = blockIdx.y * 64;
  size_t bb = (size_t)blockIdx.z * (M_ * M_);
  int tid = threadIdx.x, wid = tid >> 6, lane = tid & 63;
  int lr = lane & 15, lg = lane >> 4;
  int r0 = wid * 16;
  const f32x4 zf = {0.f, 0.f, 0.f, 0.f};
  f32x4 acc[4];
  #pragma unroll
  for (int nt = 0; nt < 4; nt++) acc[nt] = zf;

  for (int k0 = 0; k0 < M_; k0 += 64) {
    __syncthreads();
    #pragma unroll
    for (int pass = 0; pass < 2; pass++) {
      int idx = pass * 2048 + tid * 8;
      int row = idx >> 6, col = idx & 63;
      *reinterpret_cast<bf16x8*>(&Ash[row][col]) =
          *reinterpret_cast<const bf16x8*>(&Ah[bb + (size_t)(bm + row) * M_ + k0 + col]);
      *reinterpret_cast<bf16x8*>(&Asl[row][col]) =
          *reinterpret_cast<const bf16x8*>(&Al[bb + (size_t)(bm + row) * M_ + k0 + col]);
      *reinterpret_cast<bf16x8*>(&Bsh[row][col]) =
          *reinterpret_cast<const bf16x8*>(&BTh[bb + (size_t)(bn + row) * M_ + k0 + col]);
      *reinterpret_cast<bf16x8*>(&Bsl[row][col]) =
          *reinterpret_cast<const bf16x8*>(&BTl[bb + (size_t)(bn + row) * M_ + k0 + col]);
    }
    __syncthreads();
    #pragma unroll
    for (int kk = 0; kk < 64; kk += 32) {
      bf16x8 ah = *reinterpret_cast<const bf16x8*>(&Ash[r0 + lr][kk + lg * 8]);
      bf16x8 al = *reinterpret_cast<const bf16x8*>(&Asl[r0 + lr][kk + lg * 8]);
      #pragma unroll
      for (int nt = 0; nt < 4; nt++) {
        bf16x8 bh = *reinterpret_cast<const bf16x8*>(&Bsh[nt * 16 + lr][kk + lg * 8]);
        bf16x8 bl = *reinterpret_cast<const bf16x8*>(&Bsl[nt * 16 + lr][kk + lg * 8]);
        acc[nt] = __builtin_amdgcn_mfma_f32_16x16x32_bf16(ah, bh, acc[nt], 0, 0, 0);
        acc[nt] = __builtin_amdgcn_mfma_f32_16x16x32_bf16(ah, bl, acc[nt], 0, 0, 0);
        acc[nt] = __builtin_amdgcn_mfma_f32_16x16x32_bf16(al, bh, acc[nt], 0, 0, 0);
      }
    }
  }
  // ---- R: direct row-major stores ----
  if (Rh) {
    #pragma unroll
    for (int nt = 0; nt < 4; nt++) {
      int col = bn + nt * 16 + lr;
      #pragma unroll
      for (int r = 0; r < 4; r++) {
        int row = bm + r0 + 4 * lg + r;
        unsigned short h, l;
        split2(sR * acc[nt][r], h, l);
        Rh[bb + (size_t)row * M_ + col] = h;
        Rl[bb + (size_t)row * M_ + col] = l;
      }
    }
  }
  // ---- Y: T-form via LDS bounce (reuse Ash/Asl), coalesced b128 stores ----
  if (YTh) {
    __syncthreads();
    #pragma unroll
    for (int nt = 0; nt < 4; nt++) {
      int nl = nt * 16 + lr;
      #pragma unroll
      for (int r = 0; r < 4; r++) {
        int ml = r0 + 4 * lg + r;
        float t = sY * acc[nt][r] + ((bm + ml) == (bn + nl) ? aY : 0.f);
        unsigned short h, l;
        split2(t, h, l);
        Ash[nl][ml] = h;
        Asl[nl][ml] = l;
      }
    }
    __syncthreads();
    #pragma unroll
    for (int pass = 0; pass < 2; pass++) {
      int idx = pass * 2048 + tid * 8;
      int nl = idx >> 6, ml = idx & 63;
      *reinterpret_cast<bf16x8*>(&YTh[bb + (size_t)(bn + nl) * M_ + bm + ml]) =
          *reinterpret_cast<const bf16x8*>(&Ash[nl][ml]);
      *reinterpret_cast<bf16x8*>(&YTl[bb + (size_t)(bn + nl) * M_ + bm + ml]) =
          *reinterpret_cast<const bf16x8*>(&Asl[nl][ml]);
    }
  }
}

// ---------------- W2 = pinv @ pv -> w2t bf16 [bh][64][256] ----------------
__global__ __launch_bounds__(256) void gemm_w2(
    const unsigned short* __restrict__ zRh, const unsigned short* __restrict__ zRl,
    const unsigned short* __restrict__ pvTh, const unsigned short* __restrict__ pvTl,
    unsigned short* __restrict__ w2t)
{
  int bm = blockIdx.x * 64;
  int batch = blockIdx.y;
  size_t bz = (size_t)batch * (M_ * M_);
  size_t bp = (size_t)batch << 14;
  int tid = threadIdx.x, wid = tid >> 6, lane = tid & 63;
  int lr = lane & 15, lg = lane >> 4;
  int r0 = bm + wid * 16;
  const f32x4 zf = {0.f, 0.f, 0.f, 0.f};
  f32x4 acc[4];
  #pragma unroll
  for (int nt = 0; nt < 4; nt++) acc[nt] = zf;

  #pragma unroll
  for (int k0 = 0; k0 < M_; k0 += 32) {
    bf16x8 ah = *reinterpret_cast<const bf16x8*>(&zRh[bz + (size_t)(r0 + lr) * M_ + k0 + lg * 8]);
    bf16x8 al = *reinterpret_cast<const bf16x8*>(&zRl[bz + (size_t)(r0 + lr) * M_ + k0 + lg * 8]);
    #pragma unroll
    for (int nt = 0; nt < 4; nt++) {
      size_t boff = bp + (size_t)(nt * 16 + lr) * M_ + k0 + lg * 8;
      bf16x8 bh = *reinterpret_cast<const bf16x8*>(&pvTh[boff]);
      bf16x8 bl = *reinterpret_cast<const bf16x8*>(&pvTl[boff]);
      acc[nt] = __builtin_amdgcn_mfma_f32_16x16x32_bf16(ah, bh, acc[nt], 0, 0, 0);
      acc[nt] = __builtin_amdgcn_mfma_f32_16x16x32_bf16(ah, bl, acc[nt], 0, 0, 0);
      acc[nt] = __builtin_amdgcn_mfma_f32_16x16x32_bf16(al, bh, acc[nt], 0, 0, 0);
    }
  }
  #pragma unroll
  for (int nt = 0; nt < 4; nt++) {
    int col = nt * 16 + lr;   // dh
    #pragma unroll
    for (int r = 0; r < 4; r++) {
      int row = r0 + 4 * lg + r;   // m
      w2t[bp + (size_t)col * M_ + row] = f2bf(acc[nt][r]);
    }
  }
}

// ---------------- pv partials: softmax(q_l @ k^T) @ v via MFMA, split over N ----------------
__global__ __launch_bounds__(256) void pv_mfma(
    const unsigned short* __restrict__ kb, const unsigned short* __restrict__ vb,
    const unsigned short* __restrict__ qlb,
    float* __restrict__ pvpart, float2* __restrict__ msbuf)
{
  int slice = blockIdx.x;
  int msp   = blockIdx.y;
  int bh    = blockIdx.z;
  int tid = threadIdx.x, wid = tid >> 6, lane = tid & 63;
  int lr = lane & 15, lg = lane >> 4;

  __shared__ unsigned short klds[64][72];
  __shared__ unsigned short vtld[64][72];
  __shared__ unsigned short plds_all[4][32][72];
  unsigned short (*plds)[72] = plds_all[wid];

  int mbase = msp * 128 + wid * 32;
  const unsigned short* qbase = qlb + (((size_t)bh * M_ + mbase) << 6);
  bf16x8 qf[2][2];
  #pragma unroll
  for (int rt = 0; rt < 2; rt++)
    #pragma unroll
    for (int h2 = 0; h2 < 2; h2++)
      qf[rt][h2] = *reinterpret_cast<const bf16x8*>(&qbase[((rt * 16 + lr) << 6) + h2 * 32 + lg * 8]);

  const f32x4 zf = {0.f, 0.f, 0.f, 0.f};
  f32x4 oacc[2][4];
  #pragma unroll
  for (int rt = 0; rt < 2; rt++)
    #pragma unroll
    for (int dt = 0; dt < 4; dt++) oacc[rt][dt] = zf;
  float mrun[8], srun[8];
  #pragma unroll
  for (int i = 0; i < 8; i++) { mrun[i] = -1e30f; srun[i] = 0.f; }

  const unsigned short* kgb = kb + (((size_t)bh * N_ + slice * 1024) << 6);
  const unsigned short* vgb = vb + (((size_t)bh * N_ + slice * 1024) << 6);

  for (int c = 0; c < 16; c++) {
    __syncthreads();
    for (int u = tid; u < 512; u += 256) {
      int key = u >> 3, seg = u & 7;
      size_t goff = (((size_t)(c * 64 + key)) << 6) + seg * 8;
      bf16x8 kv = *reinterpret_cast<const bf16x8*>(&kgb[goff]);
      *reinterpret_cast<bf16x8*>(&klds[key][seg * 8]) = kv;
      bf16x8 vv = *reinterpret_cast<const bf16x8*>(&vgb[goff]);
      int col = key ^ (seg << 3);
      #pragma unroll
      for (int j = 0; j < 8; j++) vtld[seg * 8 + j][col] = (unsigned short)vv[j];
    }
    __syncthreads();
    f32x4 sacc[2][4];
    #pragma unroll
    for (int rt = 0; rt < 2; rt++)
      #pragma unroll
      for (int ct = 0; ct < 4; ct++) {
        bf16x8 b0 = *reinterpret_cast<const bf16x8*>(&klds[ct * 16 + lr][lg * 8]);
        bf16x8 b1 = *reinterpret_cast<const bf16x8*>(&klds[ct * 16 + lr][32 + lg * 8]);
        f32x4 a = __builtin_amdgcn_mfma_f32_16x16x32_bf16(qf[rt][0], b0, zf, 0, 0, 0);
        sacc[rt][ct] = __builtin_amdgcn_mfma_f32_16x16x32_bf16(qf[rt][1], b1, a, 0, 0, 0);
      }
    #pragma unroll
    for (int rt = 0; rt < 2; rt++)
      #pragma unroll
      for (int r = 0; r < 4; r++) {
        int ri = rt * 4 + r;
        float mc = fmaxf(fmaxf(sacc[rt][0][r], sacc[rt][1][r]), fmaxf(sacc[rt][2][r], sacc[rt][3][r]));
        #pragma unroll
        for (int off = 1; off < 16; off <<= 1) mc = fmaxf(mc, __shfl_xor(mc, off));
        float mnew = fmaxf(mrun[ri], mc);
        float corr = __expf(mrun[ri] - mnew);
        float psum = 0.f;
        #pragma unroll
        for (int ct = 0; ct < 4; ct++) {
          float p = __expf(sacc[rt][ct][r] - mnew);
          sacc[rt][ct][r] = p;
          psum += p;
        }
        #pragma unroll
        for (int off = 1; off < 16; off <<= 1) psum += __shfl_xor(psum, off);
        srun[ri] = srun[ri] * corr + psum;
        mrun[ri] = mnew;
        #pragma unroll
        for (int dt = 0; dt < 4; dt++) oacc[rt][dt][r] *= corr;
        #pragma unroll
        for (int ct = 0; ct < 4; ct++)
          plds[rt * 16 + 4 * lg + r][ct * 16 + lr] = f2bf(sacc[rt][ct][r]);
      }
    __builtin_amdgcn_s_waitcnt(0);
    bf16x8 pa[2][2];
    #pragma unroll
    for (int rt = 0; rt < 2; rt++)
      #pragma unroll
      for (int h = 0; h < 2; h++)
        pa[rt][h] = *reinterpret_cast<const bf16x8*>(&plds[rt * 16 + lr][h * 32 + lg * 8]);
    #pragma unroll
    for (int dt = 0; dt < 4; dt++) {
      int d = dt * 16 + lr;
      bf16x8 bv0 = *reinterpret_cast<const bf16x8*>(&vtld[d][(lg * 8) ^ (d & 0x38)]);
      bf16x8 bv1 = *reinterpret_cast<const bf16x8*>(&vtld[d][(32 + lg * 8) ^ (d & 0x38)]);
      #pragma unroll
      for (int rt = 0; rt < 2; rt++) {
        oacc[rt][dt] = __builtin_amdgcn_mfma_f32_16x16x32_bf16(pa[rt][0], bv0, oacc[rt][dt], 0, 0, 0);
        oacc[rt][dt] = __builtin_amdgcn_mfma_f32_16x16x32_bf16(pa[rt][1], bv1, oacc[rt][dt], 0, 0, 0);
      }
    }
  }
  size_t pbase = (((size_t)(bh * 8 + slice) * M_ + mbase) << 6);
  #pragma unroll
  for (int rt = 0; rt < 2; rt++)
    #pragma unroll
    for (int dt = 0; dt < 4; dt++)
      #pragma unroll
      for (int r = 0; r < 4; r++)
        pvpart[pbase + ((size_t)(rt * 16 + 4 * lg + r) << 6) + dt * 16 + lr] = oacc[rt][dt][r];
  if (lr == 0) {
    #pragma unroll
    for (int rt = 0; rt < 2; rt++)
      #pragma unroll
      for (int r = 0; r < 4; r++)
        msbuf[(size_t)(bh * 8 + slice) * M_ + mbase + rt * 16 + 4 * lg + r] =
            make_float2(mrun[rt * 4 + r], srun[rt * 4 + r]);
  }
}

// ---------------- combine split-N partials -> pv^T split bf16 [bh][64][256] ----------------
__global__ __launch_bounds__(256) void pv_combine(const float* __restrict__ pvpart,
    const float2* __restrict__ msbuf,
    unsigned short* __restrict__ pvTh, unsigned short* __restrict__ pvTl)
{
  int row = blockIdx.x * 4 + (threadIdx.x >> 6);
  int bh = row >> 8, m = row & (M_ - 1);
  int d = threadIdx.x & 63;
  float2 ms[8];
  float mg = -1e30f;
  #pragma unroll
  for (int s = 0; s < 8; s++) {
    ms[s] = msbuf[(size_t)(bh * 8 + s) * M_ + m];
    mg = fmaxf(mg, ms[s].x);
  }
  float ssum = 0.f, o = 0.f;
  #pragma unroll
  for (int s = 0; s < 8; s++) {
    float w = __expf(ms[s].x - mg);
    ssum += ms[s].y * w;
    o += w * pvpart[(((size_t)(bh * 8 + s) * M_ + m) << 6) + d];
  }
  float val = o / ssum;
  unsigned short h, l;
  split2(val, h, l);
  size_t oi = ((size_t)bh << 14) + (size_t)d * M_ + m;
  pvTh[oi] = h;
  pvTl[oi] = l;
}

// ---------------- attn1: oh = softmax(q @ kl^T) @ W2 via MFMA ----------------
__global__ __launch_bounds__(256) void attn1_kernel(
    const unsigned short* __restrict__ qb,
    const unsigned short* __restrict__ klb,
    const unsigned short* __restrict__ w2t,
    unsigned short* __restrict__ oh)
{
  int ntile = blockIdx.x & 31;
  int bh = blockIdx.x >> 5;
  int h = bh & (H_ - 1), b = bh >> 3;
  int tid = threadIdx.x, wid = tid >> 6, lane = tid & 63;
  int lr = lane & 15, lg = lane >> 4;
  __shared__ unsigned short plds_all[4][16][264];
  unsigned short* plds = &plds_all[wid][0][0];

  const unsigned short* qbh  = qb  + (((size_t)bh * N_) << 6);
  const unsigned short* klbh = klb + ((size_t)bh << 14);
  const unsigned short* w2bh = w2t + ((size_t)bh << 14);

  const f32x4 zf = {0.f, 0.f, 0.f, 0.f};
  for (int sub = 0; sub < 4; sub++) {
    int n0 = ntile * 256 + sub * 64 + wid * 16;
    bf16x8 aq0 = *reinterpret_cast<const bf16x8*>(&qbh[((size_t)(n0 + lr) << 6) + lg * 8]);
    bf16x8 aq1 = *reinterpret_cast<const bf16x8*>(&qbh[((size_t)(n0 + lr) << 6) + 32 + lg * 8]);
    f32x4 accs[16];
    #pragma unroll
    for (int mt = 0; mt < 16; mt++) {
      bf16x8 b0 = *reinterpret_cast<const bf16x8*>(&klbh[((size_t)(mt * 16 + lr) << 6) + lg * 8]);
      bf16x8 b1 = *reinterpret_cast<const bf16x8*>(&klbh[((size_t)(mt * 16 + lr) << 6) + 32 + lg * 8]);
      f32x4 a = __builtin_amdgcn_mfma_f32_16x16x32_bf16(aq0, b0, zf, 0, 0, 0);
      accs[mt] = __builtin_amdgcn_mfma_f32_16x16x32_bf16(aq1, b1, a, 0, 0, 0);
    }
    float rs[4];
    #pragma unroll
    for (int r = 0; r < 4; r++) {
      float m0 = accs[0][r];
      #pragma unroll
      for (int mt = 1; mt < 16; mt++) m0 = fmaxf(m0, accs[mt][r]);
      #pragma unroll
      for (int off = 1; off < 16; off <<= 1) m0 = fmaxf(m0, __shfl_xor(m0, off));
      float s0 = 0.f;
      #pragma unroll
      for (int mt = 0; mt < 16; mt++) {
        float p = __expf(accs[mt][r] - m0);
        accs[mt][r] = p;
        s0 += p;
      }
      #pragma unroll
      for (int off = 1; off < 16; off <<= 1) s0 += __shfl_xor(s0, off);
      rs[r] = 1.f / s0;
    }
    #pragma unroll
    for (int mt = 0; mt < 16; mt++)
      #pragma unroll
      for (int r = 0; r < 4; r++)
        plds[(4 * lg + r) * 264 + mt * 16 + lr] = f2bf(accs[mt][r]);
    __builtin_amdgcn_s_waitcnt(0);
    bf16x8 pa[8];
    #pragma unroll
    for (int mc = 0; mc < 8; mc++)
      pa[mc] = *reinterpret_cast<const bf16x8*>(&plds[lr * 264 + mc * 32 + lg * 8]);
    f32x4 acco[4];
    #pragma unroll
    for (int dt = 0; dt < 4; dt++) {
      f32x4 a = zf;
      #pragma unroll
      for (int mc = 0; mc < 8; mc++) {
        bf16x8 wf = *reinterpret_cast<const bf16x8*>(&w2bh[(size_t)(dt * 16 + lr) * M_ + mc * 32 + lg * 8]);
        a = __builtin_amdgcn_mfma_f32_16x16x32_bf16(pa[mc], wf, a, 0, 0, 0);
      }
      acco[dt] = a;
    }
    #pragma unroll
    for (int dt = 0; dt < 4; dt++)
      #pragma unroll
      for (int r = 0; r < 4; r++) {
        int n = n0 + 4 * lg + r;
        oh[((size_t)(b * N_ + n) << 9) + h * DH_ + dt * 16 + lr] = f2bf(acco[dt][r] * rs[r]);
      }
  }
}

// ---------------- depthwise conv residual: register sliding window ----------------
__global__ __launch_bounds__(256) void conv_kernel(const unsigned short* __restrict__ vb,
    const float* __restrict__ rw, unsigned short* __restrict__ oh)
{
  int bh = blockIdx.y;
  int h = bh & (H_ - 1), b = bh >> 3;
  int d = threadIdx.x & 63, g = threadIdx.x >> 6;
  int n0 = blockIdx.x * 128 + g * 32;
  const unsigned short* vbb = vb + (((size_t)bh * N_) << 6) + d;
  float w[64];
  #pragma unroll
  for (int j = 0; j < 64; j++) {
    int nn = n0 - 16 + j;
    w[j] = (nn >= 0 && nn < N_) ? bf2f(vbb[(size_t)nn << 6]) : 0.f;
  }
  float rwr[RESK_];
  #pragma unroll
  for (int j = 0; j < RESK_; j++) rwr[j] = rw[h * RESK_ + j];
  size_t obase = (((size_t)(b * N_ + n0)) << 9) + h * 64 + d;
  #pragma unroll
  for (int t = 0; t < 32; t++) {
    float acc = 0.f;
    #pragma unroll
    for (int j = 0; j < RESK_; j++) acc += rwr[j] * w[t + j];
    size_t oi = obase + ((size_t)t << 9);
    oh[oi] = f2bf(bf2f(oh[oi]) + acc);
  }
}

extern "C" void kernel_launch(void* const* d_in, const int* in_sizes, int n_in,
                              void* d_out, int out_size, void* d_ws, size_t ws_size,
                              hipStream_t stream)
{
  const float* x     = (const float*)d_in[0];
  const float* ln_w  = (const float*)d_in[1];
  const float* ln_b  = (const float*)d_in[2];
  const float* w_qkv = (const float*)d_in[3];
  const float* w_out = (const float*)d_in[4];
  const float* b_out = (const float*)d_in[5];
  const float* res_w = (const float*)d_in[6];
  float* out = (float*)d_out;

  const size_t HEADEL = (size_t)B_ * H_ * N_ * DH_;   // 16,777,216
  const size_t SMALL  = (size_t)B_ * H_ * M_ * DH_;   // 524,288
  const size_t MSQ    = (size_t)B_ * H_ * M_ * M_;    // 2,097,152

  char* p = (char*)d_ws;
  auto alloc = [&](size_t bytes) { char* r = p; p += (bytes + 255) & ~(size_t)255; return r; };

  unsigned short* qb  = (unsigned short*)alloc(HEADEL * 2);
  unsigned short* kb  = (unsigned short*)alloc(HEADEL * 2);
  unsigned short* vb  = (unsigned short*)alloc(HEADEL * 2);
  unsigned short* oh  = (unsigned short*)alloc(HEADEL * 2);
  // union A: xnb (32 MB) then z ping-pong (R and T forms, 8 x 4 MB)
  char* unA = alloc(HEADEL * 2);
  unsigned short* xnb  = (unsigned short*)unA;
  unsigned short* z0Rh = (unsigned short*)unA;
  unsigned short* z0Rl = z0Rh + MSQ;
  unsigned short* z0Th = z0Rl + MSQ;
  unsigned short* z0Tl = z0Th + MSQ;
  unsigned short* z1Rh = z0Tl + MSQ;
  unsigned short* z1Rl = z1Rh + MSQ;
  unsigned short* z1Th = z1Rl + MSQ;
  unsigned short* z1Tl = z1Th + MSQ;
  // union B: pvpart f32 (16 MB) + msbuf then u / vT / wT / yT (8 x 4 MB)
  char* unB = alloc(HEADEL * 2);
  float*  pvpart = (float*)unB;
  float2* msbuf  = (float2*)(unB + (size_t)B_ * H_ * 8 * M_ * DH_ * 4);
  unsigned short* uh  = (unsigned short*)unB;
  unsigned short* ul  = uh + MSQ;
  unsigned short* vTh = ul + MSQ;
  unsigned short* vTl = vTh + MSQ;
  unsigned short* wTh = vTl + MSQ;
  unsigned short* wTl = wTh + MSQ;
  unsigned short* yTh = wTl + MSQ;
  unsigned short* yTl = yTh + MSQ;

  unsigned short* wqkvT = (unsigned short*)alloc((size_t)K3_ * DIM_ * 2);
  unsigned short* woutT = (unsigned short*)alloc((size_t)DIM_ * INNER_ * 2);
  float* ql  = (float*)alloc(SMALL * 4);
  float* kl  = (float*)alloc(SMALL * 4);
  unsigned short* qlb  = (unsigned short*)alloc(SMALL * 2);
  unsigned short* klb  = (unsigned short*)alloc(SMALL * 2);
  unsigned short* pvTh = (unsigned short*)alloc(SMALL * 2);
  unsigned short* pvTl = (unsigned short*)alloc(SMALL * 2);
  unsigned short* w2t  = (unsigned short*)alloc(SMALL * 2);
  unsigned short* a2h  = (unsigned short*)alloc(MSQ * 2);
  unsigned short* a2l  = (unsigned short*)alloc(MSQ * 2);
  unsigned int* scal   = (unsigned int*)alloc(256);
  if ((size_t)(p - (char*)d_ws) > ws_size) return;

  float* a2 = (float*)d_out;   // 8 MB, dead before mfma_out overwrites d_out

  ln_bf16<<<B_ * N_, 256, 0, stream>>>(x, ln_w, ln_b, xnb);
  transpose_w<<<dim3(K3_ / 64, DIM_ / 64), 256, 0, stream>>>(w_qkv, wqkvT, DIM_, K3_, INNER_, 0.125f);
  transpose_w<<<dim3(DIM_ / 64, INNER_ / 64), 256, 0, stream>>>(w_out, woutT, INNER_, DIM_, 0, 1.f);
  mfma_qkv<<<dim3(K3_ / 128, (B_ * N_) / 128), 256, 0, stream>>>(xnb, wqkvT, qb, kb, vb);
  landmark_kernel<<<B_ * H_ * M_, 64, 0, stream>>>(qb, kb, ql, kl, qlb, klb);
  attn2_kernel<<<B_ * H_ * M_, 256, 0, stream>>>(ql, kl, a2, a2h, a2l);
  zero_scal<<<1, 2, 0, stream>>>(scal);
  pinv_scale_kernel<<<B_ * H_, 256, 0, stream>>>(a2, scal);
  pv_mfma<<<dim3(8, 2, B_ * H_), 256, 0, stream>>>(kb, vb, qlb, pvpart, msbuf);
  pv_combine<<<(B_ * H_ * M_) / 4, 256, 0, stream>>>(pvpart, msbuf, pvTh, pvTl);
  // zinit AFTER mfma_qkv (xnb dead)
  zinit_kernel<<<dim3(4, 4, B_ * H_), 256, 0, stream>>>(a2, scal, z0Rh, z0Rl, z0Th, z0Tl);

  // Newton-Schulz chain: A row-split, B T-split everywhere (chain bufs overwrite pvpart — pv done)
  unsigned short *cRh = z0Rh, *cRl = z0Rl, *cTh = z0Th, *cTl = z0Tl;
  unsigned short *nRh = z1Rh, *nRl = z1Rl, *nTh = z1Th, *nTl = z1Tl;
  dim3 g44(4, 4, B_ * H_);
  for (int it = 0; it < 6; it++) {
    // u = a2 @ z (R) ; vT = (7I - u)^T
    bgemm_ns<<<g44, 256, 0, stream>>>(a2h, a2l, cTh, cTl, uh, ul, vTh, vTl, 7.f, -1.f, 1.f);
    // wT = (15I - u@v)^T
    bgemm_ns<<<g44, 256, 0, stream>>>(uh, ul, vTh, vTl, nullptr, nullptr, wTh, wTl, 15.f, -1.f, 0.f);
    // yT = (13I - u@w)^T
    bgemm_ns<<<g44, 256, 0, stream>>>(uh, ul, wTh, wTl, nullptr, nullptr, yTh, yTl, 13.f, -1.f, 0.f);
    // z' = 0.25 z@y : both R and T forms
    bgemm_ns<<<g44, 256, 0, stream>>>(cRh, cRl, yTh, yTl, nRh, nRl, nTh, nTl, 0.f, 0.25f, 0.25f);
    unsigned short* t;
    t = cRh; cRh = nRh; nRh = t;  t = cRl; cRl = nRl; nRl = t;
    t = cTh; cTh = nTh; nTh = t;  t = cTl; cTl = nTl; nTl = t;
  }

  gemm_w2<<<dim3(4, B_ * H_), 256, 0, stream>>>(cRh, cRl, pvTh, pvTl, w2t);

  attn1_kernel<<<B_ * H_ * (N_ / 256), 256, 0, stream>>>(qb, klb, w2t, oh);
  conv_kernel<<<dim3(N_ / 128, B_ * H_), 256, 0, stream>>>(vb, res_w, oh);
  mfma_out<<<dim3(DIM_ / 128, (B_ * N_) / 128), 256, 0, stream>>>(oh, woutT, b_out, x, out);
}

// Round 9
// 692.275 us; speedup vs baseline: 7.4585x; 1.1364x over previous
//
#include <hip/hip_runtime.h>
#include <cstdint>

#define B_ 4
#define N_ 8192
#define DIM_ 512
#define H_ 8
#define DH_ 64
#define M_ 256
#define L_ 32
#define INNER_ 512
#define K3_ 1536
#define RESK_ 33

struct __align__(16) ushort8_t { unsigned short u[8]; };
typedef short bf16x8 __attribute__((ext_vector_type(8)));
typedef float f32x4 __attribute__((ext_vector_type(4)));

__device__ __forceinline__ float bf2f(unsigned short u) {
  return __uint_as_float(((unsigned)u) << 16);
}
__device__ __forceinline__ unsigned short f2bf(float f) {
  unsigned x = __float_as_uint(f);
  return (unsigned short)((x + 0x7fffu + ((x >> 16) & 1u)) >> 16);  // RNE
}

// ---------------- fused LayerNorm -> bf16 activations ----------------
__global__ __launch_bounds__(256) void ln_bf16(const float* __restrict__ x,
    const float* __restrict__ w, const float* __restrict__ bb, unsigned short* __restrict__ xnb)
{
  int row = blockIdx.x;
  int tid = threadIdx.x;
  float2 v = reinterpret_cast<const float2*>(x + (size_t)row * DIM_)[tid];
  float s = v.x + v.y, s2 = v.x * v.x + v.y * v.y;
  #pragma unroll
  for (int off = 32; off; off >>= 1) { s += __shfl_down(s, off); s2 += __shfl_down(s2, off); }
  __shared__ float rs[4], rs2[4];
  int wid = tid >> 6, lane = tid & 63;
  if (lane == 0) { rs[wid] = s; rs2[wid] = s2; }
  __syncthreads();
  float ts = rs[0] + rs[1] + rs[2] + rs[3];
  float ts2 = rs2[0] + rs2[1] + rs2[2] + rs2[3];
  float mu = ts * (1.f / DIM_);
  float var = ts2 * (1.f / DIM_) - mu * mu;
  float inv = rsqrtf(var + 1e-5f);
  int c = tid * 2;
  unsigned int p0 = f2bf((v.x - mu) * inv * w[c] + bb[c]);
  unsigned int p1 = f2bf((v.y - mu) * inv * w[c + 1] + bb[c + 1]);
  reinterpret_cast<unsigned int*>(xnb + (size_t)row * DIM_)[tid] = p0 | (p1 << 16);
}

// ---------------- transpose weights to bf16 ----------------
__global__ __launch_bounds__(256) void transpose_w(const float* __restrict__ src,
    unsigned short* __restrict__ dst, int K, int C, int qcols, float qs)
{
  __shared__ float T[64][65];
  int c0 = blockIdx.x * 64, k0 = blockIdx.y * 64;
  #pragma unroll 4
  for (int it = 0; it < 16; it++) {
    int idx = it * 256 + threadIdx.x;
    int kk = idx >> 6, cc = idx & 63;
    T[kk][cc] = src[(size_t)(k0 + kk) * C + c0 + cc];
  }
  __syncthreads();
  #pragma unroll 4
  for (int it = 0; it < 16; it++) {
    int idx = it * 256 + threadIdx.x;
    int cc = idx >> 6, kk = idx & 63;
    float v = T[kk][cc];
    int c = c0 + cc;
    dst[(size_t)c * K + k0 + kk] = f2bf(c < qcols ? v * qs : v);
  }
}

// ---------------- MFMA GEMM: qkv = xnb @ wT^T, scatter head-major bf16 ----------------
__global__ __launch_bounds__(256, 2) void mfma_qkv(const unsigned short* __restrict__ xnb,
    const unsigned short* __restrict__ wT,
    unsigned short* __restrict__ qb, unsigned short* __restrict__ kb, unsigned short* __restrict__ vb)
{
  __shared__ unsigned short As[128][72];
  __shared__ unsigned short Bs[128][72];
  int tid = threadIdx.x;
  int bn = blockIdx.x * 128, bm = blockIdx.y * 128;
  int wid = tid >> 6, lane = tid & 63;
  int wr = wid >> 1, wc = wid & 1;
  int lr = lane & 15, lg = lane >> 4;
  const f32x4 zf = {0.f, 0.f, 0.f, 0.f};
  f32x4 acc[4][4];
  #pragma unroll
  for (int mt = 0; mt < 4; mt++)
    #pragma unroll
    for (int nt = 0; nt < 4; nt++) acc[mt][nt] = zf;

  for (int k0 = 0; k0 < DIM_; k0 += 64) {
    __syncthreads();
    #pragma unroll
    for (int rnd = 0; rnd < 4; rnd++) {
      int idx = rnd * 2048 + tid * 8;
      int row = idx >> 6, col = idx & 63;
      *reinterpret_cast<bf16x8*>(&As[row][col]) =
          *reinterpret_cast<const bf16x8*>(&xnb[(size_t)(bm + row) * DIM_ + k0 + col]);
      *reinterpret_cast<bf16x8*>(&Bs[row][col]) =
          *reinterpret_cast<const bf16x8*>(&wT[(size_t)(bn + row) * DIM_ + k0 + col]);
    }
    __syncthreads();
    bf16x8 af[4][2], bfr[4][2];
    #pragma unroll
    for (int mt = 0; mt < 4; mt++) {
      af[mt][0] = *reinterpret_cast<const bf16x8*>(&As[wr * 64 + mt * 16 + lr][lg * 8]);
      af[mt][1] = *reinterpret_cast<const bf16x8*>(&As[wr * 64 + mt * 16 + lr][32 + lg * 8]);
    }
    #pragma unroll
    for (int nt = 0; nt < 4; nt++) {
      bfr[nt][0] = *reinterpret_cast<const bf16x8*>(&Bs[wc * 64 + nt * 16 + lr][lg * 8]);
      bfr[nt][1] = *reinterpret_cast<const bf16x8*>(&Bs[wc * 64 + nt * 16 + lr][32 + lg * 8]);
    }
    #pragma unroll
    for (int mt = 0; mt < 4; mt++)
      #pragma unroll
      for (int nt = 0; nt < 4; nt++) {
        acc[mt][nt] = __builtin_amdgcn_mfma_f32_16x16x32_bf16(af[mt][0], bfr[nt][0], acc[mt][nt], 0, 0, 0);
        acc[mt][nt] = __builtin_amdgcn_mfma_f32_16x16x32_bf16(af[mt][1], bfr[nt][1], acc[mt][nt], 0, 0, 0);
      }
  }
  #pragma unroll
  for (int nt = 0; nt < 4; nt++) {
    int c = bn + wc * 64 + nt * 16 + lr;
    int which = c >> 9;
    int h = (c >> 6) & (H_ - 1);
    int d = c & 63;
    unsigned short* dst = which == 0 ? qb : (which == 1 ? kb : vb);
    #pragma unroll
    for (int mt = 0; mt < 4; mt++)
      #pragma unroll
      for (int r = 0; r < 4; r++) {
        int row = bm + wr * 64 + mt * 16 + 4 * lg + r;
        int b = row >> 13, n = row & (N_ - 1);
        dst[(((size_t)(b * H_ + h) * N_ + n) << 6) + d] = f2bf(acc[mt][nt][r]);
      }
  }
}

// ---------------- MFMA GEMM: out = oh @ woutT^T + bias + resid (f32 out) ----------------
__global__ __launch_bounds__(256, 2) void mfma_out(const unsigned short* __restrict__ oh,
    const unsigned short* __restrict__ wT, const float* __restrict__ bias,
    const float* __restrict__ resid, float* __restrict__ out)
{
  __shared__ unsigned short As[128][72];
  __shared__ unsigned short Bs[128][72];
  int tid = threadIdx.x;
  int bn = blockIdx.x * 128, bm = blockIdx.y * 128;
  int wid = tid >> 6, lane = tid & 63;
  int wr = wid >> 1, wc = wid & 1;
  int lr = lane & 15, lg = lane >> 4;
  const f32x4 zf = {0.f, 0.f, 0.f, 0.f};
  f32x4 acc[4][4];
  #pragma unroll
  for (int mt = 0; mt < 4; mt++)
    #pragma unroll
    for (int nt = 0; nt < 4; nt++) acc[mt][nt] = zf;

  for (int k0 = 0; k0 < INNER_; k0 += 64) {
    __syncthreads();
    #pragma unroll
    for (int rnd = 0; rnd < 4; rnd++) {
      int idx = rnd * 2048 + tid * 8;
      int row = idx >> 6, col = idx & 63;
      *reinterpret_cast<bf16x8*>(&As[row][col]) =
          *reinterpret_cast<const bf16x8*>(&oh[((size_t)(bm + row) << 9) + k0 + col]);
      *reinterpret_cast<bf16x8*>(&Bs[row][col]) =
          *reinterpret_cast<const bf16x8*>(&wT[(size_t)(bn + row) * INNER_ + k0 + col]);
    }
    __syncthreads();
    bf16x8 af[4][2], bfr[4][2];
    #pragma unroll
    for (int mt = 0; mt < 4; mt++) {
      af[mt][0] = *reinterpret_cast<const bf16x8*>(&As[wr * 64 + mt * 16 + lr][lg * 8]);
      af[mt][1] = *reinterpret_cast<const bf16x8*>(&As[wr * 64 + mt * 16 + lr][32 + lg * 8]);
    }
    #pragma unroll
    for (int nt = 0; nt < 4; nt++) {
      bfr[nt][0] = *reinterpret_cast<const bf16x8*>(&Bs[wc * 64 + nt * 16 + lr][lg * 8]);
      bfr[nt][1] = *reinterpret_cast<const bf16x8*>(&Bs[wc * 64 + nt * 16 + lr][32 + lg * 8]);
    }
    #pragma unroll
    for (int mt = 0; mt < 4; mt++)
      #pragma unroll
      for (int nt = 0; nt < 4; nt++) {
        acc[mt][nt] = __builtin_amdgcn_mfma_f32_16x16x32_bf16(af[mt][0], bfr[nt][0], acc[mt][nt], 0, 0, 0);
        acc[mt][nt] = __builtin_amdgcn_mfma_f32_16x16x32_bf16(af[mt][1], bfr[nt][1], acc[mt][nt], 0, 0, 0);
      }
  }
  #pragma unroll
  for (int nt = 0; nt < 4; nt++) {
    int c = bn + wc * 64 + nt * 16 + lr;
    float bias_c = bias[c];
    #pragma unroll
    for (int mt = 0; mt < 4; mt++)
      #pragma unroll
      for (int r = 0; r < 4; r++) {
        int row = bm + wr * 64 + mt * 16 + 4 * lg + r;
        out[(size_t)row * DIM_ + c] = acc[mt][nt][r] + bias_c + resid[(size_t)row * DIM_ + c];
      }
  }
}

// ---------------- landmark means (f32 + bf16 q_l, bf16 k_l) ----------------
__global__ __launch_bounds__(64) void landmark_kernel(const unsigned short* __restrict__ qb,
    const unsigned short* __restrict__ kb, float* __restrict__ ql, float* __restrict__ kl,
    unsigned short* __restrict__ qlb, unsigned short* __restrict__ klb)
{
  int id = blockIdx.x;
  int m = id & (M_ - 1);
  int bh = id >> 8;
  int d = threadIdx.x;
  size_t base = (((size_t)bh * N_ + m * L_) << 6) + d;
  float sq = 0, sk = 0;
  #pragma unroll 4
  for (int j = 0; j < L_; j++) {
    sq += bf2f(qb[base + ((size_t)j << 6)]);
    sk += bf2f(kb[base + ((size_t)j << 6)]);
  }
  float qv = sq * (1.f / L_);
  float kv = sk * (1.f / L_);
  size_t o = ((size_t)bh * M_ + m) * DH_ + d;
  ql[o] = qv;
  kl[o] = kv;
  qlb[o] = f2bf(qv);
  klb[o] = f2bf(kv);
}

// ---------------- sim2 + softmax -> attn2 (f32 + bf16) ----------------
__global__ __launch_bounds__(256) void attn2_kernel(const float* __restrict__ ql,
    const float* __restrict__ kl, float* __restrict__ a2, unsigned short* __restrict__ a2b)
{
  int id = blockIdx.x;
  int i = id & (M_ - 1);
  int bh = id >> 8;
  int j = threadIdx.x;
  __shared__ float qs[DH_];
  __shared__ float wred[4];
  if (j < DH_) qs[j] = ql[((size_t)bh * M_ + i) * DH_ + j];
  __syncthreads();
  const float* krow = kl + ((size_t)bh * M_ + j) * DH_;
  float s = 0;
  #pragma unroll
  for (int d = 0; d < DH_; d++) s += qs[d] * krow[d];
  float mx = s;
  #pragma unroll
  for (int off = 1; off < 64; off <<= 1) mx = fmaxf(mx, __shfl_xor(mx, off));
  int wid = j >> 6, lane = j & 63;
  if (lane == 0) wred[wid] = mx;
  __syncthreads();
  mx = fmaxf(fmaxf(wred[0], wred[1]), fmaxf(wred[2], wred[3]));
  float e = __expf(s - mx);
  float sum = e;
  #pragma unroll
  for (int off = 1; off < 64; off <<= 1) sum += __shfl_xor(sum, off);
  __syncthreads();
  if (lane == 0) wred[wid] = sum;
  __syncthreads();
  sum = wred[0] + wred[1] + wred[2] + wred[3];
  float p = e / sum;
  size_t o = ((size_t)bh * M_ + i) * M_ + j;
  a2[o] = p;
  a2b[o] = f2bf(p);
}

// ---------------- pinv scale ----------------
__global__ void zero_scal(unsigned int* scal) { scal[threadIdx.x] = 0u; }

__global__ __launch_bounds__(256) void pinv_scale_kernel(const float* __restrict__ a2,
    unsigned int* __restrict__ scal)
{
  int bh = blockIdx.x;
  int t = threadIdx.x;
  const float* xb = a2 + (size_t)bh * M_ * M_;
  float rowsum = 0, colsum = 0;
  for (int j = 0; j < M_; j++) {
    rowsum += xb[(size_t)t * M_ + j];
    colsum += xb[(size_t)j * M_ + t];
  }
  #pragma unroll
  for (int off = 1; off < 64; off <<= 1) {
    rowsum = fmaxf(rowsum, __shfl_xor(rowsum, off));
    colsum = fmaxf(colsum, __shfl_xor(colsum, off));
  }
  __shared__ float wr[4], wc[4];
  int wid = t >> 6, lane = t & 63;
  if (lane == 0) { wr[wid] = rowsum; wc[wid] = colsum; }
  __syncthreads();
  if (t == 0) {
    float rm = fmaxf(fmaxf(wr[0], wr[1]), fmaxf(wr[2], wr[3]));
    float cm = fmaxf(fmaxf(wc[0], wc[1]), fmaxf(wc[2], wc[3]));
    atomicMax(&scal[0], __float_as_uint(rm));
    atomicMax(&scal[1], __float_as_uint(cm));
  }
}

// ---------------- z0 = a2^T/s: row-form (LDS transpose) + T-form (direct) bf16 ----------------
__global__ __launch_bounds__(256) void zinit_kernel(const float* __restrict__ a2,
    const unsigned int* __restrict__ scal,
    unsigned short* __restrict__ zR, unsigned short* __restrict__ zT)
{
  __shared__ float T[64][65];
  int j0 = blockIdx.x * 64, i0 = blockIdx.y * 64;
  size_t bb = (size_t)blockIdx.z * (M_ * M_);
  float inv = 1.f / (__uint_as_float(scal[0]) * __uint_as_float(scal[1]));
  int tid = threadIdx.x;
  #pragma unroll 4
  for (int pass = 0; pass < 16; pass++) {
    int idx = pass * 256 + tid;
    int ii = idx >> 6, jj = idx & 63;
    float v = a2[bb + (size_t)(i0 + ii) * M_ + j0 + jj];
    T[ii][jj] = v;
    zT[bb + (size_t)(i0 + ii) * M_ + j0 + jj] = f2bf(v * inv);  // zT[n][k] = a2[n][k]*inv
  }
  __syncthreads();
  #pragma unroll 4
  for (int pass = 0; pass < 16; pass++) {
    int idx = pass * 256 + tid;
    int jj = idx >> 6, ii = idx & 63;
    zR[bb + (size_t)(j0 + jj) * M_ + i0 + ii] = f2bf(T[ii][jj] * inv);  // z0[j][i]
  }
}

// ---------------- batched bf16 MFMA GEMM, B pre-transposed (T-form [n][k]) ----------------
// C = A @ B. Outputs: R (row) = sR*C ; YT (T-form via LDS bounce) = (aY*I + sY*C)^T.
__global__ __launch_bounds__(256, 2) void bgemm_ns(
    const unsigned short* __restrict__ Ab, const unsigned short* __restrict__ BTb,
    unsigned short* __restrict__ Rb, unsigned short* __restrict__ YTb,
    float aY, float sY, float sR)
{
  __shared__ unsigned short Ash[64][72];   // [row][k]
  __shared__ unsigned short Bsh[64][72];   // [col][k]
  int bn = blockIdx.x * 64, bm = blockIdx.y * 64;
  size_t bb = (size_t)blockIdx.z * (M_ * M_);
  int tid = threadIdx.x, wid = tid >> 6, lane = tid & 63;
  int lr = lane & 15, lg = lane >> 4;
  int wr = (wid >> 1) * 32, wc = (wid & 1) * 32;   // wave tile 32x32
  const f32x4 zf = {0.f, 0.f, 0.f, 0.f};
  f32x4 acc[2][2];
  #pragma unroll
  for (int mt = 0; mt < 2; mt++)
    #pragma unroll
    for (int nt = 0; nt < 2; nt++) acc[mt][nt] = zf;

  for (int k0 = 0; k0 < M_; k0 += 64) {
    __syncthreads();
    #pragma unroll
    for (int pass = 0; pass < 2; pass++) {
      int idx = pass * 2048 + tid * 8;
      int row = idx >> 6, col = idx & 63;
      *reinterpret_cast<bf16x8*>(&Ash[row][col]) =
          *reinterpret_cast<const bf16x8*>(&Ab[bb + (size_t)(bm + row) * M_ + k0 + col]);
      *reinterpret_cast<bf16x8*>(&Bsh[row][col]) =
          *reinterpret_cast<const bf16x8*>(&BTb[bb + (size_t)(bn + row) * M_ + k0 + col]);
    }
    __syncthreads();
    #pragma unroll
    for (int kk = 0; kk < 64; kk += 32) {
      bf16x8 a0 = *reinterpret_cast<const bf16x8*>(&Ash[wr + lr][kk + lg * 8]);
      bf16x8 a1 = *reinterpret_cast<const bf16x8*>(&Ash[wr + 16 + lr][kk + lg * 8]);
      bf16x8 b0 = *reinterpret_cast<const bf16x8*>(&Bsh[wc + lr][kk + lg * 8]);
      bf16x8 b1 = *reinterpret_cast<const bf16x8*>(&Bsh[wc + 16 + lr][kk + lg * 8]);
      acc[0][0] = __builtin_amdgcn_mfma_f32_16x16x32_bf16(a0, b0, acc[0][0], 0, 0, 0);
      acc[0][1] = __builtin_amdgcn_mfma_f32_16x16x32_bf16(a0, b1, acc[0][1], 0, 0, 0);
      acc[1][0] = __builtin_amdgcn_mfma_f32_16x16x32_bf16(a1, b0, acc[1][0], 0, 0, 0);
      acc[1][1] = __builtin_amdgcn_mfma_f32_16x16x32_bf16(a1, b1, acc[1][1], 0, 0, 0);
    }
  }
  // ---- R: direct row-major stores ----
  if (Rb) {
    #pragma unroll
    for (int mt = 0; mt < 2; mt++)
      #pragma unroll
      for (int nt = 0; nt < 2; nt++) {
        int col = bn + wc + nt * 16 + lr;
        #pragma unroll
        for (int r = 0; r < 4; r++) {
          int row = bm + wr + mt * 16 + 4 * lg + r;
          Rb[bb + (size_t)row * M_ + col] = f2bf(sR * acc[mt][nt][r]);
        }
      }
  }
  // ---- YT: T-form via LDS bounce (reuse Ash), coalesced b128 stores ----
  if (YTb) {
    __syncthreads();
    #pragma unroll
    for (int mt = 0; mt < 2; mt++)
      #pragma unroll
      for (int nt = 0; nt < 2; nt++) {
        int nl = wc + nt * 16 + lr;
        #pragma unroll
        for (int r = 0; r < 4; r++) {
          int ml = wr + mt * 16 + 4 * lg + r;
          float t = sY * acc[mt][nt][r] + ((bm + ml) == (bn + nl) ? aY : 0.f);
          Ash[nl][ml] = f2bf(t);
        }
      }
    __syncthreads();
    #pragma unroll
    for (int pass = 0; pass < 2; pass++) {
      int idx = pass * 2048 + tid * 8;
      int nl = idx >> 6, ml = idx & 63;
      *reinterpret_cast<bf16x8*>(&YTb[bb + (size_t)(bn + nl) * M_ + bm + ml]) =
          *reinterpret_cast<const bf16x8*>(&Ash[nl][ml]);
    }
  }
}

// ---------------- W2 = pinv @ pv -> w2t bf16 [bh][64][256] ----------------
__global__ __launch_bounds__(256) void gemm_w2(
    const unsigned short* __restrict__ zR,
    const unsigned short* __restrict__ pvT, unsigned short* __restrict__ w2t)
{
  int bm = blockIdx.x * 64;
  int batch = blockIdx.y;
  size_t bz = (size_t)batch * (M_ * M_);
  size_t bp = (size_t)batch << 14;
  int tid = threadIdx.x, wid = tid >> 6, lane = tid & 63;
  int lr = lane & 15, lg = lane >> 4;
  int r0 = bm + wid * 16;
  const f32x4 zf = {0.f, 0.f, 0.f, 0.f};
  f32x4 acc[4];
  #pragma unroll
  for (int nt = 0; nt < 4; nt++) acc[nt] = zf;

  #pragma unroll
  for (int k0 = 0; k0 < M_; k0 += 32) {
    bf16x8 a = *reinterpret_cast<const bf16x8*>(&zR[bz + (size_t)(r0 + lr) * M_ + k0 + lg * 8]);
    #pragma unroll
    for (int nt = 0; nt < 4; nt++) {
      bf16x8 b = *reinterpret_cast<const bf16x8*>(&pvT[bp + (size_t)(nt * 16 + lr) * M_ + k0 + lg * 8]);
      acc[nt] = __builtin_amdgcn_mfma_f32_16x16x32_bf16(a, b, acc[nt], 0, 0, 0);
    }
  }
  #pragma unroll
  for (int nt = 0; nt < 4; nt++) {
    int col = nt * 16 + lr;   // dh
    #pragma unroll
    for (int r = 0; r < 4; r++) {
      int row = r0 + 4 * lg + r;   // m
      w2t[bp + (size_t)col * M_ + row] = f2bf(acc[nt][r]);
    }
  }
}

// ---------------- pv partials: softmax(q_l @ k^T) @ v via MFMA, split over N ----------------
__global__ __launch_bounds__(256) void pv_mfma(
    const unsigned short* __restrict__ kb, const unsigned short* __restrict__ vb,
    const unsigned short* __restrict__ qlb,
    float* __restrict__ pvpart, float2* __restrict__ msbuf)
{
  int slice = blockIdx.x;
  int msp   = blockIdx.y;
  int bh    = blockIdx.z;
  int tid = threadIdx.x, wid = tid >> 6, lane = tid & 63;
  int lr = lane & 15, lg = lane >> 4;

  __shared__ unsigned short klds[64][72];
  __shared__ unsigned short vtld[64][72];
  __shared__ unsigned short plds_all[4][32][72];
  unsigned short (*plds)[72] = plds_all[wid];

  int mbase = msp * 128 + wid * 32;
  const unsigned short* qbase = qlb + (((size_t)bh * M_ + mbase) << 6);
  bf16x8 qf[2][2];
  #pragma unroll
  for (int rt = 0; rt < 2; rt++)
    #pragma unroll
    for (int h2 = 0; h2 < 2; h2++)
      qf[rt][h2] = *reinterpret_cast<const bf16x8*>(&qbase[((rt * 16 + lr) << 6) + h2 * 32 + lg * 8]);

  const f32x4 zf = {0.f, 0.f, 0.f, 0.f};
  f32x4 oacc[2][4];
  #pragma unroll
  for (int rt = 0; rt < 2; rt++)
    #pragma unroll
    for (int dt = 0; dt < 4; dt++) oacc[rt][dt] = zf;
  float mrun[8], srun[8];
  #pragma unroll
  for (int i = 0; i < 8; i++) { mrun[i] = -1e30f; srun[i] = 0.f; }

  const unsigned short* kgb = kb + (((size_t)bh * N_ + slice * 1024) << 6);
  const unsigned short* vgb = vb + (((size_t)bh * N_ + slice * 1024) << 6);

  for (int c = 0; c < 16; c++) {
    __syncthreads();
    for (int u = tid; u < 512; u += 256) {
      int key = u >> 3, seg = u & 7;
      size_t goff = (((size_t)(c * 64 + key)) << 6) + seg * 8;
      bf16x8 kv = *reinterpret_cast<const bf16x8*>(&kgb[goff]);
      *reinterpret_cast<bf16x8*>(&klds[key][seg * 8]) = kv;
      bf16x8 vv = *reinterpret_cast<const bf16x8*>(&vgb[goff]);
      int col = key ^ (seg << 3);
      #pragma unroll
      for (int j = 0; j < 8; j++) vtld[seg * 8 + j][col] = (unsigned short)vv[j];
    }
    __syncthreads();
    f32x4 sacc[2][4];
    #pragma unroll
    for (int rt = 0; rt < 2; rt++)
      #pragma unroll
      for (int ct = 0; ct < 4; ct++) {
        bf16x8 b0 = *reinterpret_cast<const bf16x8*>(&klds[ct * 16 + lr][lg * 8]);
        bf16x8 b1 = *reinterpret_cast<const bf16x8*>(&klds[ct * 16 + lr][32 + lg * 8]);
        f32x4 a = __builtin_amdgcn_mfma_f32_16x16x32_bf16(qf[rt][0], b0, zf, 0, 0, 0);
        sacc[rt][ct] = __builtin_amdgcn_mfma_f32_16x16x32_bf16(qf[rt][1], b1, a, 0, 0, 0);
      }
    #pragma unroll
    for (int rt = 0; rt < 2; rt++)
      #pragma unroll
      for (int r = 0; r < 4; r++) {
        int ri = rt * 4 + r;
        float mc = fmaxf(fmaxf(sacc[rt][0][r], sacc[rt][1][r]), fmaxf(sacc[rt][2][r], sacc[rt][3][r]));
        #pragma unroll
        for (int off = 1; off < 16; off <<= 1) mc = fmaxf(mc, __shfl_xor(mc, off));
        float mnew = fmaxf(mrun[ri], mc);
        float corr = __expf(mrun[ri] - mnew);
        float psum = 0.f;
        #pragma unroll
        for (int ct = 0; ct < 4; ct++) {
          float p = __expf(sacc[rt][ct][r] - mnew);
          sacc[rt][ct][r] = p;
          psum += p;
        }
        #pragma unroll
        for (int off = 1; off < 16; off <<= 1) psum += __shfl_xor(psum, off);
        srun[ri] = srun[ri] * corr + psum;
        mrun[ri] = mnew;
        #pragma unroll
        for (int dt = 0; dt < 4; dt++) oacc[rt][dt][r] *= corr;
        #pragma unroll
        for (int ct = 0; ct < 4; ct++)
          plds[rt * 16 + 4 * lg + r][ct * 16 + lr] = f2bf(sacc[rt][ct][r]);
      }
    __builtin_amdgcn_s_waitcnt(0);
    bf16x8 pa[2][2];
    #pragma unroll
    for (int rt = 0; rt < 2; rt++)
      #pragma unroll
      for (int h = 0; h < 2; h++)
        pa[rt][h] = *reinterpret_cast<const bf16x8*>(&plds[rt * 16 + lr][h * 32 + lg * 8]);
    #pragma unroll
    for (int dt = 0; dt < 4; dt++) {
      int d = dt * 16 + lr;
      bf16x8 bv0 = *reinterpret_cast<const bf16x8*>(&vtld[d][(lg * 8) ^ (d & 0x38)]);
      bf16x8 bv1 = *reinterpret_cast<const bf16x8*>(&vtld[d][(32 + lg * 8) ^ (d & 0x38)]);
      #pragma unroll
      for (int rt = 0; rt < 2; rt++) {
        oacc[rt][dt] = __builtin_amdgcn_mfma_f32_16x16x32_bf16(pa[rt][0], bv0, oacc[rt][dt], 0, 0, 0);
        oacc[rt][dt] = __builtin_amdgcn_mfma_f32_16x16x32_bf16(pa[rt][1], bv1, oacc[rt][dt], 0, 0, 0);
      }
    }
  }
  size_t pbase = (((size_t)(bh * 8 + slice) * M_ + mbase) << 6);
  #pragma unroll
  for (int rt = 0; rt < 2; rt++)
    #pragma unroll
    for (int dt = 0; dt < 4; dt++)
      #pragma unroll
      for (int r = 0; r < 4; r++)
        pvpart[pbase + ((size_t)(rt * 16 + 4 * lg + r) << 6) + dt * 16 + lr] = oacc[rt][dt][r];
  if (lr == 0) {
    #pragma unroll
    for (int rt = 0; rt < 2; rt++)
      #pragma unroll
      for (int r = 0; r < 4; r++)
        msbuf[(size_t)(bh * 8 + slice) * M_ + mbase + rt * 16 + 4 * lg + r] =
            make_float2(mrun[rt * 4 + r], srun[rt * 4 + r]);
  }
}

// ---------------- combine split-N partials -> pv^T bf16 [bh][64][256] ----------------
__global__ __launch_bounds__(256) void pv_combine(const float* __restrict__ pvpart,
    const float2* __restrict__ msbuf, unsigned short* __restrict__ pvT)
{
  int row = blockIdx.x * 4 + (threadIdx.x >> 6);
  int bh = row >> 8, m = row & (M_ - 1);
  int d = threadIdx.x & 63;
  float2 ms[8];
  float mg = -1e30f;
  #pragma unroll
  for (int s = 0; s < 8; s++) {
    ms[s] = msbuf[(size_t)(bh * 8 + s) * M_ + m];
    mg = fmaxf(mg, ms[s].x);
  }
  float ssum = 0.f, o = 0.f;
  #pragma unroll
  for (int s = 0; s < 8; s++) {
    float w = __expf(ms[s].x - mg);
    ssum += ms[s].y * w;
    o += w * pvpart[(((size_t)(bh * 8 + s) * M_ + m) << 6) + d];
  }
  pvT[((size_t)bh << 14) + (size_t)d * M_ + m] = f2bf(o / ssum);
}

// ---------------- attn1: oh = softmax(q @ kl^T) @ W2 via MFMA ----------------
__global__ __launch_bounds__(256) void attn1_kernel(
    const unsigned short* __restrict__ qb,
    const unsigned short* __restrict__ klb,
    const unsigned short* __restrict__ w2t,
    unsigned short* __restrict__ oh)
{
  int ntile = blockIdx.x & 31;
  int bh = blockIdx.x >> 5;
  int h = bh & (H_ - 1), b = bh >> 3;
  int tid = threadIdx.x, wid = tid >> 6, lane = tid & 63;
  int lr = lane & 15, lg = lane >> 4;
  __shared__ unsigned short plds_all[4][16][264];
  unsigned short* plds = &plds_all[wid][0][0];

  const unsigned short* qbh  = qb  + (((size_t)bh * N_) << 6);
  const unsigned short* klbh = klb + ((size_t)bh << 14);
  const unsigned short* w2bh = w2t + ((size_t)bh << 14);

  const f32x4 zf = {0.f, 0.f, 0.f, 0.f};
  for (int sub = 0; sub < 4; sub++) {
    int n0 = ntile * 256 + sub * 64 + wid * 16;
    bf16x8 aq0 = *reinterpret_cast<const bf16x8*>(&qbh[((size_t)(n0 + lr) << 6) + lg * 8]);
    bf16x8 aq1 = *reinterpret_cast<const bf16x8*>(&qbh[((size_t)(n0 + lr) << 6) + 32 + lg * 8]);
    f32x4 accs[16];
    #pragma unroll
    for (int mt = 0; mt < 16; mt++) {
      bf16x8 b0 = *reinterpret_cast<const bf16x8*>(&klbh[((size_t)(mt * 16 + lr) << 6) + lg * 8]);
      bf16x8 b1 = *reinterpret_cast<const bf16x8*>(&klbh[((size_t)(mt * 16 + lr) << 6) + 32 + lg * 8]);
      f32x4 a = __builtin_amdgcn_mfma_f32_16x16x32_bf16(aq0, b0, zf, 0, 0, 0);
      accs[mt] = __builtin_amdgcn_mfma_f32_16x16x32_bf16(aq1, b1, a, 0, 0, 0);
    }
    float rs[4];
    #pragma unroll
    for (int r = 0; r < 4; r++) {
      float m0 = accs[0][r];
      #pragma unroll
      for (int mt = 1; mt < 16; mt++) m0 = fmaxf(m0, accs[mt][r]);
      #pragma unroll
      for (int off = 1; off < 16; off <<= 1) m0 = fmaxf(m0, __shfl_xor(m0, off));
      float s0 = 0.f;
      #pragma unroll
      for (int mt = 0; mt < 16; mt++) {
        float p = __expf(accs[mt][r] - m0);
        accs[mt][r] = p;
        s0 += p;
      }
      #pragma unroll
      for (int off = 1; off < 16; off <<= 1) s0 += __shfl_xor(s0, off);
      rs[r] = 1.f / s0;
    }
    #pragma unroll
    for (int mt = 0; mt < 16; mt++)
      #pragma unroll
      for (int r = 0; r < 4; r++)
        plds[(4 * lg + r) * 264 + mt * 16 + lr] = f2bf(accs[mt][r]);
    __builtin_amdgcn_s_waitcnt(0);
    bf16x8 pa[8];
    #pragma unroll
    for (int mc = 0; mc < 8; mc++)
      pa[mc] = *reinterpret_cast<const bf16x8*>(&plds[lr * 264 + mc * 32 + lg * 8]);
    f32x4 acco[4];
    #pragma unroll
    for (int dt = 0; dt < 4; dt++) {
      f32x4 a = zf;
      #pragma unroll
      for (int mc = 0; mc < 8; mc++) {
        bf16x8 wf = *reinterpret_cast<const bf16x8*>(&w2bh[(size_t)(dt * 16 + lr) * M_ + mc * 32 + lg * 8]);
        a = __builtin_amdgcn_mfma_f32_16x16x32_bf16(pa[mc], wf, a, 0, 0, 0);
      }
      acco[dt] = a;
    }
    #pragma unroll
    for (int dt = 0; dt < 4; dt++)
      #pragma unroll
      for (int r = 0; r < 4; r++) {
        int n = n0 + 4 * lg + r;
        oh[((size_t)(b * N_ + n) << 9) + h * DH_ + dt * 16 + lr] = f2bf(acco[dt][r] * rs[r]);
      }
  }
}

// ---------------- depthwise conv residual: register sliding window ----------------
__global__ __launch_bounds__(256) void conv_kernel(const unsigned short* __restrict__ vb,
    const float* __restrict__ rw, unsigned short* __restrict__ oh)
{
  int bh = blockIdx.y;
  int h = bh & (H_ - 1), b = bh >> 3;
  int d = threadIdx.x & 63, g = threadIdx.x >> 6;
  int n0 = blockIdx.x * 128 + g * 32;
  const unsigned short* vbb = vb + (((size_t)bh * N_) << 6) + d;
  float w[64];
  #pragma unroll
  for (int j = 0; j < 64; j++) {
    int nn = n0 - 16 + j;
    w[j] = (nn >= 0 && nn < N_) ? bf2f(vbb[(size_t)nn << 6]) : 0.f;
  }
  float rwr[RESK_];
  #pragma unroll
  for (int j = 0; j < RESK_; j++) rwr[j] = rw[h * RESK_ + j];
  size_t obase = (((size_t)(b * N_ + n0)) << 9) + h * 64 + d;
  #pragma unroll
  for (int t = 0; t < 32; t++) {
    float acc = 0.f;
    #pragma unroll
    for (int j = 0; j < RESK_; j++) acc += rwr[j] * w[t + j];
    size_t oi = obase + ((size_t)t << 9);
    oh[oi] = f2bf(bf2f(oh[oi]) + acc);
  }
}

extern "C" void kernel_launch(void* const* d_in, const int* in_sizes, int n_in,
                              void* d_out, int out_size, void* d_ws, size_t ws_size,
                              hipStream_t stream)
{
  const float* x     = (const float*)d_in[0];
  const float* ln_w  = (const float*)d_in[1];
  const float* ln_b  = (const float*)d_in[2];
  const float* w_qkv = (const float*)d_in[3];
  const float* w_out = (const float*)d_in[4];
  const float* b_out = (const float*)d_in[5];
  const float* res_w = (const float*)d_in[6];
  float* out = (float*)d_out;

  const size_t HEADEL = (size_t)B_ * H_ * N_ * DH_;   // 16,777,216
  const size_t SMALL  = (size_t)B_ * H_ * M_ * DH_;   // 524,288
  const size_t MSQ    = (size_t)B_ * H_ * M_ * M_;    // 2,097,152

  char* p = (char*)d_ws;
  auto alloc = [&](size_t bytes) { char* r = p; p += (bytes + 255) & ~(size_t)255; return r; };

  unsigned short* qb  = (unsigned short*)alloc(HEADEL * 2);
  unsigned short* kb  = (unsigned short*)alloc(HEADEL * 2);
  unsigned short* vb  = (unsigned short*)alloc(HEADEL * 2);
  unsigned short* oh  = (unsigned short*)alloc(HEADEL * 2);
  // union A: xnb (32 MB) then z ping-pong (R and T forms, 4 x 4 MB)
  char* unA = alloc(HEADEL * 2);
  unsigned short* xnb = (unsigned short*)unA;
  unsigned short* z0R = (unsigned short*)unA;
  unsigned short* z0T = z0R + MSQ;
  unsigned short* z1R = z0T + MSQ;
  unsigned short* z1T = z1R + MSQ;
  // union B: pvpart f32 (16 MB) + msbuf then u / vT / wT / yT (4 x 4 MB)
  char* unB = alloc(HEADEL * 2);
  float*  pvpart = (float*)unB;
  float2* msbuf  = (float2*)(unB + (size_t)B_ * H_ * 8 * M_ * DH_ * 4);
  unsigned short* ub  = (unsigned short*)unB;
  unsigned short* vTb = ub + MSQ;
  unsigned short* wTb = vTb + MSQ;
  unsigned short* yTb = wTb + MSQ;

  unsigned short* wqkvT = (unsigned short*)alloc((size_t)K3_ * DIM_ * 2);
  unsigned short* woutT = (unsigned short*)alloc((size_t)DIM_ * INNER_ * 2);
  float* ql  = (float*)alloc(SMALL * 4);
  float* kl  = (float*)alloc(SMALL * 4);
  unsigned short* qlb = (unsigned short*)alloc(SMALL * 2);
  unsigned short* klb = (unsigned short*)alloc(SMALL * 2);
  unsigned short* pvT = (unsigned short*)alloc(SMALL * 2);
  unsigned short* w2t = (unsigned short*)alloc(SMALL * 2);
  unsigned short* a2b = (unsigned short*)alloc(MSQ * 2);
  unsigned int* scal  = (unsigned int*)alloc(256);
  if ((size_t)(p - (char*)d_ws) > ws_size) return;

  float* a2 = (float*)d_out;   // 8 MB, dead before mfma_out overwrites d_out

  ln_bf16<<<B_ * N_, 256, 0, stream>>>(x, ln_w, ln_b, xnb);
  transpose_w<<<dim3(K3_ / 64, DIM_ / 64), 256, 0, stream>>>(w_qkv, wqkvT, DIM_, K3_, INNER_, 0.125f);
  transpose_w<<<dim3(DIM_ / 64, INNER_ / 64), 256, 0, stream>>>(w_out, woutT, INNER_, DIM_, 0, 1.f);
  mfma_qkv<<<dim3(K3_ / 128, (B_ * N_) / 128), 256, 0, stream>>>(xnb, wqkvT, qb, kb, vb);
  landmark_kernel<<<B_ * H_ * M_, 64, 0, stream>>>(qb, kb, ql, kl, qlb, klb);
  attn2_kernel<<<B_ * H_ * M_, 256, 0, stream>>>(ql, kl, a2, a2b);
  zero_scal<<<1, 2, 0, stream>>>(scal);
  pinv_scale_kernel<<<B_ * H_, 256, 0, stream>>>(a2, scal);
  pv_mfma<<<dim3(8, 2, B_ * H_), 256, 0, stream>>>(kb, vb, qlb, pvpart, msbuf);
  pv_combine<<<(B_ * H_ * M_) / 4, 256, 0, stream>>>(pvpart, msbuf, pvT);
  // zinit AFTER mfma_qkv (xnb dead)
  zinit_kernel<<<dim3(4, 4, B_ * H_), 256, 0, stream>>>(a2, scal, z0R, z0T);

  // Newton-Schulz chain, pure bf16 (self-correcting iteration; chain bufs overwrite pvpart)
  unsigned short *cR = z0R, *cT = z0T, *nR = z1R, *nT = z1T;
  dim3 g44(4, 4, B_ * H_);
  for (int it = 0; it < 6; it++) {
    // u = a2 @ z (R) ; vT = (7I - u)^T
    bgemm_ns<<<g44, 256, 0, stream>>>(a2b, cT, ub, vTb, 7.f, -1.f, 1.f);
    // wT = (15I - u@v)^T
    bgemm_ns<<<g44, 256, 0, stream>>>(ub, vTb, nullptr, wTb, 15.f, -1.f, 0.f);
    // yT = (13I - u@w)^T
    bgemm_ns<<<g44, 256, 0, stream>>>(ub, wTb, nullptr, yTb, 13.f, -1.f, 0.f);
    // z' = 0.25 z@y : both R and T forms
    bgemm_ns<<<g44, 256, 0, stream>>>(cR, yTb, nR, nT, 0.f, 0.25f, 0.25f);
    unsigned short* t;
    t = cR; cR = nR; nR = t;  t = cT; cT = nT; nT = t;
  }

  gemm_w2<<<dim3(4, B_ * H_), 256, 0, stream>>>(cR, pvT, w2t);

  attn1_kernel<<<B_ * H_ * (N_ / 256), 256, 0, stream>>>(qb, klb, w2t, oh);
  conv_kernel<<<dim3(N_ / 128, B_ * H_), 256, 0, stream>>>(vb, res_w, oh);
  mfma_out<<<dim3(DIM_ / 128, (B_ * N_) / 128), 256, 0, stream>>>(oh, woutT, b_out, x, out);
}

// Round 10
// 663.492 us; speedup vs baseline: 7.7821x; 1.0434x over previous
//
#include <hip/hip_runtime.h>
#include <cstdint>

#define B_ 4
#define N_ 8192
#define DIM_ 512
#define H_ 8
#define DH_ 64
#define M_ 256
#define L_ 32
#define INNER_ 512
#define K3_ 1536
#define RESK_ 33

struct __align__(16) ushort8_t { unsigned short u[8]; };
typedef short bf16x8 __attribute__((ext_vector_type(8)));
typedef float f32x4 __attribute__((ext_vector_type(4)));

__device__ __forceinline__ float bf2f(unsigned short u) {
  return __uint_as_float(((unsigned)u) << 16);
}
__device__ __forceinline__ unsigned short f2bf(float f) {
  unsigned x = __float_as_uint(f);
  return (unsigned short)((x + 0x7fffu + ((x >> 16) & 1u)) >> 16);  // RNE
}

// ---------------- fused LayerNorm -> bf16 activations ----------------
__global__ __launch_bounds__(256) void ln_bf16(const float* __restrict__ x,
    const float* __restrict__ w, const float* __restrict__ bb, unsigned short* __restrict__ xnb)
{
  int row = blockIdx.x;
  int tid = threadIdx.x;
  float2 v = reinterpret_cast<const float2*>(x + (size_t)row * DIM_)[tid];
  float s = v.x + v.y, s2 = v.x * v.x + v.y * v.y;
  #pragma unroll
  for (int off = 32; off; off >>= 1) { s += __shfl_down(s, off); s2 += __shfl_down(s2, off); }
  __shared__ float rs[4], rs2[4];
  int wid = tid >> 6, lane = tid & 63;
  if (lane == 0) { rs[wid] = s; rs2[wid] = s2; }
  __syncthreads();
  float ts = rs[0] + rs[1] + rs[2] + rs[3];
  float ts2 = rs2[0] + rs2[1] + rs2[2] + rs2[3];
  float mu = ts * (1.f / DIM_);
  float var = ts2 * (1.f / DIM_) - mu * mu;
  float inv = rsqrtf(var + 1e-5f);
  int c = tid * 2;
  unsigned int p0 = f2bf((v.x - mu) * inv * w[c] + bb[c]);
  unsigned int p1 = f2bf((v.y - mu) * inv * w[c + 1] + bb[c + 1]);
  reinterpret_cast<unsigned int*>(xnb + (size_t)row * DIM_)[tid] = p0 | (p1 << 16);
}

// ---------------- transpose weights to bf16 ----------------
__global__ __launch_bounds__(256) void transpose_w(const float* __restrict__ src,
    unsigned short* __restrict__ dst, int K, int C, int qcols, float qs)
{
  __shared__ float T[64][65];
  int c0 = blockIdx.x * 64, k0 = blockIdx.y * 64;
  #pragma unroll 4
  for (int it = 0; it < 16; it++) {
    int idx = it * 256 + threadIdx.x;
    int kk = idx >> 6, cc = idx & 63;
    T[kk][cc] = src[(size_t)(k0 + kk) * C + c0 + cc];
  }
  __syncthreads();
  #pragma unroll 4
  for (int it = 0; it < 16; it++) {
    int idx = it * 256 + threadIdx.x;
    int cc = idx >> 6, kk = idx & 63;
    float v = T[kk][cc];
    int c = c0 + cc;
    dst[(size_t)c * K + k0 + kk] = f2bf(c < qcols ? v * qs : v);
  }
}

// ---------------- MFMA GEMM: qkv = xnb @ wT^T, scatter head-major bf16 ----------------
__global__ __launch_bounds__(256, 2) void mfma_qkv(const unsigned short* __restrict__ xnb,
    const unsigned short* __restrict__ wT,
    unsigned short* __restrict__ qb, unsigned short* __restrict__ kb, unsigned short* __restrict__ vb)
{
  __shared__ unsigned short As[128][72];
  __shared__ unsigned short Bs[128][72];
  int tid = threadIdx.x;
  int bn = blockIdx.x * 128, bm = blockIdx.y * 128;
  int wid = tid >> 6, lane = tid & 63;
  int wr = wid >> 1, wc = wid & 1;
  int lr = lane & 15, lg = lane >> 4;
  const f32x4 zf = {0.f, 0.f, 0.f, 0.f};
  f32x4 acc[4][4];
  #pragma unroll
  for (int mt = 0; mt < 4; mt++)
    #pragma unroll
    for (int nt = 0; nt < 4; nt++) acc[mt][nt] = zf;

  for (int k0 = 0; k0 < DIM_; k0 += 64) {
    __syncthreads();
    #pragma unroll
    for (int rnd = 0; rnd < 4; rnd++) {
      int idx = rnd * 2048 + tid * 8;
      int row = idx >> 6, col = idx & 63;
      *reinterpret_cast<bf16x8*>(&As[row][col]) =
          *reinterpret_cast<const bf16x8*>(&xnb[(size_t)(bm + row) * DIM_ + k0 + col]);
      *reinterpret_cast<bf16x8*>(&Bs[row][col]) =
          *reinterpret_cast<const bf16x8*>(&wT[(size_t)(bn + row) * DIM_ + k0 + col]);
    }
    __syncthreads();
    bf16x8 af[4][2], bfr[4][2];
    #pragma unroll
    for (int mt = 0; mt < 4; mt++) {
      af[mt][0] = *reinterpret_cast<const bf16x8*>(&As[wr * 64 + mt * 16 + lr][lg * 8]);
      af[mt][1] = *reinterpret_cast<const bf16x8*>(&As[wr * 64 + mt * 16 + lr][32 + lg * 8]);
    }
    #pragma unroll
    for (int nt = 0; nt < 4; nt++) {
      bfr[nt][0] = *reinterpret_cast<const bf16x8*>(&Bs[wc * 64 + nt * 16 + lr][lg * 8]);
      bfr[nt][1] = *reinterpret_cast<const bf16x8*>(&Bs[wc * 64 + nt * 16 + lr][32 + lg * 8]);
    }
    #pragma unroll
    for (int mt = 0; mt < 4; mt++)
      #pragma unroll
      for (int nt = 0; nt < 4; nt++) {
        acc[mt][nt] = __builtin_amdgcn_mfma_f32_16x16x32_bf16(af[mt][0], bfr[nt][0], acc[mt][nt], 0, 0, 0);
        acc[mt][nt] = __builtin_amdgcn_mfma_f32_16x16x32_bf16(af[mt][1], bfr[nt][1], acc[mt][nt], 0, 0, 0);
      }
  }
  #pragma unroll
  for (int nt = 0; nt < 4; nt++) {
    int c = bn + wc * 64 + nt * 16 + lr;
    int which = c >> 9;
    int h = (c >> 6) & (H_ - 1);
    int d = c & 63;
    unsigned short* dst = which == 0 ? qb : (which == 1 ? kb : vb);
    #pragma unroll
    for (int mt = 0; mt < 4; mt++)
      #pragma unroll
      for (int r = 0; r < 4; r++) {
        int row = bm + wr * 64 + mt * 16 + 4 * lg + r;
        int b = row >> 13, n = row & (N_ - 1);
        dst[(((size_t)(b * H_ + h) * N_ + n) << 6) + d] = f2bf(acc[mt][nt][r]);
      }
  }
}

// ---------------- MFMA GEMM: out = oh @ woutT^T + bias + resid (f32 out) ----------------
__global__ __launch_bounds__(256, 2) void mfma_out(const unsigned short* __restrict__ oh,
    const unsigned short* __restrict__ wT, const float* __restrict__ bias,
    const float* __restrict__ resid, float* __restrict__ out)
{
  __shared__ unsigned short As[128][72];
  __shared__ unsigned short Bs[128][72];
  int tid = threadIdx.x;
  int bn = blockIdx.x * 128, bm = blockIdx.y * 128;
  int wid = tid >> 6, lane = tid & 63;
  int wr = wid >> 1, wc = wid & 1;
  int lr = lane & 15, lg = lane >> 4;
  const f32x4 zf = {0.f, 0.f, 0.f, 0.f};
  f32x4 acc[4][4];
  #pragma unroll
  for (int mt = 0; mt < 4; mt++)
    #pragma unroll
    for (int nt = 0; nt < 4; nt++) acc[mt][nt] = zf;

  for (int k0 = 0; k0 < INNER_; k0 += 64) {
    __syncthreads();
    #pragma unroll
    for (int rnd = 0; rnd < 4; rnd++) {
      int idx = rnd * 2048 + tid * 8;
      int row = idx >> 6, col = idx & 63;
      *reinterpret_cast<bf16x8*>(&As[row][col]) =
          *reinterpret_cast<const bf16x8*>(&oh[((size_t)(bm + row) << 9) + k0 + col]);
      *reinterpret_cast<bf16x8*>(&Bs[row][col]) =
          *reinterpret_cast<const bf16x8*>(&wT[(size_t)(bn + row) * INNER_ + k0 + col]);
    }
    __syncthreads();
    bf16x8 af[4][2], bfr[4][2];
    #pragma unroll
    for (int mt = 0; mt < 4; mt++) {
      af[mt][0] = *reinterpret_cast<const bf16x8*>(&As[wr * 64 + mt * 16 + lr][lg * 8]);
      af[mt][1] = *reinterpret_cast<const bf16x8*>(&As[wr * 64 + mt * 16 + lr][32 + lg * 8]);
    }
    #pragma unroll
    for (int nt = 0; nt < 4; nt++) {
      bfr[nt][0] = *reinterpret_cast<const bf16x8*>(&Bs[wc * 64 + nt * 16 + lr][lg * 8]);
      bfr[nt][1] = *reinterpret_cast<const bf16x8*>(&Bs[wc * 64 + nt * 16 + lr][32 + lg * 8]);
    }
    #pragma unroll
    for (int mt = 0; mt < 4; mt++)
      #pragma unroll
      for (int nt = 0; nt < 4; nt++) {
        acc[mt][nt] = __builtin_amdgcn_mfma_f32_16x16x32_bf16(af[mt][0], bfr[nt][0], acc[mt][nt], 0, 0, 0);
        acc[mt][nt] = __builtin_amdgcn_mfma_f32_16x16x32_bf16(af[mt][1], bfr[nt][1], acc[mt][nt], 0, 0, 0);
      }
  }
  #pragma unroll
  for (int nt = 0; nt < 4; nt++) {
    int c = bn + wc * 64 + nt * 16 + lr;
    float bias_c = bias[c];
    #pragma unroll
    for (int mt = 0; mt < 4; mt++)
      #pragma unroll
      for (int r = 0; r < 4; r++) {
        int row = bm + wr * 64 + mt * 16 + 4 * lg + r;
        out[(size_t)row * DIM_ + c] = acc[mt][nt][r] + bias_c + resid[(size_t)row * DIM_ + c];
      }
  }
}

// ---------------- landmark means (f32 + bf16 q_l, bf16 k_l) ----------------
__global__ __launch_bounds__(64) void landmark_kernel(const unsigned short* __restrict__ qb,
    const unsigned short* __restrict__ kb, float* __restrict__ ql, float* __restrict__ kl,
    unsigned short* __restrict__ qlb, unsigned short* __restrict__ klb)
{
  int id = blockIdx.x;
  int m = id & (M_ - 1);
  int bh = id >> 8;
  int d = threadIdx.x;
  size_t base = (((size_t)bh * N_ + m * L_) << 6) + d;
  float sq = 0, sk = 0;
  #pragma unroll 4
  for (int j = 0; j < L_; j++) {
    sq += bf2f(qb[base + ((size_t)j << 6)]);
    sk += bf2f(kb[base + ((size_t)j << 6)]);
  }
  float qv = sq * (1.f / L_);
  float kv = sk * (1.f / L_);
  size_t o = ((size_t)bh * M_ + m) * DH_ + d;
  ql[o] = qv;
  kl[o] = kv;
  qlb[o] = f2bf(qv);
  klb[o] = f2bf(kv);
}

// ---------------- sim2 + softmax -> attn2 (f32 + bf16) ----------------
__global__ __launch_bounds__(256) void attn2_kernel(const float* __restrict__ ql,
    const float* __restrict__ kl, float* __restrict__ a2, unsigned short* __restrict__ a2b)
{
  int id = blockIdx.x;
  int i = id & (M_ - 1);
  int bh = id >> 8;
  int j = threadIdx.x;
  __shared__ float qs[DH_];
  __shared__ float wred[4];
  if (j < DH_) qs[j] = ql[((size_t)bh * M_ + i) * DH_ + j];
  __syncthreads();
  const float* krow = kl + ((size_t)bh * M_ + j) * DH_;
  float s = 0;
  #pragma unroll
  for (int d = 0; d < DH_; d++) s += qs[d] * krow[d];
  float mx = s;
  #pragma unroll
  for (int off = 1; off < 64; off <<= 1) mx = fmaxf(mx, __shfl_xor(mx, off));
  int wid = j >> 6, lane = j & 63;
  if (lane == 0) wred[wid] = mx;
  __syncthreads();
  mx = fmaxf(fmaxf(wred[0], wred[1]), fmaxf(wred[2], wred[3]));
  float e = __expf(s - mx);
  float sum = e;
  #pragma unroll
  for (int off = 1; off < 64; off <<= 1) sum += __shfl_xor(sum, off);
  __syncthreads();
  if (lane == 0) wred[wid] = sum;
  __syncthreads();
  sum = wred[0] + wred[1] + wred[2] + wred[3];
  float p = e / sum;
  size_t o = ((size_t)bh * M_ + i) * M_ + j;
  a2[o] = p;
  a2b[o] = f2bf(p);
}

// ---------------- pinv scale ----------------
__global__ void zero_scal(unsigned int* scal) { scal[threadIdx.x] = 0u; }

__global__ __launch_bounds__(256) void pinv_scale_kernel(const float* __restrict__ a2,
    unsigned int* __restrict__ scal)
{
  int bh = blockIdx.x;
  int t = threadIdx.x;
  const float* xb = a2 + (size_t)bh * M_ * M_;
  float rowsum = 0, colsum = 0;
  for (int j = 0; j < M_; j++) {
    rowsum += xb[(size_t)t * M_ + j];
    colsum += xb[(size_t)j * M_ + t];
  }
  #pragma unroll
  for (int off = 1; off < 64; off <<= 1) {
    rowsum = fmaxf(rowsum, __shfl_xor(rowsum, off));
    colsum = fmaxf(colsum, __shfl_xor(colsum, off));
  }
  __shared__ float wr[4], wc[4];
  int wid = t >> 6, lane = t & 63;
  if (lane == 0) { wr[wid] = rowsum; wc[wid] = colsum; }
  __syncthreads();
  if (t == 0) {
    float rm = fmaxf(fmaxf(wr[0], wr[1]), fmaxf(wr[2], wr[3]));
    float cm = fmaxf(fmaxf(wc[0], wc[1]), fmaxf(wc[2], wc[3]));
    atomicMax(&scal[0], __float_as_uint(rm));
    atomicMax(&scal[1], __float_as_uint(cm));
  }
}

// ---------------- z0 = a2^T/s: row-form (LDS transpose) + T-form (direct) bf16 ----------------
__global__ __launch_bounds__(256) void zinit_kernel(const float* __restrict__ a2,
    const unsigned int* __restrict__ scal,
    unsigned short* __restrict__ zR, unsigned short* __restrict__ zT)
{
  __shared__ float T[64][65];
  int j0 = blockIdx.x * 64, i0 = blockIdx.y * 64;
  size_t bb = (size_t)blockIdx.z * (M_ * M_);
  float inv = 1.f / (__uint_as_float(scal[0]) * __uint_as_float(scal[1]));
  int tid = threadIdx.x;
  #pragma unroll 4
  for (int pass = 0; pass < 16; pass++) {
    int idx = pass * 256 + tid;
    int ii = idx >> 6, jj = idx & 63;
    float v = a2[bb + (size_t)(i0 + ii) * M_ + j0 + jj];
    T[ii][jj] = v;
    zT[bb + (size_t)(i0 + ii) * M_ + j0 + jj] = f2bf(v * inv);  // zT[n][k] = a2[n][k]*inv
  }
  __syncthreads();
  #pragma unroll 4
  for (int pass = 0; pass < 16; pass++) {
    int idx = pass * 256 + tid;
    int jj = idx >> 6, ii = idx & 63;
    zR[bb + (size_t)(j0 + jj) * M_ + i0 + ii] = f2bf(T[ii][jj] * inv);  // z0[j][i]
  }
}

// ---------------- batched bf16 MFMA GEMM, B pre-transposed (T-form [n][k]) ----------------
// C = A @ B. Outputs: R (row) = sR*C ; YT (T-form via LDS bounce) = (aY*I + sY*C)^T.
__global__ __launch_bounds__(256, 2) void bgemm_ns(
    const unsigned short* __restrict__ Ab, const unsigned short* __restrict__ BTb,
    unsigned short* __restrict__ Rb, unsigned short* __restrict__ YTb,
    float aY, float sY, float sR)
{
  __shared__ unsigned short Ash[64][72];   // [row][k]
  __shared__ unsigned short Bsh[64][72];   // [col][k]
  int bn = blockIdx.x * 64, bm = blockIdx.y * 64;
  size_t bb = (size_t)blockIdx.z * (M_ * M_);
  int tid = threadIdx.x, wid = tid >> 6, lane = tid & 63;
  int lr = lane & 15, lg = lane >> 4;
  int wr = (wid >> 1) * 32, wc = (wid & 1) * 32;   // wave tile 32x32
  const f32x4 zf = {0.f, 0.f, 0.f, 0.f};
  f32x4 acc[2][2];
  #pragma unroll
  for (int mt = 0; mt < 2; mt++)
    #pragma unroll
    for (int nt = 0; nt < 2; nt++) acc[mt][nt] = zf;

  for (int k0 = 0; k0 < M_; k0 += 64) {
    __syncthreads();
    #pragma unroll
    for (int pass = 0; pass < 2; pass++) {
      int idx = pass * 2048 + tid * 8;
      int row = idx >> 6, col = idx & 63;
      *reinterpret_cast<bf16x8*>(&Ash[row][col]) =
          *reinterpret_cast<const bf16x8*>(&Ab[bb + (size_t)(bm + row) * M_ + k0 + col]);
      *reinterpret_cast<bf16x8*>(&Bsh[row][col]) =
          *reinterpret_cast<const bf16x8*>(&BTb[bb + (size_t)(bn + row) * M_ + k0 + col]);
    }
    __syncthreads();
    #pragma unroll
    for (int kk = 0; kk < 64; kk += 32) {
      bf16x8 a0 = *reinterpret_cast<const bf16x8*>(&Ash[wr + lr][kk + lg * 8]);
      bf16x8 a1 = *reinterpret_cast<const bf16x8*>(&Ash[wr + 16 + lr][kk + lg * 8]);
      bf16x8 b0 = *reinterpret_cast<const bf16x8*>(&Bsh[wc + lr][kk + lg * 8]);
      bf16x8 b1 = *reinterpret_cast<const bf16x8*>(&Bsh[wc + 16 + lr][kk + lg * 8]);
      acc[0][0] = __builtin_amdgcn_mfma_f32_16x16x32_bf16(a0, b0, acc[0][0], 0, 0, 0);
      acc[0][1] = __builtin_amdgcn_mfma_f32_16x16x32_bf16(a0, b1, acc[0][1], 0, 0, 0);
      acc[1][0] = __builtin_amdgcn_mfma_f32_16x16x32_bf16(a1, b0, acc[1][0], 0, 0, 0);
      acc[1][1] = __builtin_amdgcn_mfma_f32_16x16x32_bf16(a1, b1, acc[1][1], 0, 0, 0);
    }
  }
  // ---- R: direct row-major stores ----
  if (Rb) {
    #pragma unroll
    for (int mt = 0; mt < 2; mt++)
      #pragma unroll
      for (int nt = 0; nt < 2; nt++) {
        int col = bn + wc + nt * 16 + lr;
        #pragma unroll
        for (int r = 0; r < 4; r++) {
          int row = bm + wr + mt * 16 + 4 * lg + r;
          Rb[bb + (size_t)row * M_ + col] = f2bf(sR * acc[mt][nt][r]);
        }
      }
  }
  // ---- YT: T-form via LDS bounce (reuse Ash), coalesced b128 stores ----
  if (YTb) {
    __syncthreads();
    #pragma unroll
    for (int mt = 0; mt < 2; mt++)
      #pragma unroll
      for (int nt = 0; nt < 2; nt++) {
        int nl = wc + nt * 16 + lr;
        #pragma unroll
        for (int r = 0; r < 4; r++) {
          int ml = wr + mt * 16 + 4 * lg + r;
          float t = sY * acc[mt][nt][r] + ((bm + ml) == (bn + nl) ? aY : 0.f);
          Ash[nl][ml] = f2bf(t);
        }
      }
    __syncthreads();
    #pragma unroll
    for (int pass = 0; pass < 2; pass++) {
      int idx = pass * 2048 + tid * 8;
      int nl = idx >> 6, ml = idx & 63;
      *reinterpret_cast<bf16x8*>(&YTb[bb + (size_t)(bn + nl) * M_ + bm + ml]) =
          *reinterpret_cast<const bf16x8*>(&Ash[nl][ml]);
    }
  }
}

// ---------------- W2 = pinv @ pv -> w2t bf16 [bh][64][256] ----------------
__global__ __launch_bounds__(256) void gemm_w2(
    const unsigned short* __restrict__ zR,
    const unsigned short* __restrict__ pvT, unsigned short* __restrict__ w2t)
{
  int bm = blockIdx.x * 64;
  int batch = blockIdx.y;
  size_t bz = (size_t)batch * (M_ * M_);
  size_t bp = (size_t)batch << 14;
  int tid = threadIdx.x, wid = tid >> 6, lane = tid & 63;
  int lr = lane & 15, lg = lane >> 4;
  int r0 = bm + wid * 16;
  const f32x4 zf = {0.f, 0.f, 0.f, 0.f};
  f32x4 acc[4];
  #pragma unroll
  for (int nt = 0; nt < 4; nt++) acc[nt] = zf;

  #pragma unroll
  for (int k0 = 0; k0 < M_; k0 += 32) {
    bf16x8 a = *reinterpret_cast<const bf16x8*>(&zR[bz + (size_t)(r0 + lr) * M_ + k0 + lg * 8]);
    #pragma unroll
    for (int nt = 0; nt < 4; nt++) {
      bf16x8 b = *reinterpret_cast<const bf16x8*>(&pvT[bp + (size_t)(nt * 16 + lr) * M_ + k0 + lg * 8]);
      acc[nt] = __builtin_amdgcn_mfma_f32_16x16x32_bf16(a, b, acc[nt], 0, 0, 0);
    }
  }
  #pragma unroll
  for (int nt = 0; nt < 4; nt++) {
    int col = nt * 16 + lr;   // dh
    #pragma unroll
    for (int r = 0; r < 4; r++) {
      int row = r0 + 4 * lg + r;   // m
      w2t[bp + (size_t)col * M_ + row] = f2bf(acc[nt][r]);
    }
  }
}

// ---------------- pv partials: 8 waves x 32 rows, K/V staged once per (bh,slice) ----------------
__global__ __launch_bounds__(512) void pv_mfma(
    const unsigned short* __restrict__ kb, const unsigned short* __restrict__ vb,
    const unsigned short* __restrict__ qlb,
    float* __restrict__ pvpart, float2* __restrict__ msbuf)
{
  int slice = blockIdx.x;
  int bh    = blockIdx.z;
  int tid = threadIdx.x, wid = tid >> 6, lane = tid & 63;
  int lr = lane & 15, lg = lane >> 4;

  __shared__ unsigned short klds[64][72];
  __shared__ unsigned short vtld[64][72];
  __shared__ unsigned short plds_all[8][32][72];
  unsigned short (*plds)[72] = plds_all[wid];

  int mbase = wid * 32;   // 8 waves cover all 256 landmark rows
  const unsigned short* qbase = qlb + (((size_t)bh * M_ + mbase) << 6);
  bf16x8 qf[2][2];
  #pragma unroll
  for (int rt = 0; rt < 2; rt++)
    #pragma unroll
    for (int h2 = 0; h2 < 2; h2++)
      qf[rt][h2] = *reinterpret_cast<const bf16x8*>(&qbase[((rt * 16 + lr) << 6) + h2 * 32 + lg * 8]);

  const f32x4 zf = {0.f, 0.f, 0.f, 0.f};
  f32x4 oacc[2][4];
  #pragma unroll
  for (int rt = 0; rt < 2; rt++)
    #pragma unroll
    for (int dt = 0; dt < 4; dt++) oacc[rt][dt] = zf;
  float mrun[8], srun[8];
  #pragma unroll
  for (int i = 0; i < 8; i++) { mrun[i] = -1e30f; srun[i] = 0.f; }

  const unsigned short* kgb = kb + (((size_t)bh * N_ + slice * 1024) << 6);
  const unsigned short* vgb = vb + (((size_t)bh * N_ + slice * 1024) << 6);

  for (int c = 0; c < 16; c++) {
    __syncthreads();
    {
      int key = tid >> 3, seg = tid & 7;   // 512 threads: one b128 each
      size_t goff = (((size_t)(c * 64 + key)) << 6) + seg * 8;
      bf16x8 kv = *reinterpret_cast<const bf16x8*>(&kgb[goff]);
      *reinterpret_cast<bf16x8*>(&klds[key][seg * 8]) = kv;
      bf16x8 vv = *reinterpret_cast<const bf16x8*>(&vgb[goff]);
      int col = key ^ (seg << 3);
      #pragma unroll
      for (int j = 0; j < 8; j++) vtld[seg * 8 + j][col] = (unsigned short)vv[j];
    }
    __syncthreads();
    f32x4 sacc[2][4];
    #pragma unroll
    for (int rt = 0; rt < 2; rt++)
      #pragma unroll
      for (int ct = 0; ct < 4; ct++) {
        bf16x8 b0 = *reinterpret_cast<const bf16x8*>(&klds[ct * 16 + lr][lg * 8]);
        bf16x8 b1 = *reinterpret_cast<const bf16x8*>(&klds[ct * 16 + lr][32 + lg * 8]);
        f32x4 a = __builtin_amdgcn_mfma_f32_16x16x32_bf16(qf[rt][0], b0, zf, 0, 0, 0);
        sacc[rt][ct] = __builtin_amdgcn_mfma_f32_16x16x32_bf16(qf[rt][1], b1, a, 0, 0, 0);
      }
    #pragma unroll
    for (int rt = 0; rt < 2; rt++)
      #pragma unroll
      for (int r = 0; r < 4; r++) {
        int ri = rt * 4 + r;
        float mc = fmaxf(fmaxf(sacc[rt][0][r], sacc[rt][1][r]), fmaxf(sacc[rt][2][r], sacc[rt][3][r]));
        #pragma unroll
        for (int off = 1; off < 16; off <<= 1) mc = fmaxf(mc, __shfl_xor(mc, off));
        float mnew = fmaxf(mrun[ri], mc);
        float corr = __expf(mrun[ri] - mnew);
        float psum = 0.f;
        #pragma unroll
        for (int ct = 0; ct < 4; ct++) {
          float p = __expf(sacc[rt][ct][r] - mnew);
          sacc[rt][ct][r] = p;
          psum += p;
        }
        #pragma unroll
        for (int off = 1; off < 16; off <<= 1) psum += __shfl_xor(psum, off);
        srun[ri] = srun[ri] * corr + psum;
        mrun[ri] = mnew;
        #pragma unroll
        for (int dt = 0; dt < 4; dt++) oacc[rt][dt][r] *= corr;
        #pragma unroll
        for (int ct = 0; ct < 4; ct++)
          plds[rt * 16 + 4 * lg + r][ct * 16 + lr] = f2bf(sacc[rt][ct][r]);
      }
    __builtin_amdgcn_s_waitcnt(0);
    bf16x8 pa[2][2];
    #pragma unroll
    for (int rt = 0; rt < 2; rt++)
      #pragma unroll
      for (int h = 0; h < 2; h++)
        pa[rt][h] = *reinterpret_cast<const bf16x8*>(&plds[rt * 16 + lr][h * 32 + lg * 8]);
    #pragma unroll
    for (int dt = 0; dt < 4; dt++) {
      int d = dt * 16 + lr;
      bf16x8 bv0 = *reinterpret_cast<const bf16x8*>(&vtld[d][(lg * 8) ^ (d & 0x38)]);
      bf16x8 bv1 = *reinterpret_cast<const bf16x8*>(&vtld[d][(32 + lg * 8) ^ (d & 0x38)]);
      #pragma unroll
      for (int rt = 0; rt < 2; rt++) {
        oacc[rt][dt] = __builtin_amdgcn_mfma_f32_16x16x32_bf16(pa[rt][0], bv0, oacc[rt][dt], 0, 0, 0);
        oacc[rt][dt] = __builtin_amdgcn_mfma_f32_16x16x32_bf16(pa[rt][1], bv1, oacc[rt][dt], 0, 0, 0);
      }
    }
  }
  size_t pbase = (((size_t)(bh * 8 + slice) * M_ + mbase) << 6);
  #pragma unroll
  for (int rt = 0; rt < 2; rt++)
    #pragma unroll
    for (int dt = 0; dt < 4; dt++)
      #pragma unroll
      for (int r = 0; r < 4; r++)
        pvpart[pbase + ((size_t)(rt * 16 + 4 * lg + r) << 6) + dt * 16 + lr] = oacc[rt][dt][r];
  if (lr == 0) {
    #pragma unroll
    for (int rt = 0; rt < 2; rt++)
      #pragma unroll
      for (int r = 0; r < 4; r++)
        msbuf[(size_t)(bh * 8 + slice) * M_ + mbase + rt * 16 + 4 * lg + r] =
            make_float2(mrun[rt * 4 + r], srun[rt * 4 + r]);
  }
}

// ---------------- combine split-N partials -> pv^T bf16 [bh][64][256] ----------------
__global__ __launch_bounds__(256) void pv_combine(const float* __restrict__ pvpart,
    const float2* __restrict__ msbuf, unsigned short* __restrict__ pvT)
{
  int row = blockIdx.x * 4 + (threadIdx.x >> 6);
  int bh = row >> 8, m = row & (M_ - 1);
  int d = threadIdx.x & 63;
  float2 ms[8];
  float mg = -1e30f;
  #pragma unroll
  for (int s = 0; s < 8; s++) {
    ms[s] = msbuf[(size_t)(bh * 8 + s) * M_ + m];
    mg = fmaxf(mg, ms[s].x);
  }
  float ssum = 0.f, o = 0.f;
  #pragma unroll
  for (int s = 0; s < 8; s++) {
    float w = __expf(ms[s].x - mg);
    ssum += ms[s].y * w;
    o += w * pvpart[(((size_t)(bh * 8 + s) * M_ + m) << 6) + d];
  }
  pvT[((size_t)bh << 14) + (size_t)d * M_ + m] = f2bf(o / ssum);
}

// ---------------- attn1: oh = softmax(q @ kl^T) @ W2 via MFMA; kl staged in LDS ----------------
__global__ __launch_bounds__(256) void attn1_kernel(
    const unsigned short* __restrict__ qb,
    const unsigned short* __restrict__ klb,
    const unsigned short* __restrict__ w2t,
    unsigned short* __restrict__ oh)
{
  int ntile = blockIdx.x & 31;
  int bh = blockIdx.x >> 5;
  int h = bh & (H_ - 1), b = bh >> 3;
  int tid = threadIdx.x, wid = tid >> 6, lane = tid & 63;
  int lr = lane & 15, lg = lane >> 4;
  __shared__ unsigned short klds[256][72];
  __shared__ unsigned short plds_all[4][16][264];
  unsigned short* plds = &plds_all[wid][0][0];

  const unsigned short* qbh  = qb  + (((size_t)bh * N_) << 6);
  const unsigned short* klbh = klb + ((size_t)bh << 14);
  const unsigned short* w2bh = w2t + ((size_t)bh << 14);

  // stage kl (256x64 bf16) into LDS once per block, shared by 4 waves x 4 subs
  #pragma unroll
  for (int e = 0; e < 8; e++) {
    int idx = e * 2048 + tid * 8;
    int row = idx >> 6, col = idx & 63;
    *reinterpret_cast<bf16x8*>(&klds[row][col]) =
        *reinterpret_cast<const bf16x8*>(&klbh[((size_t)row << 6) + col]);
  }
  __syncthreads();

  const f32x4 zf = {0.f, 0.f, 0.f, 0.f};
  for (int sub = 0; sub < 4; sub++) {
    int n0 = ntile * 256 + sub * 64 + wid * 16;
    bf16x8 aq0 = *reinterpret_cast<const bf16x8*>(&qbh[((size_t)(n0 + lr) << 6) + lg * 8]);
    bf16x8 aq1 = *reinterpret_cast<const bf16x8*>(&qbh[((size_t)(n0 + lr) << 6) + 32 + lg * 8]);
    f32x4 accs[16];
    #pragma unroll
    for (int mt = 0; mt < 16; mt++) {
      bf16x8 b0 = *reinterpret_cast<const bf16x8*>(&klds[mt * 16 + lr][lg * 8]);
      bf16x8 b1 = *reinterpret_cast<const bf16x8*>(&klds[mt * 16 + lr][32 + lg * 8]);
      f32x4 a = __builtin_amdgcn_mfma_f32_16x16x32_bf16(aq0, b0, zf, 0, 0, 0);
      accs[mt] = __builtin_amdgcn_mfma_f32_16x16x32_bf16(aq1, b1, a, 0, 0, 0);
    }
    float rs[4];
    #pragma unroll
    for (int r = 0; r < 4; r++) {
      float m0 = accs[0][r];
      #pragma unroll
      for (int mt = 1; mt < 16; mt++) m0 = fmaxf(m0, accs[mt][r]);
      #pragma unroll
      for (int off = 1; off < 16; off <<= 1) m0 = fmaxf(m0, __shfl_xor(m0, off));
      float s0 = 0.f;
      #pragma unroll
      for (int mt = 0; mt < 16; mt++) {
        float p = __expf(accs[mt][r] - m0);
        accs[mt][r] = p;
        s0 += p;
      }
      #pragma unroll
      for (int off = 1; off < 16; off <<= 1) s0 += __shfl_xor(s0, off);
      rs[r] = 1.f / s0;
    }
    #pragma unroll
    for (int mt = 0; mt < 16; mt++)
      #pragma unroll
      for (int r = 0; r < 4; r++)
        plds[(4 * lg + r) * 264 + mt * 16 + lr] = f2bf(accs[mt][r]);
    __builtin_amdgcn_s_waitcnt(0);
    bf16x8 pa[8];
    #pragma unroll
    for (int mc = 0; mc < 8; mc++)
      pa[mc] = *reinterpret_cast<const bf16x8*>(&plds[lr * 264 + mc * 32 + lg * 8]);
    f32x4 acco[4];
    #pragma unroll
    for (int dt = 0; dt < 4; dt++) {
      f32x4 a = zf;
      #pragma unroll
      for (int mc = 0; mc < 8; mc++) {
        bf16x8 wf = *reinterpret_cast<const bf16x8*>(&w2bh[(size_t)(dt * 16 + lr) * M_ + mc * 32 + lg * 8]);
        a = __builtin_amdgcn_mfma_f32_16x16x32_bf16(pa[mc], wf, a, 0, 0, 0);
      }
      acco[dt] = a;
    }
    #pragma unroll
    for (int dt = 0; dt < 4; dt++)
      #pragma unroll
      for (int r = 0; r < 4; r++) {
        int n = n0 + 4 * lg + r;
        oh[((size_t)(b * N_ + n) << 9) + h * DH_ + dt * 16 + lr] = f2bf(acco[dt][r] * rs[r]);
      }
  }
}

// ---------------- depthwise conv residual: register sliding window ----------------
__global__ __launch_bounds__(256) void conv_kernel(const unsigned short* __restrict__ vb,
    const float* __restrict__ rw, unsigned short* __restrict__ oh)
{
  int bh = blockIdx.y;
  int h = bh & (H_ - 1), b = bh >> 3;
  int d = threadIdx.x & 63, g = threadIdx.x >> 6;
  int n0 = blockIdx.x * 128 + g * 32;
  const unsigned short* vbb = vb + (((size_t)bh * N_) << 6) + d;
  float w[64];
  #pragma unroll
  for (int j = 0; j < 64; j++) {
    int nn = n0 - 16 + j;
    w[j] = (nn >= 0 && nn < N_) ? bf2f(vbb[(size_t)nn << 6]) : 0.f;
  }
  float rwr[RESK_];
  #pragma unroll
  for (int j = 0; j < RESK_; j++) rwr[j] = rw[h * RESK_ + j];
  size_t obase = (((size_t)(b * N_ + n0)) << 9) + h * 64 + d;
  #pragma unroll
  for (int t = 0; t < 32; t++) {
    float acc = 0.f;
    #pragma unroll
    for (int j = 0; j < RESK_; j++) acc += rwr[j] * w[t + j];
    size_t oi = obase + ((size_t)t << 9);
    oh[oi] = f2bf(bf2f(oh[oi]) + acc);
  }
}

extern "C" void kernel_launch(void* const* d_in, const int* in_sizes, int n_in,
                              void* d_out, int out_size, void* d_ws, size_t ws_size,
                              hipStream_t stream)
{
  const float* x     = (const float*)d_in[0];
  const float* ln_w  = (const float*)d_in[1];
  const float* ln_b  = (const float*)d_in[2];
  const float* w_qkv = (const float*)d_in[3];
  const float* w_out = (const float*)d_in[4];
  const float* b_out = (const float*)d_in[5];
  const float* res_w = (const float*)d_in[6];
  float* out = (float*)d_out;

  const size_t HEADEL = (size_t)B_ * H_ * N_ * DH_;   // 16,777,216
  const size_t SMALL  = (size_t)B_ * H_ * M_ * DH_;   // 524,288
  const size_t MSQ    = (size_t)B_ * H_ * M_ * M_;    // 2,097,152

  char* p = (char*)d_ws;
  auto alloc = [&](size_t bytes) { char* r = p; p += (bytes + 255) & ~(size_t)255; return r; };

  unsigned short* qb  = (unsigned short*)alloc(HEADEL * 2);
  unsigned short* kb  = (unsigned short*)alloc(HEADEL * 2);
  unsigned short* vb  = (unsigned short*)alloc(HEADEL * 2);
  unsigned short* oh  = (unsigned short*)alloc(HEADEL * 2);
  // union A: xnb (32 MB) then z ping-pong (R and T forms, 4 x 4 MB)
  char* unA = alloc(HEADEL * 2);
  unsigned short* xnb = (unsigned short*)unA;
  unsigned short* z0R = (unsigned short*)unA;
  unsigned short* z0T = z0R + MSQ;
  unsigned short* z1R = z0T + MSQ;
  unsigned short* z1T = z1R + MSQ;
  // union B: pvpart f32 (16 MB) + msbuf then u / vT / wT / yT (4 x 4 MB)
  char* unB = alloc(HEADEL * 2);
  float*  pvpart = (float*)unB;
  float2* msbuf  = (float2*)(unB + (size_t)B_ * H_ * 8 * M_ * DH_ * 4);
  unsigned short* ub  = (unsigned short*)unB;
  unsigned short* vTb = ub + MSQ;
  unsigned short* wTb = vTb + MSQ;
  unsigned short* yTb = wTb + MSQ;

  unsigned short* wqkvT = (unsigned short*)alloc((size_t)K3_ * DIM_ * 2);
  unsigned short* woutT = (unsigned short*)alloc((size_t)DIM_ * INNER_ * 2);
  float* ql  = (float*)alloc(SMALL * 4);
  float* kl  = (float*)alloc(SMALL * 4);
  unsigned short* qlb = (unsigned short*)alloc(SMALL * 2);
  unsigned short* klb = (unsigned short*)alloc(SMALL * 2);
  unsigned short* pvT = (unsigned short*)alloc(SMALL * 2);
  unsigned short* w2t = (unsigned short*)alloc(SMALL * 2);
  unsigned short* a2b = (unsigned short*)alloc(MSQ * 2);
  unsigned int* scal  = (unsigned int*)alloc(256);
  if ((size_t)(p - (char*)d_ws) > ws_size) return;

  float* a2 = (float*)d_out;   // 8 MB, dead before mfma_out overwrites d_out

  ln_bf16<<<B_ * N_, 256, 0, stream>>>(x, ln_w, ln_b, xnb);
  transpose_w<<<dim3(K3_ / 64, DIM_ / 64), 256, 0, stream>>>(w_qkv, wqkvT, DIM_, K3_, INNER_, 0.125f);
  transpose_w<<<dim3(DIM_ / 64, INNER_ / 64), 256, 0, stream>>>(w_out, woutT, INNER_, DIM_, 0, 1.f);
  mfma_qkv<<<dim3(K3_ / 128, (B_ * N_) / 128), 256, 0, stream>>>(xnb, wqkvT, qb, kb, vb);
  landmark_kernel<<<B_ * H_ * M_, 64, 0, stream>>>(qb, kb, ql, kl, qlb, klb);
  attn2_kernel<<<B_ * H_ * M_, 256, 0, stream>>>(ql, kl, a2, a2b);
  zero_scal<<<1, 2, 0, stream>>>(scal);
  pinv_scale_kernel<<<B_ * H_, 256, 0, stream>>>(a2, scal);
  pv_mfma<<<dim3(8, 1, B_ * H_), 512, 0, stream>>>(kb, vb, qlb, pvpart, msbuf);
  pv_combine<<<(B_ * H_ * M_) / 4, 256, 0, stream>>>(pvpart, msbuf, pvT);
  // zinit AFTER mfma_qkv (xnb dead)
  zinit_kernel<<<dim3(4, 4, B_ * H_), 256, 0, stream>>>(a2, scal, z0R, z0T);

  // Newton-Schulz chain, pure bf16 (self-correcting iteration; chain bufs overwrite pvpart)
  unsigned short *cR = z0R, *cT = z0T, *nR = z1R, *nT = z1T;
  dim3 g44(4, 4, B_ * H_);
  for (int it = 0; it < 6; it++) {
    // u = a2 @ z (R) ; vT = (7I - u)^T
    bgemm_ns<<<g44, 256, 0, stream>>>(a2b, cT, ub, vTb, 7.f, -1.f, 1.f);
    // wT = (15I - u@v)^T
    bgemm_ns<<<g44, 256, 0, stream>>>(ub, vTb, nullptr, wTb, 15.f, -1.f, 0.f);
    // yT = (13I - u@w)^T
    bgemm_ns<<<g44, 256, 0, stream>>>(ub, wTb, nullptr, yTb, 13.f, -1.f, 0.f);
    // z' = 0.25 z@y : both R and T forms
    bgemm_ns<<<g44, 256, 0, stream>>>(cR, yTb, nR, nT, 0.f, 0.25f, 0.25f);
    unsigned short* t;
    t = cR; cR = nR; nR = t;  t = cT; cT = nT; nT = t;
  }

  gemm_w2<<<dim3(4, B_ * H_), 256, 0, stream>>>(cR, pvT, w2t);

  attn1_kernel<<<B_ * H_ * (N_ / 256), 256, 0, stream>>>(qb, klb, w2t, oh);
  conv_kernel<<<dim3(N_ / 128, B_ * H_), 256, 0, stream>>>(vb, res_w, oh);
  mfma_out<<<dim3(DIM_ / 128, (B_ * N_) / 128), 256, 0, stream>>>(oh, woutT, b_out, x, out);
}

// Round 11
// 608.577 us; speedup vs baseline: 8.4843x; 1.0902x over previous
//
#include <hip/hip_runtime.h>
#include <cstdint>

#define B_ 4
#define N_ 8192
#define DIM_ 512
#define H_ 8
#define DH_ 64
#define M_ 256
#define L_ 32
#define INNER_ 512
#define K3_ 1536
#define RESK_ 33

struct __align__(16) ushort8_t { unsigned short u[8]; };
typedef short bf16x8 __attribute__((ext_vector_type(8)));
typedef float f32x4 __attribute__((ext_vector_type(4)));

__device__ __forceinline__ float bf2f(unsigned short u) {
  return __uint_as_float(((unsigned)u) << 16);
}
__device__ __forceinline__ unsigned short f2bf(float f) {
  unsigned x = __float_as_uint(f);
  return (unsigned short)((x + 0x7fffu + ((x >> 16) & 1u)) >> 16);  // RNE
}

// ---------------- fused LayerNorm -> bf16 activations ----------------
__global__ __launch_bounds__(256) void ln_bf16(const float* __restrict__ x,
    const float* __restrict__ w, const float* __restrict__ bb, unsigned short* __restrict__ xnb)
{
  int row = blockIdx.x;
  int tid = threadIdx.x;
  float2 v = reinterpret_cast<const float2*>(x + (size_t)row * DIM_)[tid];
  float s = v.x + v.y, s2 = v.x * v.x + v.y * v.y;
  #pragma unroll
  for (int off = 32; off; off >>= 1) { s += __shfl_down(s, off); s2 += __shfl_down(s2, off); }
  __shared__ float rs[4], rs2[4];
  int wid = tid >> 6, lane = tid & 63;
  if (lane == 0) { rs[wid] = s; rs2[wid] = s2; }
  __syncthreads();
  float ts = rs[0] + rs[1] + rs[2] + rs[3];
  float ts2 = rs2[0] + rs2[1] + rs2[2] + rs2[3];
  float mu = ts * (1.f / DIM_);
  float var = ts2 * (1.f / DIM_) - mu * mu;
  float inv = rsqrtf(var + 1e-5f);
  int c = tid * 2;
  unsigned int p0 = f2bf((v.x - mu) * inv * w[c] + bb[c]);
  unsigned int p1 = f2bf((v.y - mu) * inv * w[c + 1] + bb[c + 1]);
  reinterpret_cast<unsigned int*>(xnb + (size_t)row * DIM_)[tid] = p0 | (p1 << 16);
}

// ---------------- transpose weights to bf16 ----------------
__global__ __launch_bounds__(256) void transpose_w(const float* __restrict__ src,
    unsigned short* __restrict__ dst, int K, int C, int qcols, float qs)
{
  __shared__ float T[64][65];
  int c0 = blockIdx.x * 64, k0 = blockIdx.y * 64;
  #pragma unroll 4
  for (int it = 0; it < 16; it++) {
    int idx = it * 256 + threadIdx.x;
    int kk = idx >> 6, cc = idx & 63;
    T[kk][cc] = src[(size_t)(k0 + kk) * C + c0 + cc];
  }
  __syncthreads();
  #pragma unroll 4
  for (int it = 0; it < 16; it++) {
    int idx = it * 256 + threadIdx.x;
    int cc = idx >> 6, kk = idx & 63;
    float v = T[kk][cc];
    int c = c0 + cc;
    dst[(size_t)c * K + k0 + kk] = f2bf(c < qcols ? v * qs : v);
  }
}

// ---------------- MFMA GEMM: qkv = xnb @ wT^T, XCD-swizzled, head-major bf16 out ----------------
__global__ __launch_bounds__(256, 2) void mfma_qkv(const unsigned short* __restrict__ xnb,
    const unsigned short* __restrict__ wT,
    unsigned short* __restrict__ qb, unsigned short* __restrict__ kb, unsigned short* __restrict__ vb)
{
  __shared__ unsigned short As[128][72];
  __shared__ unsigned short Bs[128][72];
  int tid = threadIdx.x;
  // XCD-aware bijective swizzle (nwg = 12*256 = 3072, %8==0): A-panel stays on one XCD
  int nwgx = gridDim.x, nwg = nwgx * gridDim.y;
  int l = blockIdx.y * nwgx + blockIdx.x;
  int swz = (l & 7) * (nwg >> 3) + (l >> 3);
  int bn = (swz % nwgx) * 128, bm = (swz / nwgx) * 128;
  int wid = tid >> 6, lane = tid & 63;
  int wr = wid >> 1, wc = wid & 1;
  int lr = lane & 15, lg = lane >> 4;
  const f32x4 zf = {0.f, 0.f, 0.f, 0.f};
  f32x4 acc[4][4];
  #pragma unroll
  for (int mt = 0; mt < 4; mt++)
    #pragma unroll
    for (int nt = 0; nt < 4; nt++) acc[mt][nt] = zf;

  for (int k0 = 0; k0 < DIM_; k0 += 64) {
    __syncthreads();
    #pragma unroll
    for (int rnd = 0; rnd < 4; rnd++) {
      int idx = rnd * 2048 + tid * 8;
      int row = idx >> 6, col = idx & 63;
      *reinterpret_cast<bf16x8*>(&As[row][col]) =
          *reinterpret_cast<const bf16x8*>(&xnb[(size_t)(bm + row) * DIM_ + k0 + col]);
      *reinterpret_cast<bf16x8*>(&Bs[row][col]) =
          *reinterpret_cast<const bf16x8*>(&wT[(size_t)(bn + row) * DIM_ + k0 + col]);
    }
    __syncthreads();
    bf16x8 af[4][2], bfr[4][2];
    #pragma unroll
    for (int mt = 0; mt < 4; mt++) {
      af[mt][0] = *reinterpret_cast<const bf16x8*>(&As[wr * 64 + mt * 16 + lr][lg * 8]);
      af[mt][1] = *reinterpret_cast<const bf16x8*>(&As[wr * 64 + mt * 16 + lr][32 + lg * 8]);
    }
    #pragma unroll
    for (int nt = 0; nt < 4; nt++) {
      bfr[nt][0] = *reinterpret_cast<const bf16x8*>(&Bs[wc * 64 + nt * 16 + lr][lg * 8]);
      bfr[nt][1] = *reinterpret_cast<const bf16x8*>(&Bs[wc * 64 + nt * 16 + lr][32 + lg * 8]);
    }
    __builtin_amdgcn_s_setprio(1);
    #pragma unroll
    for (int mt = 0; mt < 4; mt++)
      #pragma unroll
      for (int nt = 0; nt < 4; nt++) {
        acc[mt][nt] = __builtin_amdgcn_mfma_f32_16x16x32_bf16(af[mt][0], bfr[nt][0], acc[mt][nt], 0, 0, 0);
        acc[mt][nt] = __builtin_amdgcn_mfma_f32_16x16x32_bf16(af[mt][1], bfr[nt][1], acc[mt][nt], 0, 0, 0);
      }
    __builtin_amdgcn_s_setprio(0);
  }
  #pragma unroll
  for (int nt = 0; nt < 4; nt++) {
    int c = bn + wc * 64 + nt * 16 + lr;
    int which = c >> 9;
    int h = (c >> 6) & (H_ - 1);
    int d = c & 63;
    unsigned short* dst = which == 0 ? qb : (which == 1 ? kb : vb);
    #pragma unroll
    for (int mt = 0; mt < 4; mt++)
      #pragma unroll
      for (int r = 0; r < 4; r++) {
        int row = bm + wr * 64 + mt * 16 + 4 * lg + r;
        int b = row >> 13, n = row & (N_ - 1);
        dst[(((size_t)(b * H_ + h) * N_ + n) << 6) + d] = f2bf(acc[mt][nt][r]);
      }
  }
}

// ---------------- MFMA GEMM: out = oh @ woutT^T + bias + resid (f32 out), XCD-swizzled ----------------
__global__ __launch_bounds__(256, 2) void mfma_out(const unsigned short* __restrict__ oh,
    const unsigned short* __restrict__ wT, const float* __restrict__ bias,
    const float* __restrict__ resid, float* __restrict__ out)
{
  __shared__ unsigned short As[128][72];
  __shared__ unsigned short Bs[128][72];
  int tid = threadIdx.x;
  // XCD swizzle (nwg = 4*256 = 1024, %8==0)
  int nwgx = gridDim.x, nwg = nwgx * gridDim.y;
  int l = blockIdx.y * nwgx + blockIdx.x;
  int swz = (l & 7) * (nwg >> 3) + (l >> 3);
  int bn = (swz % nwgx) * 128, bm = (swz / nwgx) * 128;
  int wid = tid >> 6, lane = tid & 63;
  int wr = wid >> 1, wc = wid & 1;
  int lr = lane & 15, lg = lane >> 4;
  const f32x4 zf = {0.f, 0.f, 0.f, 0.f};
  f32x4 acc[4][4];
  #pragma unroll
  for (int mt = 0; mt < 4; mt++)
    #pragma unroll
    for (int nt = 0; nt < 4; nt++) acc[mt][nt] = zf;

  for (int k0 = 0; k0 < INNER_; k0 += 64) {
    __syncthreads();
    #pragma unroll
    for (int rnd = 0; rnd < 4; rnd++) {
      int idx = rnd * 2048 + tid * 8;
      int row = idx >> 6, col = idx & 63;
      *reinterpret_cast<bf16x8*>(&As[row][col]) =
          *reinterpret_cast<const bf16x8*>(&oh[((size_t)(bm + row) << 9) + k0 + col]);
      *reinterpret_cast<bf16x8*>(&Bs[row][col]) =
          *reinterpret_cast<const bf16x8*>(&wT[(size_t)(bn + row) * INNER_ + k0 + col]);
    }
    __syncthreads();
    bf16x8 af[4][2], bfr[4][2];
    #pragma unroll
    for (int mt = 0; mt < 4; mt++) {
      af[mt][0] = *reinterpret_cast<const bf16x8*>(&As[wr * 64 + mt * 16 + lr][lg * 8]);
      af[mt][1] = *reinterpret_cast<const bf16x8*>(&As[wr * 64 + mt * 16 + lr][32 + lg * 8]);
    }
    #pragma unroll
    for (int nt = 0; nt < 4; nt++) {
      bfr[nt][0] = *reinterpret_cast<const bf16x8*>(&Bs[wc * 64 + nt * 16 + lr][lg * 8]);
      bfr[nt][1] = *reinterpret_cast<const bf16x8*>(&Bs[wc * 64 + nt * 16 + lr][32 + lg * 8]);
    }
    __builtin_amdgcn_s_setprio(1);
    #pragma unroll
    for (int mt = 0; mt < 4; mt++)
      #pragma unroll
      for (int nt = 0; nt < 4; nt++) {
        acc[mt][nt] = __builtin_amdgcn_mfma_f32_16x16x32_bf16(af[mt][0], bfr[nt][0], acc[mt][nt], 0, 0, 0);
        acc[mt][nt] = __builtin_amdgcn_mfma_f32_16x16x32_bf16(af[mt][1], bfr[nt][1], acc[mt][nt], 0, 0, 0);
      }
    __builtin_amdgcn_s_setprio(0);
  }
  #pragma unroll
  for (int nt = 0; nt < 4; nt++) {
    int c = bn + wc * 64 + nt * 16 + lr;
    float bias_c = bias[c];
    #pragma unroll
    for (int mt = 0; mt < 4; mt++)
      #pragma unroll
      for (int r = 0; r < 4; r++) {
        int row = bm + wr * 64 + mt * 16 + 4 * lg + r;
        out[(size_t)row * DIM_ + c] = acc[mt][nt][r] + bias_c + resid[(size_t)row * DIM_ + c];
      }
  }
}

// ---------------- landmark means (f32 + bf16 q_l, bf16 k_l) ----------------
__global__ __launch_bounds__(64) void landmark_kernel(const unsigned short* __restrict__ qb,
    const unsigned short* __restrict__ kb, float* __restrict__ ql, float* __restrict__ kl,
    unsigned short* __restrict__ qlb, unsigned short* __restrict__ klb)
{
  int id = blockIdx.x;
  int m = id & (M_ - 1);
  int bh = id >> 8;
  int d = threadIdx.x;
  size_t base = (((size_t)bh * N_ + m * L_) << 6) + d;
  float sq = 0, sk = 0;
  #pragma unroll 4
  for (int j = 0; j < L_; j++) {
    sq += bf2f(qb[base + ((size_t)j << 6)]);
    sk += bf2f(kb[base + ((size_t)j << 6)]);
  }
  float qv = sq * (1.f / L_);
  float kv = sk * (1.f / L_);
  size_t o = ((size_t)bh * M_ + m) * DH_ + d;
  ql[o] = qv;
  kl[o] = kv;
  qlb[o] = f2bf(qv);
  klb[o] = f2bf(kv);
}

// ---------------- sim2 + softmax -> attn2 (f32 + bf16) ----------------
__global__ __launch_bounds__(256) void attn2_kernel(const float* __restrict__ ql,
    const float* __restrict__ kl, float* __restrict__ a2, unsigned short* __restrict__ a2b)
{
  int id = blockIdx.x;
  int i = id & (M_ - 1);
  int bh = id >> 8;
  int j = threadIdx.x;
  __shared__ float qs[DH_];
  __shared__ float wred[4];
  if (j < DH_) qs[j] = ql[((size_t)bh * M_ + i) * DH_ + j];
  __syncthreads();
  const float* krow = kl + ((size_t)bh * M_ + j) * DH_;
  float s = 0;
  #pragma unroll
  for (int d = 0; d < DH_; d++) s += qs[d] * krow[d];
  float mx = s;
  #pragma unroll
  for (int off = 1; off < 64; off <<= 1) mx = fmaxf(mx, __shfl_xor(mx, off));
  int wid = j >> 6, lane = j & 63;
  if (lane == 0) wred[wid] = mx;
  __syncthreads();
  mx = fmaxf(fmaxf(wred[0], wred[1]), fmaxf(wred[2], wred[3]));
  float e = __expf(s - mx);
  float sum = e;
  #pragma unroll
  for (int off = 1; off < 64; off <<= 1) sum += __shfl_xor(sum, off);
  __syncthreads();
  if (lane == 0) wred[wid] = sum;
  __syncthreads();
  sum = wred[0] + wred[1] + wred[2] + wred[3];
  float p = e / sum;
  size_t o = ((size_t)bh * M_ + i) * M_ + j;
  a2[o] = p;
  a2b[o] = f2bf(p);
}

// ---------------- pinv scale ----------------
__global__ void zero_scal(unsigned int* scal) { scal[threadIdx.x] = 0u; }

__global__ __launch_bounds__(256) void pinv_scale_kernel(const float* __restrict__ a2,
    unsigned int* __restrict__ scal)
{
  int bh = blockIdx.x;
  int t = threadIdx.x;
  const float* xb = a2 + (size_t)bh * M_ * M_;
  float rowsum = 0, colsum = 0;
  for (int j = 0; j < M_; j++) {
    rowsum += xb[(size_t)t * M_ + j];
    colsum += xb[(size_t)j * M_ + t];
  }
  #pragma unroll
  for (int off = 1; off < 64; off <<= 1) {
    rowsum = fmaxf(rowsum, __shfl_xor(rowsum, off));
    colsum = fmaxf(colsum, __shfl_xor(colsum, off));
  }
  __shared__ float wr[4], wc[4];
  int wid = t >> 6, lane = t & 63;
  if (lane == 0) { wr[wid] = rowsum; wc[wid] = colsum; }
  __syncthreads();
  if (t == 0) {
    float rm = fmaxf(fmaxf(wr[0], wr[1]), fmaxf(wr[2], wr[3]));
    float cm = fmaxf(fmaxf(wc[0], wc[1]), fmaxf(wc[2], wc[3]));
    atomicMax(&scal[0], __float_as_uint(rm));
    atomicMax(&scal[1], __float_as_uint(cm));
  }
}

// ---------------- z0 = a2^T/s: row-form (LDS transpose) + T-form (direct) bf16 ----------------
__global__ __launch_bounds__(256) void zinit_kernel(const float* __restrict__ a2,
    const unsigned int* __restrict__ scal,
    unsigned short* __restrict__ zR, unsigned short* __restrict__ zT)
{
  __shared__ float T[64][65];
  int j0 = blockIdx.x * 64, i0 = blockIdx.y * 64;
  size_t bb = (size_t)blockIdx.z * (M_ * M_);
  float inv = 1.f / (__uint_as_float(scal[0]) * __uint_as_float(scal[1]));
  int tid = threadIdx.x;
  #pragma unroll 4
  for (int pass = 0; pass < 16; pass++) {
    int idx = pass * 256 + tid;
    int ii = idx >> 6, jj = idx & 63;
    float v = a2[bb + (size_t)(i0 + ii) * M_ + j0 + jj];
    T[ii][jj] = v;
    zT[bb + (size_t)(i0 + ii) * M_ + j0 + jj] = f2bf(v * inv);  // zT[n][k] = a2[n][k]*inv
  }
  __syncthreads();
  #pragma unroll 4
  for (int pass = 0; pass < 16; pass++) {
    int idx = pass * 256 + tid;
    int jj = idx >> 6, ii = idx & 63;
    zR[bb + (size_t)(j0 + jj) * M_ + i0 + ii] = f2bf(T[ii][jj] * inv);  // z0[j][i]
  }
}

// ---------------- batched bf16 MFMA GEMM, B pre-transposed (T-form [n][k]) ----------------
// C = A @ B. Outputs: R (row) = sR*C ; YT (T-form via LDS bounce) = (aY*I + sY*C)^T.
__global__ __launch_bounds__(256, 2) void bgemm_ns(
    const unsigned short* __restrict__ Ab, const unsigned short* __restrict__ BTb,
    unsigned short* __restrict__ Rb, unsigned short* __restrict__ YTb,
    float aY, float sY, float sR)
{
  __shared__ unsigned short Ash[64][72];   // [row][k]
  __shared__ unsigned short Bsh[64][72];   // [col][k]
  int bn = blockIdx.x * 64, bm = blockIdx.y * 64;
  size_t bb = (size_t)blockIdx.z * (M_ * M_);
  int tid = threadIdx.x, wid = tid >> 6, lane = tid & 63;
  int lr = lane & 15, lg = lane >> 4;
  int wr = (wid >> 1) * 32, wc = (wid & 1) * 32;   // wave tile 32x32
  const f32x4 zf = {0.f, 0.f, 0.f, 0.f};
  f32x4 acc[2][2];
  #pragma unroll
  for (int mt = 0; mt < 2; mt++)
    #pragma unroll
    for (int nt = 0; nt < 2; nt++) acc[mt][nt] = zf;

  for (int k0 = 0; k0 < M_; k0 += 64) {
    __syncthreads();
    #pragma unroll
    for (int pass = 0; pass < 2; pass++) {
      int idx = pass * 2048 + tid * 8;
      int row = idx >> 6, col = idx & 63;
      *reinterpret_cast<bf16x8*>(&Ash[row][col]) =
          *reinterpret_cast<const bf16x8*>(&Ab[bb + (size_t)(bm + row) * M_ + k0 + col]);
      *reinterpret_cast<bf16x8*>(&Bsh[row][col]) =
          *reinterpret_cast<const bf16x8*>(&BTb[bb + (size_t)(bn + row) * M_ + k0 + col]);
    }
    __syncthreads();
    #pragma unroll
    for (int kk = 0; kk < 64; kk += 32) {
      bf16x8 a0 = *reinterpret_cast<const bf16x8*>(&Ash[wr + lr][kk + lg * 8]);
      bf16x8 a1 = *reinterpret_cast<const bf16x8*>(&Ash[wr + 16 + lr][kk + lg * 8]);
      bf16x8 b0 = *reinterpret_cast<const bf16x8*>(&Bsh[wc + lr][kk + lg * 8]);
      bf16x8 b1 = *reinterpret_cast<const bf16x8*>(&Bsh[wc + 16 + lr][kk + lg * 8]);
      acc[0][0] = __builtin_amdgcn_mfma_f32_16x16x32_bf16(a0, b0, acc[0][0], 0, 0, 0);
      acc[0][1] = __builtin_amdgcn_mfma_f32_16x16x32_bf16(a0, b1, acc[0][1], 0, 0, 0);
      acc[1][0] = __builtin_amdgcn_mfma_f32_16x16x32_bf16(a1, b0, acc[1][0], 0, 0, 0);
      acc[1][1] = __builtin_amdgcn_mfma_f32_16x16x32_bf16(a1, b1, acc[1][1], 0, 0, 0);
    }
  }
  if (Rb) {
    #pragma unroll
    for (int mt = 0; mt < 2; mt++)
      #pragma unroll
      for (int nt = 0; nt < 2; nt++) {
        int col = bn + wc + nt * 16 + lr;
        #pragma unroll
        for (int r = 0; r < 4; r++) {
          int row = bm + wr + mt * 16 + 4 * lg + r;
          Rb[bb + (size_t)row * M_ + col] = f2bf(sR * acc[mt][nt][r]);
        }
      }
  }
  if (YTb) {
    __syncthreads();
    #pragma unroll
    for (int mt = 0; mt < 2; mt++)
      #pragma unroll
      for (int nt = 0; nt < 2; nt++) {
        int nl = wc + nt * 16 + lr;
        #pragma unroll
        for (int r = 0; r < 4; r++) {
          int ml = wr + mt * 16 + 4 * lg + r;
          float t = sY * acc[mt][nt][r] + ((bm + ml) == (bn + nl) ? aY : 0.f);
          Ash[nl][ml] = f2bf(t);
        }
      }
    __syncthreads();
    #pragma unroll
    for (int pass = 0; pass < 2; pass++) {
      int idx = pass * 2048 + tid * 8;
      int nl = idx >> 6, ml = idx & 63;
      *reinterpret_cast<bf16x8*>(&YTb[bb + (size_t)(bn + nl) * M_ + bm + ml]) =
          *reinterpret_cast<const bf16x8*>(&Ash[nl][ml]);
    }
  }
}

// ---------------- merged NS tail: z' = 0.25 z@y (R) AND u' = 0.25 u@y (R + vT') ----------------
// blockIdx.y < split: A=z -> Rz only. blockIdx.y >= split: A=u -> Ru and YT=(7I-0.25C)^T.
__global__ __launch_bounds__(256, 2) void bgemm_ns2(
    const unsigned short* __restrict__ Az, const unsigned short* __restrict__ Au,
    const unsigned short* __restrict__ BTb,
    unsigned short* __restrict__ Rz, unsigned short* __restrict__ Ru,
    unsigned short* __restrict__ YTb, int split)
{
  __shared__ unsigned short Ash[64][72];
  __shared__ unsigned short Bsh[64][72];
  int ysel = (int)blockIdx.y >= split;
  const unsigned short* Ab = ysel ? Au : Az;
  unsigned short* Rb = ysel ? Ru : Rz;
  unsigned short* Yb = ysel ? YTb : nullptr;
  int bn = blockIdx.x * 64;
  int bm = ((int)blockIdx.y - (ysel ? split : 0)) * 64;
  size_t bb = (size_t)blockIdx.z * (M_ * M_);
  int tid = threadIdx.x, wid = tid >> 6, lane = tid & 63;
  int lr = lane & 15, lg = lane >> 4;
  int wr = (wid >> 1) * 32, wc = (wid & 1) * 32;
  const f32x4 zf = {0.f, 0.f, 0.f, 0.f};
  f32x4 acc[2][2];
  #pragma unroll
  for (int mt = 0; mt < 2; mt++)
    #pragma unroll
    for (int nt = 0; nt < 2; nt++) acc[mt][nt] = zf;

  for (int k0 = 0; k0 < M_; k0 += 64) {
    __syncthreads();
    #pragma unroll
    for (int pass = 0; pass < 2; pass++) {
      int idx = pass * 2048 + tid * 8;
      int row = idx >> 6, col = idx & 63;
      *reinterpret_cast<bf16x8*>(&Ash[row][col]) =
          *reinterpret_cast<const bf16x8*>(&Ab[bb + (size_t)(bm + row) * M_ + k0 + col]);
      *reinterpret_cast<bf16x8*>(&Bsh[row][col]) =
          *reinterpret_cast<const bf16x8*>(&BTb[bb + (size_t)(bn + row) * M_ + k0 + col]);
    }
    __syncthreads();
    #pragma unroll
    for (int kk = 0; kk < 64; kk += 32) {
      bf16x8 a0 = *reinterpret_cast<const bf16x8*>(&Ash[wr + lr][kk + lg * 8]);
      bf16x8 a1 = *reinterpret_cast<const bf16x8*>(&Ash[wr + 16 + lr][kk + lg * 8]);
      bf16x8 b0 = *reinterpret_cast<const bf16x8*>(&Bsh[wc + lr][kk + lg * 8]);
      bf16x8 b1 = *reinterpret_cast<const bf16x8*>(&Bsh[wc + 16 + lr][kk + lg * 8]);
      acc[0][0] = __builtin_amdgcn_mfma_f32_16x16x32_bf16(a0, b0, acc[0][0], 0, 0, 0);
      acc[0][1] = __builtin_amdgcn_mfma_f32_16x16x32_bf16(a0, b1, acc[0][1], 0, 0, 0);
      acc[1][0] = __builtin_amdgcn_mfma_f32_16x16x32_bf16(a1, b0, acc[1][0], 0, 0, 0);
      acc[1][1] = __builtin_amdgcn_mfma_f32_16x16x32_bf16(a1, b1, acc[1][1], 0, 0, 0);
    }
  }
  // R = 0.25 * C
  #pragma unroll
  for (int mt = 0; mt < 2; mt++)
    #pragma unroll
    for (int nt = 0; nt < 2; nt++) {
      int col = bn + wc + nt * 16 + lr;
      #pragma unroll
      for (int r = 0; r < 4; r++) {
        int row = bm + wr + mt * 16 + 4 * lg + r;
        Rb[bb + (size_t)row * M_ + col] = f2bf(0.25f * acc[mt][nt][r]);
      }
    }
  // YT = (7I - 0.25 C)^T  (u-half only)
  if (Yb) {
    __syncthreads();
    #pragma unroll
    for (int mt = 0; mt < 2; mt++)
      #pragma unroll
      for (int nt = 0; nt < 2; nt++) {
        int nl = wc + nt * 16 + lr;
        #pragma unroll
        for (int r = 0; r < 4; r++) {
          int ml = wr + mt * 16 + 4 * lg + r;
          float t = -0.25f * acc[mt][nt][r] + ((bm + ml) == (bn + nl) ? 7.f : 0.f);
          Ash[nl][ml] = f2bf(t);
        }
      }
    __syncthreads();
    #pragma unroll
    for (int pass = 0; pass < 2; pass++) {
      int idx = pass * 2048 + tid * 8;
      int nl = idx >> 6, ml = idx & 63;
      *reinterpret_cast<bf16x8*>(&Yb[bb + (size_t)(bn + nl) * M_ + bm + ml]) =
          *reinterpret_cast<const bf16x8*>(&Ash[nl][ml]);
    }
  }
}

// ---------------- W2 = pinv @ pv -> w2t bf16 [bh][64][256] ----------------
__global__ __launch_bounds__(256) void gemm_w2(
    const unsigned short* __restrict__ zR,
    const unsigned short* __restrict__ pvT, unsigned short* __restrict__ w2t)
{
  int bm = blockIdx.x * 64;
  int batch = blockIdx.y;
  size_t bz = (size_t)batch * (M_ * M_);
  size_t bp = (size_t)batch << 14;
  int tid = threadIdx.x, wid = tid >> 6, lane = tid & 63;
  int lr = lane & 15, lg = lane >> 4;
  int r0 = bm + wid * 16;
  const f32x4 zf = {0.f, 0.f, 0.f, 0.f};
  f32x4 acc[4];
  #pragma unroll
  for (int nt = 0; nt < 4; nt++) acc[nt] = zf;

  #pragma unroll
  for (int k0 = 0; k0 < M_; k0 += 32) {
    bf16x8 a = *reinterpret_cast<const bf16x8*>(&zR[bz + (size_t)(r0 + lr) * M_ + k0 + lg * 8]);
    #pragma unroll
    for (int nt = 0; nt < 4; nt++) {
      bf16x8 b = *reinterpret_cast<const bf16x8*>(&pvT[bp + (size_t)(nt * 16 + lr) * M_ + k0 + lg * 8]);
      acc[nt] = __builtin_amdgcn_mfma_f32_16x16x32_bf16(a, b, acc[nt], 0, 0, 0);
    }
  }
  #pragma unroll
  for (int nt = 0; nt < 4; nt++) {
    int col = nt * 16 + lr;   // dh
    #pragma unroll
    for (int r = 0; r < 4; r++) {
      int row = r0 + 4 * lg + r;   // m
      w2t[bp + (size_t)col * M_ + row] = f2bf(acc[nt][r]);
    }
  }
}

// ---------------- pv partials: 8 waves x 32 rows, K/V staged once per (bh,slice) ----------------
__global__ __launch_bounds__(512) void pv_mfma(
    const unsigned short* __restrict__ kb, const unsigned short* __restrict__ vb,
    const unsigned short* __restrict__ qlb,
    float* __restrict__ pvpart, float2* __restrict__ msbuf)
{
  int slice = blockIdx.x;
  int bh    = blockIdx.z;
  int tid = threadIdx.x, wid = tid >> 6, lane = tid & 63;
  int lr = lane & 15, lg = lane >> 4;

  __shared__ unsigned short klds[64][72];
  __shared__ unsigned short vtld[64][72];
  __shared__ unsigned short plds_all[8][32][72];
  unsigned short (*plds)[72] = plds_all[wid];

  int mbase = wid * 32;
  const unsigned short* qbase = qlb + (((size_t)bh * M_ + mbase) << 6);
  bf16x8 qf[2][2];
  #pragma unroll
  for (int rt = 0; rt < 2; rt++)
    #pragma unroll
    for (int h2 = 0; h2 < 2; h2++)
      qf[rt][h2] = *reinterpret_cast<const bf16x8*>(&qbase[((rt * 16 + lr) << 6) + h2 * 32 + lg * 8]);

  const f32x4 zf = {0.f, 0.f, 0.f, 0.f};
  f32x4 oacc[2][4];
  #pragma unroll
  for (int rt = 0; rt < 2; rt++)
    #pragma unroll
    for (int dt = 0; dt < 4; dt++) oacc[rt][dt] = zf;
  float mrun[8], srun[8];
  #pragma unroll
  for (int i = 0; i < 8; i++) { mrun[i] = -1e30f; srun[i] = 0.f; }

  const unsigned short* kgb = kb + (((size_t)bh * N_ + slice * 1024) << 6);
  const unsigned short* vgb = vb + (((size_t)bh * N_ + slice * 1024) << 6);

  for (int c = 0; c < 16; c++) {
    __syncthreads();
    {
      int key = tid >> 3, seg = tid & 7;
      size_t goff = (((size_t)(c * 64 + key)) << 6) + seg * 8;
      bf16x8 kv = *reinterpret_cast<const bf16x8*>(&kgb[goff]);
      *reinterpret_cast<bf16x8*>(&klds[key][seg * 8]) = kv;
      bf16x8 vv = *reinterpret_cast<const bf16x8*>(&vgb[goff]);
      int col = key ^ (seg << 3);
      #pragma unroll
      for (int j = 0; j < 8; j++) vtld[seg * 8 + j][col] = (unsigned short)vv[j];
    }
    __syncthreads();
    f32x4 sacc[2][4];
    #pragma unroll
    for (int rt = 0; rt < 2; rt++)
      #pragma unroll
      for (int ct = 0; ct < 4; ct++) {
        bf16x8 b0 = *reinterpret_cast<const bf16x8*>(&klds[ct * 16 + lr][lg * 8]);
        bf16x8 b1 = *reinterpret_cast<const bf16x8*>(&klds[ct * 16 + lr][32 + lg * 8]);
        f32x4 a = __builtin_amdgcn_mfma_f32_16x16x32_bf16(qf[rt][0], b0, zf, 0, 0, 0);
        sacc[rt][ct] = __builtin_amdgcn_mfma_f32_16x16x32_bf16(qf[rt][1], b1, a, 0, 0, 0);
      }
    #pragma unroll
    for (int rt = 0; rt < 2; rt++)
      #pragma unroll
      for (int r = 0; r < 4; r++) {
        int ri = rt * 4 + r;
        float mc = fmaxf(fmaxf(sacc[rt][0][r], sacc[rt][1][r]), fmaxf(sacc[rt][2][r], sacc[rt][3][r]));
        #pragma unroll
        for (int off = 1; off < 16; off <<= 1) mc = fmaxf(mc, __shfl_xor(mc, off));
        float mnew = fmaxf(mrun[ri], mc);
        float corr = __expf(mrun[ri] - mnew);
        float psum = 0.f;
        #pragma unroll
        for (int ct = 0; ct < 4; ct++) {
          float p = __expf(sacc[rt][ct][r] - mnew);
          sacc[rt][ct][r] = p;
          psum += p;
        }
        #pragma unroll
        for (int off = 1; off < 16; off <<= 1) psum += __shfl_xor(psum, off);
        srun[ri] = srun[ri] * corr + psum;
        mrun[ri] = mnew;
        #pragma unroll
        for (int dt = 0; dt < 4; dt++) oacc[rt][dt][r] *= corr;
        #pragma unroll
        for (int ct = 0; ct < 4; ct++)
          plds[rt * 16 + 4 * lg + r][ct * 16 + lr] = f2bf(sacc[rt][ct][r]);
      }
    __builtin_amdgcn_s_waitcnt(0);
    bf16x8 pa[2][2];
    #pragma unroll
    for (int rt = 0; rt < 2; rt++)
      #pragma unroll
      for (int h = 0; h < 2; h++)
        pa[rt][h] = *reinterpret_cast<const bf16x8*>(&plds[rt * 16 + lr][h * 32 + lg * 8]);
    #pragma unroll
    for (int dt = 0; dt < 4; dt++) {
      int d = dt * 16 + lr;
      bf16x8 bv0 = *reinterpret_cast<const bf16x8*>(&vtld[d][(lg * 8) ^ (d & 0x38)]);
      bf16x8 bv1 = *reinterpret_cast<const bf16x8*>(&vtld[d][(32 + lg * 8) ^ (d & 0x38)]);
      #pragma unroll
      for (int rt = 0; rt < 2; rt++) {
        oacc[rt][dt] = __builtin_amdgcn_mfma_f32_16x16x32_bf16(pa[rt][0], bv0, oacc[rt][dt], 0, 0, 0);
        oacc[rt][dt] = __builtin_amdgcn_mfma_f32_16x16x32_bf16(pa[rt][1], bv1, oacc[rt][dt], 0, 0, 0);
      }
    }
  }
  size_t pbase = (((size_t)(bh * 8 + slice) * M_ + mbase) << 6);
  #pragma unroll
  for (int rt = 0; rt < 2; rt++)
    #pragma unroll
    for (int dt = 0; dt < 4; dt++)
      #pragma unroll
      for (int r = 0; r < 4; r++)
        pvpart[pbase + ((size_t)(rt * 16 + 4 * lg + r) << 6) + dt * 16 + lr] = oacc[rt][dt][r];
  if (lr == 0) {
    #pragma unroll
    for (int rt = 0; rt < 2; rt++)
      #pragma unroll
      for (int r = 0; r < 4; r++)
        msbuf[(size_t)(bh * 8 + slice) * M_ + mbase + rt * 16 + 4 * lg + r] =
            make_float2(mrun[rt * 4 + r], srun[rt * 4 + r]);
  }
}

// ---------------- combine split-N partials -> pv^T bf16 [bh][64][256] ----------------
__global__ __launch_bounds__(256) void pv_combine(const float* __restrict__ pvpart,
    const float2* __restrict__ msbuf, unsigned short* __restrict__ pvT)
{
  int row = blockIdx.x * 4 + (threadIdx.x >> 6);
  int bh = row >> 8, m = row & (M_ - 1);
  int d = threadIdx.x & 63;
  float2 ms[8];
  float mg = -1e30f;
  #pragma unroll
  for (int s = 0; s < 8; s++) {
    ms[s] = msbuf[(size_t)(bh * 8 + s) * M_ + m];
    mg = fmaxf(mg, ms[s].x);
  }
  float ssum = 0.f, o = 0.f;
  #pragma unroll
  for (int s = 0; s < 8; s++) {
    float w = __expf(ms[s].x - mg);
    ssum += ms[s].y * w;
    o += w * pvpart[(((size_t)(bh * 8 + s) * M_ + m) << 6) + d];
  }
  pvT[((size_t)bh << 14) + (size_t)d * M_ + m] = f2bf(o / ssum);
}

// ---------------- attn1: oh = softmax(q @ kl^T) @ W2 via MFMA; kl staged in LDS ----------------
__global__ __launch_bounds__(256) void attn1_kernel(
    const unsigned short* __restrict__ qb,
    const unsigned short* __restrict__ klb,
    const unsigned short* __restrict__ w2t,
    unsigned short* __restrict__ oh)
{
  int ntile = blockIdx.x & 31;
  int bh = blockIdx.x >> 5;
  int h = bh & (H_ - 1), b = bh >> 3;
  int tid = threadIdx.x, wid = tid >> 6, lane = tid & 63;
  int lr = lane & 15, lg = lane >> 4;
  __shared__ unsigned short klds[256][72];
  __shared__ unsigned short plds_all[4][16][264];
  unsigned short* plds = &plds_all[wid][0][0];

  const unsigned short* qbh  = qb  + (((size_t)bh * N_) << 6);
  const unsigned short* klbh = klb + ((size_t)bh << 14);
  const unsigned short* w2bh = w2t + ((size_t)bh << 14);

  #pragma unroll
  for (int e = 0; e < 8; e++) {
    int idx = e * 2048 + tid * 8;
    int row = idx >> 6, col = idx & 63;
    *reinterpret_cast<bf16x8*>(&klds[row][col]) =
        *reinterpret_cast<const bf16x8*>(&klbh[((size_t)row << 6) + col]);
  }
  __syncthreads();

  const f32x4 zf = {0.f, 0.f, 0.f, 0.f};
  for (int sub = 0; sub < 4; sub++) {
    int n0 = ntile * 256 + sub * 64 + wid * 16;
    bf16x8 aq0 = *reinterpret_cast<const bf16x8*>(&qbh[((size_t)(n0 + lr) << 6) + lg * 8]);
    bf16x8 aq1 = *reinterpret_cast<const bf16x8*>(&qbh[((size_t)(n0 + lr) << 6) + 32 + lg * 8]);
    f32x4 accs[16];
    __builtin_amdgcn_s_setprio(1);
    #pragma unroll
    for (int mt = 0; mt < 16; mt++) {
      bf16x8 b0 = *reinterpret_cast<const bf16x8*>(&klds[mt * 16 + lr][lg * 8]);
      bf16x8 b1 = *reinterpret_cast<const bf16x8*>(&klds[mt * 16 + lr][32 + lg * 8]);
      f32x4 a = __builtin_amdgcn_mfma_f32_16x16x32_bf16(aq0, b0, zf, 0, 0, 0);
      accs[mt] = __builtin_amdgcn_mfma_f32_16x16x32_bf16(aq1, b1, a, 0, 0, 0);
    }
    __builtin_amdgcn_s_setprio(0);
    float rs[4];
    #pragma unroll
    for (int r = 0; r < 4; r++) {
      float m0 = accs[0][r];
      #pragma unroll
      for (int mt = 1; mt < 16; mt++) m0 = fmaxf(m0, accs[mt][r]);
      #pragma unroll
      for (int off = 1; off < 16; off <<= 1) m0 = fmaxf(m0, __shfl_xor(m0, off));
      float s0 = 0.f;
      #pragma unroll
      for (int mt = 0; mt < 16; mt++) {
        float p = __expf(accs[mt][r] - m0);
        accs[mt][r] = p;
        s0 += p;
      }
      #pragma unroll
      for (int off = 1; off < 16; off <<= 1) s0 += __shfl_xor(s0, off);
      rs[r] = 1.f / s0;
    }
    #pragma unroll
    for (int mt = 0; mt < 16; mt++)
      #pragma unroll
      for (int r = 0; r < 4; r++)
        plds[(4 * lg + r) * 264 + mt * 16 + lr] = f2bf(accs[mt][r]);
    __builtin_amdgcn_s_waitcnt(0);
    bf16x8 pa[8];
    #pragma unroll
    for (int mc = 0; mc < 8; mc++)
      pa[mc] = *reinterpret_cast<const bf16x8*>(&plds[lr * 264 + mc * 32 + lg * 8]);
    f32x4 acco[4];
    __builtin_amdgcn_s_setprio(1);
    #pragma unroll
    for (int dt = 0; dt < 4; dt++) {
      f32x4 a = zf;
      #pragma unroll
      for (int mc = 0; mc < 8; mc++) {
        bf16x8 wf = *reinterpret_cast<const bf16x8*>(&w2bh[(size_t)(dt * 16 + lr) * M_ + mc * 32 + lg * 8]);
        a = __builtin_amdgcn_mfma_f32_16x16x32_bf16(pa[mc], wf, a, 0, 0, 0);
      }
      acco[dt] = a;
    }
    __builtin_amdgcn_s_setprio(0);
    #pragma unroll
    for (int dt = 0; dt < 4; dt++)
      #pragma unroll
      for (int r = 0; r < 4; r++) {
        int n = n0 + 4 * lg + r;
        oh[((size_t)(b * N_ + n) << 9) + h * DH_ + dt * 16 + lr] = f2bf(acco[dt][r] * rs[r]);
      }
  }
}

// ---------------- depthwise conv residual: register sliding window ----------------
__global__ __launch_bounds__(256) void conv_kernel(const unsigned short* __restrict__ vb,
    const float* __restrict__ rw, unsigned short* __restrict__ oh)
{
  int bh = blockIdx.y;
  int h = bh & (H_ - 1), b = bh >> 3;
  int d = threadIdx.x & 63, g = threadIdx.x >> 6;
  int n0 = blockIdx.x * 128 + g * 32;
  const unsigned short* vbb = vb + (((size_t)bh * N_) << 6) + d;
  float w[64];
  #pragma unroll
  for (int j = 0; j < 64; j++) {
    int nn = n0 - 16 + j;
    w[j] = (nn >= 0 && nn < N_) ? bf2f(vbb[(size_t)nn << 6]) : 0.f;
  }
  float rwr[RESK_];
  #pragma unroll
  for (int j = 0; j < RESK_; j++) rwr[j] = rw[h * RESK_ + j];
  size_t obase = (((size_t)(b * N_ + n0)) << 9) + h * 64 + d;
  #pragma unroll
  for (int t = 0; t < 32; t++) {
    float acc = 0.f;
    #pragma unroll
    for (int j = 0; j < RESK_; j++) acc += rwr[j] * w[t + j];
    size_t oi = obase + ((size_t)t << 9);
    oh[oi] = f2bf(bf2f(oh[oi]) + acc);
  }
}

extern "C" void kernel_launch(void* const* d_in, const int* in_sizes, int n_in,
                              void* d_out, int out_size, void* d_ws, size_t ws_size,
                              hipStream_t stream)
{
  const float* x     = (const float*)d_in[0];
  const float* ln_w  = (const float*)d_in[1];
  const float* ln_b  = (const float*)d_in[2];
  const float* w_qkv = (const float*)d_in[3];
  const float* w_out = (const float*)d_in[4];
  const float* b_out = (const float*)d_in[5];
  const float* res_w = (const float*)d_in[6];
  float* out = (float*)d_out;

  const size_t HEADEL = (size_t)B_ * H_ * N_ * DH_;   // 16,777,216
  const size_t SMALL  = (size_t)B_ * H_ * M_ * DH_;   // 524,288
  const size_t MSQ    = (size_t)B_ * H_ * M_ * M_;    // 2,097,152

  char* p = (char*)d_ws;
  auto alloc = [&](size_t bytes) { char* r = p; p += (bytes + 255) & ~(size_t)255; return r; };

  unsigned short* qb  = (unsigned short*)alloc(HEADEL * 2);
  unsigned short* kb  = (unsigned short*)alloc(HEADEL * 2);
  unsigned short* vb  = (unsigned short*)alloc(HEADEL * 2);
  unsigned short* oh  = (unsigned short*)alloc(HEADEL * 2);
  // union A: xnb (32 MB) then z0R/z0T/z1R + u ping (4 x 4 MB)
  char* unA = alloc(HEADEL * 2);
  unsigned short* xnb = (unsigned short*)unA;
  unsigned short* z0R = (unsigned short*)unA;
  unsigned short* z0T = z0R + MSQ;
  unsigned short* z1R = z0T + MSQ;
  unsigned short* u2  = z1R + MSQ;
  // union B: pvpart f32 (16 MB) + msbuf then u / vT / wT / yT (4 x 4 MB)
  char* unB = alloc(HEADEL * 2);
  float*  pvpart = (float*)unB;
  float2* msbuf  = (float2*)(unB + (size_t)B_ * H_ * 8 * M_ * DH_ * 4);
  unsigned short* ub  = (unsigned short*)unB;
  unsigned short* vTb = ub + MSQ;
  unsigned short* wTb = vTb + MSQ;
  unsigned short* yTb = wTb + MSQ;

  unsigned short* wqkvT = (unsigned short*)alloc((size_t)K3_ * DIM_ * 2);
  unsigned short* woutT = (unsigned short*)alloc((size_t)DIM_ * INNER_ * 2);
  float* ql  = (float*)alloc(SMALL * 4);
  float* kl  = (float*)alloc(SMALL * 4);
  unsigned short* qlb = (unsigned short*)alloc(SMALL * 2);
  unsigned short* klb = (unsigned short*)alloc(SMALL * 2);
  unsigned short* pvT = (unsigned short*)alloc(SMALL * 2);
  unsigned short* w2t = (unsigned short*)alloc(SMALL * 2);
  unsigned short* a2b = (unsigned short*)alloc(MSQ * 2);
  unsigned int* scal  = (unsigned int*)alloc(256);
  if ((size_t)(p - (char*)d_ws) > ws_size) return;

  float* a2 = (float*)d_out;   // 8 MB, dead before mfma_out overwrites d_out

  ln_bf16<<<B_ * N_, 256, 0, stream>>>(x, ln_w, ln_b, xnb);
  transpose_w<<<dim3(K3_ / 64, DIM_ / 64), 256, 0, stream>>>(w_qkv, wqkvT, DIM_, K3_, INNER_, 0.125f);
  transpose_w<<<dim3(DIM_ / 64, INNER_ / 64), 256, 0, stream>>>(w_out, woutT, INNER_, DIM_, 0, 1.f);
  mfma_qkv<<<dim3(K3_ / 128, (B_ * N_) / 128), 256, 0, stream>>>(xnb, wqkvT, qb, kb, vb);
  landmark_kernel<<<B_ * H_ * M_, 64, 0, stream>>>(qb, kb, ql, kl, qlb, klb);
  attn2_kernel<<<B_ * H_ * M_, 256, 0, stream>>>(ql, kl, a2, a2b);
  zero_scal<<<1, 2, 0, stream>>>(scal);
  pinv_scale_kernel<<<B_ * H_, 256, 0, stream>>>(a2, scal);
  pv_mfma<<<dim3(8, 1, B_ * H_), 512, 0, stream>>>(kb, vb, qlb, pvpart, msbuf);
  pv_combine<<<(B_ * H_ * M_) / 4, 256, 0, stream>>>(pvpart, msbuf, pvT);
  // zinit AFTER mfma_qkv (xnb dead)
  zinit_kernel<<<dim3(4, 4, B_ * H_), 256, 0, stream>>>(a2, scal, z0R, z0T);

  // Newton-Schulz chain, pure bf16, fused z'/u' updates.
  // u = a2@z ; v = 7I-u ; w = 15I-u@v ; y = 13I-u@w ; z' = 0.25 z@y ; u' = 0.25 u@y
  dim3 g44(4, 4, B_ * H_);
  dim3 g48(4, 8, B_ * H_);
  // u0 = a2 @ z0 (via z0T), emit u0 (row) + vT0 = (7I-u0)^T
  bgemm_ns<<<g44, 256, 0, stream>>>(a2b, z0T, ub, vTb, 7.f, -1.f, 1.f);
  unsigned short *cR = z0R, *nR = z1R, *cu = ub, *nu = u2;
  for (int it = 0; it < 6; it++) {
    bgemm_ns<<<g44, 256, 0, stream>>>(cu, vTb, nullptr, wTb, 15.f, -1.f, 0.f);
    bgemm_ns<<<g44, 256, 0, stream>>>(cu, wTb, nullptr, yTb, 13.f, -1.f, 0.f);
    if (it < 5) {
      // merged: z' (blocks y<4) and u' + vT' (blocks y>=4)
      bgemm_ns2<<<g48, 256, 0, stream>>>(cR, cu, yTb, nR, nu, vTb, 4);
      unsigned short* t;
      t = cR; cR = nR; nR = t;  t = cu; cu = nu; nu = t;
    } else {
      // last iteration: z' only
      bgemm_ns2<<<g44, 256, 0, stream>>>(cR, cu, yTb, nR, nu, vTb, 4);
      cR = nR;
    }
  }

  gemm_w2<<<dim3(4, B_ * H_), 256, 0, stream>>>(cR, pvT, w2t);

  attn1_kernel<<<B_ * H_ * (N_ / 256), 256, 0, stream>>>(qb, klb, w2t, oh);
  conv_kernel<<<dim3(N_ / 128, B_ * H_), 256, 0, stream>>>(vb, res_w, oh);
  mfma_out<<<dim3(DIM_ / 128, (B_ * N_) / 128), 256, 0, stream>>>(oh, woutT, b_out, x, out);
}